// Round 1
// baseline (2966.277 us; speedup 1.0000x reference)
//
#include <hip/hip_runtime.h>

// Problem constants (fixed by the reference)
static constexpr int N1  = 200000;
static constexpr int N2  = 40000;
static constexpr int N3  = 10000;
static constexpr int IND = 128;
static constexpr int HID = 256;
static constexpr int OUTD = 64;

// ---------------------------------------------------------------------------
// Scatter-mean layer 1: agg1[dst] += x[src] (128 floats), cnt1[dst] += 1
// One thread per (edge, float4-chunk): 32 chunks/edge.
// ---------------------------------------------------------------------------
__global__ void scatter1_kernel(const float* __restrict__ x,
                                const int* __restrict__ src,
                                const int* __restrict__ dst,
                                int E,
                                float* __restrict__ agg,
                                float* __restrict__ cnt) {
    long long idx = (long long)blockIdx.x * blockDim.x + threadIdx.x;
    long long total = (long long)E * 32;
    if (idx >= total) return;
    int e = (int)(idx >> 5);
    int c = (int)(idx & 31);
    int s = src[e];
    int d = dst[e];
    const float4 v = reinterpret_cast<const float4*>(x + (long long)s * IND)[c];
    float* a = agg + (long long)d * IND + c * 4;
    atomicAdd(a + 0, v.x);
    atomicAdd(a + 1, v.y);
    atomicAdd(a + 2, v.z);
    atomicAdd(a + 3, v.w);
    if (c == 0) atomicAdd(cnt + d, 1.0f);
}

// ---------------------------------------------------------------------------
// Layer-1 dense: h[i,j] = relu( mean1[i,:]·W1l[j,:] + b1[j] + x[i,:]·W1r[j,:] )
// One block per target row i (256 threads = 256 output channels).
// ---------------------------------------------------------------------------
__global__ __launch_bounds__(HID) void sage1_kernel(
    const float* __restrict__ x,
    const float* __restrict__ agg, const float* __restrict__ cnt,
    const float* __restrict__ W1l, const float* __restrict__ W1r,
    const float* __restrict__ b1,
    float* __restrict__ h) {
    int i = blockIdx.x;
    int t = threadIdx.x;
    __shared__ float xm[IND];
    __shared__ float xt[IND];
    if (t < IND) {
        float inv = 1.0f / fmaxf(cnt[i], 1.0f);
        xm[t] = agg[(long long)i * IND + t] * inv;
        xt[t] = x[(long long)i * IND + t];
    }
    __syncthreads();
    float acc = b1[t];
    const float4* wl = reinterpret_cast<const float4*>(W1l + (long long)t * IND);
    const float4* wr = reinterpret_cast<const float4*>(W1r + (long long)t * IND);
    const float4* pm = reinterpret_cast<const float4*>(xm);
    const float4* pt = reinterpret_cast<const float4*>(xt);
#pragma unroll 8
    for (int k = 0; k < IND / 4; ++k) {
        float4 a = wl[k], b = wr[k], m = pm[k], q = pt[k];
        acc += a.x * m.x + a.y * m.y + a.z * m.z + a.w * m.w;
        acc += b.x * q.x + b.y * q.y + b.z * q.z + b.w * q.w;
    }
    h[(long long)i * HID + t] = fmaxf(acc, 0.0f);
}

// ---------------------------------------------------------------------------
// Scatter-mean layer 2: agg2[dst] += h[src] (256 floats), cnt2[dst] += 1
// One thread per (edge, float4-chunk): 64 chunks/edge.
// ---------------------------------------------------------------------------
__global__ void scatter2_kernel(const float* __restrict__ h,
                                const int* __restrict__ src,
                                const int* __restrict__ dst,
                                int E,
                                float* __restrict__ agg,
                                float* __restrict__ cnt) {
    long long idx = (long long)blockIdx.x * blockDim.x + threadIdx.x;
    long long total = (long long)E * 64;
    if (idx >= total) return;
    int e = (int)(idx >> 6);
    int c = (int)(idx & 63);
    int s = src[e];
    int d = dst[e];
    const float4 v = reinterpret_cast<const float4*>(h + (long long)s * HID)[c];
    float* a = agg + (long long)d * HID + c * 4;
    atomicAdd(a + 0, v.x);
    atomicAdd(a + 1, v.y);
    atomicAdd(a + 2, v.z);
    atomicAdd(a + 3, v.w);
    if (c == 0) atomicAdd(cnt + d, 1.0f);
}

// ---------------------------------------------------------------------------
// Layer-2 dense + log_softmax, fused. One block (= one wave, 64 lanes) per row.
// out[i,j] = logsoftmax_j( mean2[i,:]·W2l[j,:] + b2[j] + h[i,:]·W2r[j,:] )
// ---------------------------------------------------------------------------
__global__ __launch_bounds__(OUTD) void sage2_kernel(
    const float* __restrict__ h,
    const float* __restrict__ agg, const float* __restrict__ cnt,
    const float* __restrict__ W2l, const float* __restrict__ W2r,
    const float* __restrict__ b2,
    float* __restrict__ out) {
    int i = blockIdx.x;
    int t = threadIdx.x;
    __shared__ float hm[HID];
    __shared__ float ht[HID];
    float inv = 1.0f / fmaxf(cnt[i], 1.0f);
    for (int k = t; k < HID; k += OUTD) {
        hm[k] = agg[(long long)i * HID + k] * inv;
        ht[k] = h[(long long)i * HID + k];
    }
    __syncthreads();
    float acc = b2[t];
    const float4* wl = reinterpret_cast<const float4*>(W2l + (long long)t * HID);
    const float4* wr = reinterpret_cast<const float4*>(W2r + (long long)t * HID);
    const float4* pm = reinterpret_cast<const float4*>(hm);
    const float4* pt = reinterpret_cast<const float4*>(ht);
#pragma unroll 8
    for (int k = 0; k < HID / 4; ++k) {
        float4 a = wl[k], b = wr[k], m = pm[k], q = pt[k];
        acc += a.x * m.x + a.y * m.y + a.z * m.z + a.w * m.w;
        acc += b.x * q.x + b.y * q.y + b.z * q.z + b.w * q.w;
    }
    // 64-lane (single wave) log-softmax
    float mx = acc;
#pragma unroll
    for (int o = 32; o > 0; o >>= 1) mx = fmaxf(mx, __shfl_xor(mx, o));
    float ex = __expf(acc - mx);
    float sm = ex;
#pragma unroll
    for (int o = 32; o > 0; o >>= 1) sm += __shfl_xor(sm, o);
    out[(long long)i * OUTD + t] = acc - mx - __logf(sm);
}

// ---------------------------------------------------------------------------
extern "C" void kernel_launch(void* const* d_in, const int* in_sizes, int n_in,
                              void* d_out, int out_size, void* d_ws, size_t ws_size,
                              hipStream_t stream) {
    const float* x    = (const float*)d_in[0];
    const int*   src1 = (const int*)d_in[1];
    const int*   dst1 = (const int*)d_in[2];
    const int*   src2 = (const int*)d_in[3];
    const int*   dst2 = (const int*)d_in[4];
    // d_in[5] = n2, d_in[6] = n3 (device scalars; shapes are compile-time here)
    const float* W1l  = (const float*)d_in[7];
    const float* W1r  = (const float*)d_in[8];
    const float* b1   = (const float*)d_in[9];
    const float* W2l  = (const float*)d_in[10];
    const float* W2r  = (const float*)d_in[11];
    const float* b2   = (const float*)d_in[12];
    float* out = (float*)d_out;

    const int E1 = in_sizes[1];
    const int E2 = in_sizes[3];

    // Workspace layout (bytes), 256-aligned offsets:
    //   agg1 [N2*128] : 0            (20,480,000 B)
    //   cnt1 [N2]     : 20,480,000   (   160,000 B)
    //   agg2 [N3*256] : 20,640,000   (10,240,000 B)
    //   cnt2 [N3]     : 30,880,000   (    40,000 B)
    //   h    [N2*256] : 30,920,192   (40,960,000 B)   total ~71.9 MB
    char* ws = (char*)d_ws;
    float* agg1 = (float*)(ws + 0);
    float* cnt1 = (float*)(ws + 20480000);
    float* agg2 = (float*)(ws + 20640000);
    float* cnt2 = (float*)(ws + 30880000);
    float* h    = (float*)(ws + 30920192);

    hipMemsetAsync(agg1, 0, (size_t)N2 * IND * sizeof(float), stream);
    hipMemsetAsync(cnt1, 0, (size_t)N2 * sizeof(float), stream);
    hipMemsetAsync(agg2, 0, (size_t)N3 * HID * sizeof(float), stream);
    hipMemsetAsync(cnt2, 0, (size_t)N3 * sizeof(float), stream);

    {
        long long total = (long long)E1 * 32;
        int grid = (int)((total + 255) / 256);
        scatter1_kernel<<<grid, 256, 0, stream>>>(x, src1, dst1, E1, agg1, cnt1);
    }
    sage1_kernel<<<N2, HID, 0, stream>>>(x, agg1, cnt1, W1l, W1r, b1, h);
    {
        long long total = (long long)E2 * 64;
        int grid = (int)((total + 255) / 256);
        scatter2_kernel<<<grid, 256, 0, stream>>>(h, src2, dst2, E2, agg2, cnt2);
    }
    sage2_kernel<<<N3, OUTD, 0, stream>>>(h, agg2, cnt2, W2l, W2r, b2, out);
}

// Round 2
// 2419.625 us; speedup vs baseline: 1.2259x; 1.2259x over previous
//
#include <hip/hip_runtime.h>

// Problem constants (fixed by the reference)
static constexpr int N1  = 200000;
static constexpr int N2  = 40000;
static constexpr int N3  = 10000;
static constexpr int IND = 128;
static constexpr int HID = 256;
static constexpr int OUTD = 64;

// ---------------------------------------------------------------------------
// Scatter-mean layer 1: agg1[dst] += x[src] (128 floats), cnt1[dst] += 1
// One thread per (edge, float4-chunk): 32 chunks/edge.
// ---------------------------------------------------------------------------
__global__ void scatter1_kernel(const float* __restrict__ x,
                                const int* __restrict__ src,
                                const int* __restrict__ dst,
                                int E,
                                float* __restrict__ agg,
                                float* __restrict__ cnt) {
    long long idx = (long long)blockIdx.x * blockDim.x + threadIdx.x;
    long long total = (long long)E * 32;
    if (idx >= total) return;
    int e = (int)(idx >> 5);
    int c = (int)(idx & 31);
    int s = src[e];
    int d = dst[e];
    const float4 v = reinterpret_cast<const float4*>(x + (long long)s * IND)[c];
    float* a = agg + (long long)d * IND + c * 4;
    atomicAdd(a + 0, v.x);
    atomicAdd(a + 1, v.y);
    atomicAdd(a + 2, v.z);
    atomicAdd(a + 3, v.w);
    if (c == 0) atomicAdd(cnt + d, 1.0f);
}

// ---------------------------------------------------------------------------
// Scatter-mean layer 2: agg2[dst] += h[src] (256 floats), cnt2[dst] += 1
// ---------------------------------------------------------------------------
__global__ void scatter2_kernel(const float* __restrict__ h,
                                const int* __restrict__ src,
                                const int* __restrict__ dst,
                                int E,
                                float* __restrict__ agg,
                                float* __restrict__ cnt) {
    long long idx = (long long)blockIdx.x * blockDim.x + threadIdx.x;
    long long total = (long long)E * 64;
    if (idx >= total) return;
    int e = (int)(idx >> 6);
    int c = (int)(idx & 63);
    int s = src[e];
    int d = dst[e];
    const float4 v = reinterpret_cast<const float4*>(h + (long long)s * HID)[c];
    float* a = agg + (long long)d * HID + c * 4;
    atomicAdd(a + 0, v.x);
    atomicAdd(a + 1, v.y);
    atomicAdd(a + 2, v.z);
    atomicAdd(a + 3, v.w);
    if (c == 0) atomicAdd(cnt + d, 1.0f);
}

// ---------------------------------------------------------------------------
// Layer-1 dense, SGPR-weight-streaming GEMM.
//   h[i,j] = relu( mean1[i,:]·W1l[j,:] + b1[j] + x[i,:]·W1r[j,:] )
// Block = 256 threads = 4 waves. Each wave: 64 rows (lane = row) x 64 cols.
// All 4 waves share the same 64 rows (A reads hit L1), cover cols 0..255.
// Weight addresses are wave-uniform -> s_load; inner loop = v_fmac(sgpr,vgpr).
// ---------------------------------------------------------------------------
__global__ __launch_bounds__(256) void sage1_kernel(
    const float* __restrict__ x,
    const float* __restrict__ agg, const float* __restrict__ cnt,
    const float* __restrict__ W1l, const float* __restrict__ W1r,
    const float* __restrict__ b1,
    float* __restrict__ h) {
    const int lane = threadIdx.x & 63;
    const int wid  = threadIdx.x >> 6;        // 0..3 -> column chunk
    const int row  = blockIdx.x * 64 + lane;  // 625*64 == 40000, exact
    const int j0   = wid * 64;

    const float inv = 1.0f / fmaxf(cnt[row], 1.0f);
    const float* __restrict__ arow = agg + (size_t)row * IND;
    const float* __restrict__ xrow = x   + (size_t)row * IND;

    float acc[64];
#pragma unroll
    for (int j = 0; j < 64; ++j) acc[j] = b1[j0 + j];

    // ---- part 1: mean (= agg*inv) against W1l ----
#pragma unroll 1
    for (int kc = 0; kc < IND / 8; ++kc) {
        float4 a0 = *reinterpret_cast<const float4*>(arow + kc * 8);
        float4 a1 = *reinterpret_cast<const float4*>(arow + kc * 8 + 4);
        float a[8] = {a0.x * inv, a0.y * inv, a0.z * inv, a0.w * inv,
                      a1.x * inv, a1.y * inv, a1.z * inv, a1.w * inv};
#pragma unroll
        for (int j = 0; j < 64; ++j) {
            const float* w = W1l + (size_t)(j0 + j) * IND + kc * 8;
            float4 w0 = *reinterpret_cast<const float4*>(w);
            float4 w1 = *reinterpret_cast<const float4*>(w + 4);
            acc[j] += a[0] * w0.x + a[1] * w0.y + a[2] * w0.z + a[3] * w0.w
                    + a[4] * w1.x + a[5] * w1.y + a[6] * w1.z + a[7] * w1.w;
        }
    }
    // ---- part 2: x (target) against W1r ----
#pragma unroll 1
    for (int kc = 0; kc < IND / 8; ++kc) {
        float4 a0 = *reinterpret_cast<const float4*>(xrow + kc * 8);
        float4 a1 = *reinterpret_cast<const float4*>(xrow + kc * 8 + 4);
        float a[8] = {a0.x, a0.y, a0.z, a0.w, a1.x, a1.y, a1.z, a1.w};
#pragma unroll
        for (int j = 0; j < 64; ++j) {
            const float* w = W1r + (size_t)(j0 + j) * IND + kc * 8;
            float4 w0 = *reinterpret_cast<const float4*>(w);
            float4 w1 = *reinterpret_cast<const float4*>(w + 4);
            acc[j] += a[0] * w0.x + a[1] * w0.y + a[2] * w0.z + a[3] * w0.w
                    + a[4] * w1.x + a[5] * w1.y + a[6] * w1.z + a[7] * w1.w;
        }
    }

    float4* hp = reinterpret_cast<float4*>(h + (size_t)row * HID + j0);
#pragma unroll
    for (int q = 0; q < 16; ++q) {
        hp[q] = make_float4(fmaxf(acc[4 * q + 0], 0.0f),
                            fmaxf(acc[4 * q + 1], 0.0f),
                            fmaxf(acc[4 * q + 2], 0.0f),
                            fmaxf(acc[4 * q + 3], 0.0f));
    }
}

// ---------------------------------------------------------------------------
// Layer-2 dense + log_softmax, fused. 1 wave per block; lane = row; each lane
// holds its full 64-wide output row in registers -> in-lane log_softmax.
// ---------------------------------------------------------------------------
__global__ __launch_bounds__(64) void sage2_kernel(
    const float* __restrict__ h,
    const float* __restrict__ agg, const float* __restrict__ cnt,
    const float* __restrict__ W2l, const float* __restrict__ W2r,
    const float* __restrict__ b2,
    float* __restrict__ out) {
    const int row = blockIdx.x * 64 + (threadIdx.x & 63);
    if (row >= N3) return;

    const float inv = 1.0f / fmaxf(cnt[row], 1.0f);
    const float* __restrict__ arow = agg + (size_t)row * HID;
    const float* __restrict__ hrow = h   + (size_t)row * HID;

    float acc[OUTD];
#pragma unroll
    for (int j = 0; j < OUTD; ++j) acc[j] = b2[j];

    // ---- part 1: mean (= agg2*inv) against W2l ----
#pragma unroll 1
    for (int kc = 0; kc < HID / 8; ++kc) {
        float4 a0 = *reinterpret_cast<const float4*>(arow + kc * 8);
        float4 a1 = *reinterpret_cast<const float4*>(arow + kc * 8 + 4);
        float a[8] = {a0.x * inv, a0.y * inv, a0.z * inv, a0.w * inv,
                      a1.x * inv, a1.y * inv, a1.z * inv, a1.w * inv};
#pragma unroll
        for (int j = 0; j < OUTD; ++j) {
            const float* w = W2l + (size_t)j * HID + kc * 8;
            float4 w0 = *reinterpret_cast<const float4*>(w);
            float4 w1 = *reinterpret_cast<const float4*>(w + 4);
            acc[j] += a[0] * w0.x + a[1] * w0.y + a[2] * w0.z + a[3] * w0.w
                    + a[4] * w1.x + a[5] * w1.y + a[6] * w1.z + a[7] * w1.w;
        }
    }
    // ---- part 2: h (target) against W2r ----
#pragma unroll 1
    for (int kc = 0; kc < HID / 8; ++kc) {
        float4 a0 = *reinterpret_cast<const float4*>(hrow + kc * 8);
        float4 a1 = *reinterpret_cast<const float4*>(hrow + kc * 8 + 4);
        float a[8] = {a0.x, a0.y, a0.z, a0.w, a1.x, a1.y, a1.z, a1.w};
#pragma unroll
        for (int j = 0; j < OUTD; ++j) {
            const float* w = W2r + (size_t)j * HID + kc * 8;
            float4 w0 = *reinterpret_cast<const float4*>(w);
            float4 w1 = *reinterpret_cast<const float4*>(w + 4);
            acc[j] += a[0] * w0.x + a[1] * w0.y + a[2] * w0.z + a[3] * w0.w
                    + a[4] * w1.x + a[5] * w1.y + a[6] * w1.z + a[7] * w1.w;
        }
    }

    // ---- in-lane log_softmax over acc[0..63] ----
    float mx = acc[0];
#pragma unroll
    for (int j = 1; j < OUTD; ++j) mx = fmaxf(mx, acc[j]);
    float sum = 0.0f;
#pragma unroll
    for (int j = 0; j < OUTD; ++j) sum += __expf(acc[j] - mx);
    const float lse = mx + __logf(sum);

    float4* op = reinterpret_cast<float4*>(out + (size_t)row * OUTD);
#pragma unroll
    for (int q = 0; q < OUTD / 4; ++q) {
        op[q] = make_float4(acc[4 * q + 0] - lse, acc[4 * q + 1] - lse,
                            acc[4 * q + 2] - lse, acc[4 * q + 3] - lse);
    }
}

// ---------------------------------------------------------------------------
extern "C" void kernel_launch(void* const* d_in, const int* in_sizes, int n_in,
                              void* d_out, int out_size, void* d_ws, size_t ws_size,
                              hipStream_t stream) {
    const float* x    = (const float*)d_in[0];
    const int*   src1 = (const int*)d_in[1];
    const int*   dst1 = (const int*)d_in[2];
    const int*   src2 = (const int*)d_in[3];
    const int*   dst2 = (const int*)d_in[4];
    const float* W1l  = (const float*)d_in[7];
    const float* W1r  = (const float*)d_in[8];
    const float* b1   = (const float*)d_in[9];
    const float* W2l  = (const float*)d_in[10];
    const float* W2r  = (const float*)d_in[11];
    const float* b2   = (const float*)d_in[12];
    float* out = (float*)d_out;

    const int E1 = in_sizes[1];
    const int E2 = in_sizes[3];

    // Workspace layout (bytes):
    //   agg1 [N2*128] : 0            (20,480,000 B)
    //   cnt1 [N2]     : 20,480,000   (   160,000 B)
    //   agg2 [N3*256] : 20,640,000   (10,240,000 B)
    //   cnt2 [N3]     : 30,880,000   (    40,000 B)
    //   h    [N2*256] : 30,920,192   (40,960,000 B)   total ~71.9 MB
    char* ws = (char*)d_ws;
    float* agg1 = (float*)(ws + 0);
    float* cnt1 = (float*)(ws + 20480000);
    float* agg2 = (float*)(ws + 20640000);
    float* cnt2 = (float*)(ws + 30880000);
    float* h    = (float*)(ws + 30920192);

    hipMemsetAsync(agg1, 0, (size_t)N2 * IND * sizeof(float), stream);
    hipMemsetAsync(cnt1, 0, (size_t)N2 * sizeof(float), stream);
    hipMemsetAsync(agg2, 0, (size_t)N3 * HID * sizeof(float), stream);
    hipMemsetAsync(cnt2, 0, (size_t)N3 * sizeof(float), stream);

    {
        long long total = (long long)E1 * 32;
        int grid = (int)((total + 255) / 256);
        scatter1_kernel<<<grid, 256, 0, stream>>>(x, src1, dst1, E1, agg1, cnt1);
    }
    sage1_kernel<<<N2 / 64, 256, 0, stream>>>(x, agg1, cnt1, W1l, W1r, b1, h);
    {
        long long total = (long long)E2 * 64;
        int grid = (int)((total + 255) / 256);
        scatter2_kernel<<<grid, 256, 0, stream>>>(h, src2, dst2, E2, agg2, cnt2);
    }
    sage2_kernel<<<(N3 + 63) / 64, 64, 0, stream>>>(h, agg2, cnt2, W2l, W2r, b2, out);
}

// Round 3
// 976.899 us; speedup vs baseline: 3.0364x; 2.4768x over previous
//
#include <hip/hip_runtime.h>

// Problem constants (fixed by the reference)
static constexpr int N1  = 200000;
static constexpr int N2  = 40000;
static constexpr int N3  = 10000;
static constexpr int IND = 128;
static constexpr int HID = 256;
static constexpr int OUTD = 64;

// ---------------------------------------------------------------------------
// CSR construction: degree histogram -> exclusive scan -> bucket fill.
// Replaces 82M float atomics with 2x 640k int atomics.
// ---------------------------------------------------------------------------
__global__ void hist_kernel(const int* __restrict__ dst, int E,
                            int* __restrict__ deg) {
    int i = blockIdx.x * blockDim.x + threadIdx.x;
    if (i < E) atomicAdd(&deg[dst[i]], 1);
}

// Single-block exclusive scan over n (<= ~64k) ints: each thread sums a
// contiguous chunk, Hillis-Steele over 1024 partials in LDS, then writes
// running exclusive prefix for its chunk.
__global__ __launch_bounds__(1024) void scan_kernel(
    const int* __restrict__ deg, int n, int* __restrict__ rowstart) {
    __shared__ int part[1024];
    const int T = 1024, t = threadIdx.x;
    const int per = (n + T - 1) / T;
    const int beg = t * per;
    const int end = min(beg + per, n);
    int s = 0;
    for (int i = beg; i < end; ++i) s += deg[i];
    part[t] = s;
    __syncthreads();
    for (int off = 1; off < T; off <<= 1) {
        int v = (t >= off) ? part[t - off] : 0;
        __syncthreads();
        part[t] += v;
        __syncthreads();
    }
    int run = (t == 0) ? 0 : part[t - 1];   // exclusive prefix of this chunk
    for (int i = beg; i < end; ++i) { rowstart[i] = run; run += deg[i]; }
}

__global__ void fill_kernel(const int* __restrict__ src,
                            const int* __restrict__ dst, int E,
                            const int* __restrict__ rowstart,
                            int* __restrict__ cursor,
                            int* __restrict__ csr) {
    int i = blockIdx.x * blockDim.x + threadIdx.x;
    if (i < E) {
        int d = dst[i];
        int p = atomicAdd(&cursor[d], 1);
        csr[rowstart[d] + p] = src[i];
    }
}

// ---------------------------------------------------------------------------
// Gather-mean layer 1: mean1[node,:] = mean over edges of x[src,:]  (128 f32)
// One wave per node; lane owns 2 floats (float2) -> 512 B coalesced per edge.
// ---------------------------------------------------------------------------
__global__ __launch_bounds__(256) void gather1_kernel(
    const float* __restrict__ x, const int* __restrict__ csr,
    const int* __restrict__ rowstart, const int* __restrict__ deg,
    float* __restrict__ mean) {
    const int node = blockIdx.x * 4 + (threadIdx.x >> 6);
    const int lane = threadIdx.x & 63;
    const int beg = rowstart[node];
    const int n   = deg[node];
    float2 acc0 = make_float2(0.f, 0.f), acc1 = make_float2(0.f, 0.f);
    int e = 0;
    for (; e + 1 < n; e += 2) {
        int s0 = csr[beg + e];
        int s1 = csr[beg + e + 1];
        float2 v0 = *reinterpret_cast<const float2*>(x + (size_t)s0 * IND + lane * 2);
        float2 v1 = *reinterpret_cast<const float2*>(x + (size_t)s1 * IND + lane * 2);
        acc0.x += v0.x; acc0.y += v0.y;
        acc1.x += v1.x; acc1.y += v1.y;
    }
    if (e < n) {
        int s0 = csr[beg + e];
        float2 v0 = *reinterpret_cast<const float2*>(x + (size_t)s0 * IND + lane * 2);
        acc0.x += v0.x; acc0.y += v0.y;
    }
    const float inv = (n > 0) ? 1.0f / (float)n : 0.0f;
    reinterpret_cast<float2*>(mean + (size_t)node * IND)[lane] =
        make_float2((acc0.x + acc1.x) * inv, (acc0.y + acc1.y) * inv);
}

// ---------------------------------------------------------------------------
// Gather-mean layer 2: mean2[node,:] = mean over edges of h[src,:]  (256 f32)
// One wave per node; lane owns 4 floats (float4) -> 1 KB coalesced per edge.
// ---------------------------------------------------------------------------
__global__ __launch_bounds__(256) void gather2_kernel(
    const float* __restrict__ h, const int* __restrict__ csr,
    const int* __restrict__ rowstart, const int* __restrict__ deg,
    float* __restrict__ mean) {
    const int node = blockIdx.x * 4 + (threadIdx.x >> 6);
    const int lane = threadIdx.x & 63;
    const int beg = rowstart[node];
    const int n   = deg[node];
    float4 acc0 = make_float4(0.f, 0.f, 0.f, 0.f);
    float4 acc1 = make_float4(0.f, 0.f, 0.f, 0.f);
    int e = 0;
    for (; e + 1 < n; e += 2) {
        int s0 = csr[beg + e];
        int s1 = csr[beg + e + 1];
        float4 v0 = *reinterpret_cast<const float4*>(h + (size_t)s0 * HID + lane * 4);
        float4 v1 = *reinterpret_cast<const float4*>(h + (size_t)s1 * HID + lane * 4);
        acc0.x += v0.x; acc0.y += v0.y; acc0.z += v0.z; acc0.w += v0.w;
        acc1.x += v1.x; acc1.y += v1.y; acc1.z += v1.z; acc1.w += v1.w;
    }
    if (e < n) {
        int s0 = csr[beg + e];
        float4 v0 = *reinterpret_cast<const float4*>(h + (size_t)s0 * HID + lane * 4);
        acc0.x += v0.x; acc0.y += v0.y; acc0.z += v0.z; acc0.w += v0.w;
    }
    const float inv = (n > 0) ? 1.0f / (float)n : 0.0f;
    reinterpret_cast<float4*>(mean + (size_t)node * HID)[lane] =
        make_float4((acc0.x + acc1.x) * inv, (acc0.y + acc1.y) * inv,
                    (acc0.z + acc1.z) * inv, (acc0.w + acc1.w) * inv);
}

// ---------------------------------------------------------------------------
// Layer-1 dense, SGPR-weight-streaming GEMM.
//   h[i,j] = relu( mean1[i,:]·W1l[j,:] + b1[j] + x[i,:]·W1r[j,:] )
// Block = 256 threads = 4 waves. Each wave: 64 rows (lane = row) x 64 cols.
// ---------------------------------------------------------------------------
__global__ __launch_bounds__(256) void sage1_kernel(
    const float* __restrict__ x, const float* __restrict__ mean,
    const float* __restrict__ W1l, const float* __restrict__ W1r,
    const float* __restrict__ b1,
    float* __restrict__ h) {
    const int lane = threadIdx.x & 63;
    const int wid  = threadIdx.x >> 6;        // 0..3 -> column chunk
    const int row  = blockIdx.x * 64 + lane;  // 625*64 == 40000, exact
    const int j0   = wid * 64;

    const float* __restrict__ arow = mean + (size_t)row * IND;
    const float* __restrict__ xrow = x    + (size_t)row * IND;

    float acc[64];
#pragma unroll
    for (int j = 0; j < 64; ++j) acc[j] = b1[j0 + j];

    // ---- part 1: mean1 against W1l ----
#pragma unroll 1
    for (int kc = 0; kc < IND / 8; ++kc) {
        float4 a0 = *reinterpret_cast<const float4*>(arow + kc * 8);
        float4 a1 = *reinterpret_cast<const float4*>(arow + kc * 8 + 4);
        float a[8] = {a0.x, a0.y, a0.z, a0.w, a1.x, a1.y, a1.z, a1.w};
#pragma unroll
        for (int j = 0; j < 64; ++j) {
            const float* w = W1l + (size_t)(j0 + j) * IND + kc * 8;
            float4 w0 = *reinterpret_cast<const float4*>(w);
            float4 w1 = *reinterpret_cast<const float4*>(w + 4);
            acc[j] += a[0] * w0.x + a[1] * w0.y + a[2] * w0.z + a[3] * w0.w
                    + a[4] * w1.x + a[5] * w1.y + a[6] * w1.z + a[7] * w1.w;
        }
    }
    // ---- part 2: x (target) against W1r ----
#pragma unroll 1
    for (int kc = 0; kc < IND / 8; ++kc) {
        float4 a0 = *reinterpret_cast<const float4*>(xrow + kc * 8);
        float4 a1 = *reinterpret_cast<const float4*>(xrow + kc * 8 + 4);
        float a[8] = {a0.x, a0.y, a0.z, a0.w, a1.x, a1.y, a1.z, a1.w};
#pragma unroll
        for (int j = 0; j < 64; ++j) {
            const float* w = W1r + (size_t)(j0 + j) * IND + kc * 8;
            float4 w0 = *reinterpret_cast<const float4*>(w);
            float4 w1 = *reinterpret_cast<const float4*>(w + 4);
            acc[j] += a[0] * w0.x + a[1] * w0.y + a[2] * w0.z + a[3] * w0.w
                    + a[4] * w1.x + a[5] * w1.y + a[6] * w1.z + a[7] * w1.w;
        }
    }

    float4* hp = reinterpret_cast<float4*>(h + (size_t)row * HID + j0);
#pragma unroll
    for (int q = 0; q < 16; ++q) {
        hp[q] = make_float4(fmaxf(acc[4 * q + 0], 0.0f),
                            fmaxf(acc[4 * q + 1], 0.0f),
                            fmaxf(acc[4 * q + 2], 0.0f),
                            fmaxf(acc[4 * q + 3], 0.0f));
    }
}

// ---------------------------------------------------------------------------
// Layer-2 dense + log_softmax, fused. 1 wave per block; lane = row; each lane
// holds its full 64-wide output row in registers -> in-lane log_softmax.
// ---------------------------------------------------------------------------
__global__ __launch_bounds__(64) void sage2_kernel(
    const float* __restrict__ h, const float* __restrict__ mean,
    const float* __restrict__ W2l, const float* __restrict__ W2r,
    const float* __restrict__ b2,
    float* __restrict__ out) {
    const int row = blockIdx.x * 64 + (threadIdx.x & 63);
    if (row >= N3) return;

    const float* __restrict__ arow = mean + (size_t)row * HID;
    const float* __restrict__ hrow = h    + (size_t)row * HID;

    float acc[OUTD];
#pragma unroll
    for (int j = 0; j < OUTD; ++j) acc[j] = b2[j];

    // ---- part 1: mean2 against W2l ----
#pragma unroll 1
    for (int kc = 0; kc < HID / 8; ++kc) {
        float4 a0 = *reinterpret_cast<const float4*>(arow + kc * 8);
        float4 a1 = *reinterpret_cast<const float4*>(arow + kc * 8 + 4);
        float a[8] = {a0.x, a0.y, a0.z, a0.w, a1.x, a1.y, a1.z, a1.w};
#pragma unroll
        for (int j = 0; j < OUTD; ++j) {
            const float* w = W2l + (size_t)j * HID + kc * 8;
            float4 w0 = *reinterpret_cast<const float4*>(w);
            float4 w1 = *reinterpret_cast<const float4*>(w + 4);
            acc[j] += a[0] * w0.x + a[1] * w0.y + a[2] * w0.z + a[3] * w0.w
                    + a[4] * w1.x + a[5] * w1.y + a[6] * w1.z + a[7] * w1.w;
        }
    }
    // ---- part 2: h (target) against W2r ----
#pragma unroll 1
    for (int kc = 0; kc < HID / 8; ++kc) {
        float4 a0 = *reinterpret_cast<const float4*>(hrow + kc * 8);
        float4 a1 = *reinterpret_cast<const float4*>(hrow + kc * 8 + 4);
        float a[8] = {a0.x, a0.y, a0.z, a0.w, a1.x, a1.y, a1.z, a1.w};
#pragma unroll
        for (int j = 0; j < OUTD; ++j) {
            const float* w = W2r + (size_t)j * HID + kc * 8;
            float4 w0 = *reinterpret_cast<const float4*>(w);
            float4 w1 = *reinterpret_cast<const float4*>(w + 4);
            acc[j] += a[0] * w0.x + a[1] * w0.y + a[2] * w0.z + a[3] * w0.w
                    + a[4] * w1.x + a[5] * w1.y + a[6] * w1.z + a[7] * w1.w;
        }
    }

    // ---- in-lane log_softmax over acc[0..63] ----
    float mx = acc[0];
#pragma unroll
    for (int j = 1; j < OUTD; ++j) mx = fmaxf(mx, acc[j]);
    float sum = 0.0f;
#pragma unroll
    for (int j = 0; j < OUTD; ++j) sum += __expf(acc[j] - mx);
    const float lse = mx + __logf(sum);

    float4* op = reinterpret_cast<float4*>(out + (size_t)row * OUTD);
#pragma unroll
    for (int q = 0; q < OUTD / 4; ++q) {
        op[q] = make_float4(acc[4 * q + 0] - lse, acc[4 * q + 1] - lse,
                            acc[4 * q + 2] - lse, acc[4 * q + 3] - lse);
    }
}

// ---------------------------------------------------------------------------
extern "C" void kernel_launch(void* const* d_in, const int* in_sizes, int n_in,
                              void* d_out, int out_size, void* d_ws, size_t ws_size,
                              hipStream_t stream) {
    const float* x    = (const float*)d_in[0];
    const int*   src1 = (const int*)d_in[1];
    const int*   dst1 = (const int*)d_in[2];
    const int*   src2 = (const int*)d_in[3];
    const int*   dst2 = (const int*)d_in[4];
    const float* W1l  = (const float*)d_in[7];
    const float* W1r  = (const float*)d_in[8];
    const float* b1   = (const float*)d_in[9];
    const float* W2l  = (const float*)d_in[10];
    const float* W2r  = (const float*)d_in[11];
    const float* b2   = (const float*)d_in[12];
    float* out = (float*)d_out;

    const int E1 = in_sizes[1];
    const int E2 = in_sizes[3];

    // Workspace layout (bytes). mean2 aliases mean1 (dead after sage1).
    //   mean1/mean2 : 0            (20,480,000)
    //   h           : 20,480,000   (40,960,000)
    //   csr1        : 61,440,000   ( 2,560,000)
    //   csr2        : 64,000,000   (   640,000)
    //   deg1        : 64,640,000   (   160,000)
    //   rowstart1   : 64,800,000   (   160,000)
    //   cursor1     : 64,960,000   (   160,000)
    //   deg2        : 65,120,000   (    40,000)
    //   rowstart2   : 65,160,000   (    40,000)
    //   cursor2     : 65,200,000   (    40,000)   total 65,240,000 B
    char* ws = (char*)d_ws;
    float* mean1     = (float*)(ws + 0);
    float* mean2     = (float*)(ws + 0);
    float* h         = (float*)(ws + 20480000);
    int*   csr1      = (int*)(ws + 61440000);
    int*   csr2      = (int*)(ws + 64000000);
    int*   deg1      = (int*)(ws + 64640000);
    int*   rowstart1 = (int*)(ws + 64800000);
    int*   cursor1   = (int*)(ws + 64960000);
    int*   deg2      = (int*)(ws + 65120000);
    int*   rowstart2 = (int*)(ws + 65160000);
    int*   cursor2   = (int*)(ws + 65200000);

    hipMemsetAsync(deg1, 0, (size_t)N2 * sizeof(int), stream);
    hipMemsetAsync(cursor1, 0, (size_t)N2 * sizeof(int), stream);
    hipMemsetAsync(deg2, 0, (size_t)N3 * sizeof(int), stream);
    hipMemsetAsync(cursor2, 0, (size_t)N3 * sizeof(int), stream);

    // ---- layer 1: CSR build + gather-mean + dense ----
    hist_kernel<<<(E1 + 255) / 256, 256, 0, stream>>>(dst1, E1, deg1);
    scan_kernel<<<1, 1024, 0, stream>>>(deg1, N2, rowstart1);
    fill_kernel<<<(E1 + 255) / 256, 256, 0, stream>>>(src1, dst1, E1,
                                                      rowstart1, cursor1, csr1);
    gather1_kernel<<<N2 / 4, 256, 0, stream>>>(x, csr1, rowstart1, deg1, mean1);
    sage1_kernel<<<N2 / 64, 256, 0, stream>>>(x, mean1, W1l, W1r, b1, h);

    // ---- layer 2: CSR build + gather-mean + dense+logsoftmax ----
    hist_kernel<<<(E2 + 255) / 256, 256, 0, stream>>>(dst2, E2, deg2);
    scan_kernel<<<1, 1024, 0, stream>>>(deg2, N3, rowstart2);
    fill_kernel<<<(E2 + 255) / 256, 256, 0, stream>>>(src2, dst2, E2,
                                                      rowstart2, cursor2, csr2);
    gather2_kernel<<<N3 / 4, 256, 0, stream>>>(h, csr2, rowstart2, deg2, mean2);
    sage2_kernel<<<(N3 + 63) / 64, 64, 0, stream>>>(h, mean2, W2l, W2r, b2, out);
}

// Round 4
// 690.782 us; speedup vs baseline: 4.2941x; 1.4142x over previous
//
#include <hip/hip_runtime.h>

// Problem constants (fixed by the reference)
static constexpr int N1  = 200000;
static constexpr int N2  = 40000;
static constexpr int N3  = 10000;
static constexpr int IND = 128;
static constexpr int HID = 256;
static constexpr int OUTD = 64;

// ---------------------------------------------------------------------------
// CSR construction: degree histogram -> exclusive scan -> bucket fill.
// ---------------------------------------------------------------------------
__global__ void hist_kernel(const int* __restrict__ dst, int E,
                            int* __restrict__ deg) {
    int i = blockIdx.x * blockDim.x + threadIdx.x;
    if (i < E) atomicAdd(&deg[dst[i]], 1);
}

__global__ __launch_bounds__(1024) void scan_kernel(
    const int* __restrict__ deg, int n, int* __restrict__ rowstart) {
    __shared__ int part[1024];
    const int T = 1024, t = threadIdx.x;
    const int per = (n + T - 1) / T;
    const int beg = t * per;
    const int end = min(beg + per, n);
    int s = 0;
    for (int i = beg; i < end; ++i) s += deg[i];
    part[t] = s;
    __syncthreads();
    for (int off = 1; off < T; off <<= 1) {
        int v = (t >= off) ? part[t - off] : 0;
        __syncthreads();
        part[t] += v;
        __syncthreads();
    }
    int run = (t == 0) ? 0 : part[t - 1];   // exclusive prefix of this chunk
    for (int i = beg; i < end; ++i) { rowstart[i] = run; run += deg[i]; }
}

__global__ void fill_kernel(const int* __restrict__ src,
                            const int* __restrict__ dst, int E,
                            const int* __restrict__ rowstart,
                            int* __restrict__ cursor,
                            int* __restrict__ csr) {
    int i = blockIdx.x * blockDim.x + threadIdx.x;
    if (i < E) {
        int d = dst[i];
        int p = atomicAdd(&cursor[d], 1);
        csr[rowstart[d] + p] = src[i];
    }
}

// ---------------------------------------------------------------------------
// Gather-mean layer 1: mean1[node,:] = mean over edges of x[src,:]  (128 f32)
// ---------------------------------------------------------------------------
__global__ __launch_bounds__(256) void gather1_kernel(
    const float* __restrict__ x, const int* __restrict__ csr,
    const int* __restrict__ rowstart, const int* __restrict__ deg,
    float* __restrict__ mean) {
    const int node = blockIdx.x * 4 + (threadIdx.x >> 6);
    const int lane = threadIdx.x & 63;
    const int beg = rowstart[node];
    const int n   = deg[node];
    float2 acc0 = make_float2(0.f, 0.f), acc1 = make_float2(0.f, 0.f);
    int e = 0;
    for (; e + 1 < n; e += 2) {
        int s0 = csr[beg + e];
        int s1 = csr[beg + e + 1];
        float2 v0 = *reinterpret_cast<const float2*>(x + (size_t)s0 * IND + lane * 2);
        float2 v1 = *reinterpret_cast<const float2*>(x + (size_t)s1 * IND + lane * 2);
        acc0.x += v0.x; acc0.y += v0.y;
        acc1.x += v1.x; acc1.y += v1.y;
    }
    if (e < n) {
        int s0 = csr[beg + e];
        float2 v0 = *reinterpret_cast<const float2*>(x + (size_t)s0 * IND + lane * 2);
        acc0.x += v0.x; acc0.y += v0.y;
    }
    const float inv = (n > 0) ? 1.0f / (float)n : 0.0f;
    reinterpret_cast<float2*>(mean + (size_t)node * IND)[lane] =
        make_float2((acc0.x + acc1.x) * inv, (acc0.y + acc1.y) * inv);
}

// ---------------------------------------------------------------------------
// Gather-mean layer 2: mean2[node,:] = mean over edges of h[src,:]  (256 f32)
// ---------------------------------------------------------------------------
__global__ __launch_bounds__(256) void gather2_kernel(
    const float* __restrict__ h, const int* __restrict__ csr,
    const int* __restrict__ rowstart, const int* __restrict__ deg,
    float* __restrict__ mean) {
    const int node = blockIdx.x * 4 + (threadIdx.x >> 6);
    const int lane = threadIdx.x & 63;
    const int beg = rowstart[node];
    const int n   = deg[node];
    float4 acc0 = make_float4(0.f, 0.f, 0.f, 0.f);
    float4 acc1 = make_float4(0.f, 0.f, 0.f, 0.f);
    int e = 0;
    for (; e + 1 < n; e += 2) {
        int s0 = csr[beg + e];
        int s1 = csr[beg + e + 1];
        float4 v0 = *reinterpret_cast<const float4*>(h + (size_t)s0 * HID + lane * 4);
        float4 v1 = *reinterpret_cast<const float4*>(h + (size_t)s1 * HID + lane * 4);
        acc0.x += v0.x; acc0.y += v0.y; acc0.z += v0.z; acc0.w += v0.w;
        acc1.x += v1.x; acc1.y += v1.y; acc1.z += v1.z; acc1.w += v1.w;
    }
    if (e < n) {
        int s0 = csr[beg + e];
        float4 v0 = *reinterpret_cast<const float4*>(h + (size_t)s0 * HID + lane * 4);
        acc0.x += v0.x; acc0.y += v0.y; acc0.z += v0.z; acc0.w += v0.w;
    }
    const float inv = (n > 0) ? 1.0f / (float)n : 0.0f;
    reinterpret_cast<float4*>(mean + (size_t)node * HID)[lane] =
        make_float4((acc0.x + acc1.x) * inv, (acc0.y + acc1.y) * inv,
                    (acc0.z + acc1.z) * inv, (acc0.w + acc1.w) * inv);
}

// ---------------------------------------------------------------------------
// Layer-1 dense, SGPR-weight-streaming GEMM (unchanged from R2).
// ---------------------------------------------------------------------------
__global__ __launch_bounds__(256) void sage1_kernel(
    const float* __restrict__ x, const float* __restrict__ mean,
    const float* __restrict__ W1l, const float* __restrict__ W1r,
    const float* __restrict__ b1,
    float* __restrict__ h) {
    const int lane = threadIdx.x & 63;
    const int wid  = threadIdx.x >> 6;        // 0..3 -> column chunk
    const int row  = blockIdx.x * 64 + lane;  // 625*64 == 40000, exact
    const int j0   = wid * 64;

    const float* __restrict__ arow = mean + (size_t)row * IND;
    const float* __restrict__ xrow = x    + (size_t)row * IND;

    float acc[64];
#pragma unroll
    for (int j = 0; j < 64; ++j) acc[j] = b1[j0 + j];

#pragma unroll 1
    for (int kc = 0; kc < IND / 8; ++kc) {
        float4 a0 = *reinterpret_cast<const float4*>(arow + kc * 8);
        float4 a1 = *reinterpret_cast<const float4*>(arow + kc * 8 + 4);
        float a[8] = {a0.x, a0.y, a0.z, a0.w, a1.x, a1.y, a1.z, a1.w};
#pragma unroll
        for (int j = 0; j < 64; ++j) {
            const float* w = W1l + (size_t)(j0 + j) * IND + kc * 8;
            float4 w0 = *reinterpret_cast<const float4*>(w);
            float4 w1 = *reinterpret_cast<const float4*>(w + 4);
            acc[j] += a[0] * w0.x + a[1] * w0.y + a[2] * w0.z + a[3] * w0.w
                    + a[4] * w1.x + a[5] * w1.y + a[6] * w1.z + a[7] * w1.w;
        }
    }
#pragma unroll 1
    for (int kc = 0; kc < IND / 8; ++kc) {
        float4 a0 = *reinterpret_cast<const float4*>(xrow + kc * 8);
        float4 a1 = *reinterpret_cast<const float4*>(xrow + kc * 8 + 4);
        float a[8] = {a0.x, a0.y, a0.z, a0.w, a1.x, a1.y, a1.z, a1.w};
#pragma unroll
        for (int j = 0; j < 64; ++j) {
            const float* w = W1r + (size_t)(j0 + j) * IND + kc * 8;
            float4 w0 = *reinterpret_cast<const float4*>(w);
            float4 w1 = *reinterpret_cast<const float4*>(w + 4);
            acc[j] += a[0] * w0.x + a[1] * w0.y + a[2] * w0.z + a[3] * w0.w
                    + a[4] * w1.x + a[5] * w1.y + a[6] * w1.z + a[7] * w1.w;
        }
    }

    float4* hp = reinterpret_cast<float4*>(h + (size_t)row * HID + j0);
#pragma unroll
    for (int q = 0; q < 16; ++q) {
        hp[q] = make_float4(fmaxf(acc[4 * q + 0], 0.0f),
                            fmaxf(acc[4 * q + 1], 0.0f),
                            fmaxf(acc[4 * q + 2], 0.0f),
                            fmaxf(acc[4 * q + 3], 0.0f));
    }
}

// ---------------------------------------------------------------------------
// Weight transpose for layer 2: Wt[k][j] (k<256: W2l, else W2r), j contiguous.
// ---------------------------------------------------------------------------
__global__ void w2t_kernel(const float* __restrict__ W2l,
                           const float* __restrict__ W2r,
                           float* __restrict__ Wt) {
    int i = blockIdx.x * blockDim.x + threadIdx.x;   // over 512*64
    if (i >= 2 * HID * OUTD) return;
    int k = i >> 6, j = i & 63;
    Wt[i] = (k < HID) ? W2l[(size_t)j * HID + k]
                      : W2r[(size_t)j * HID + (k - HID)];
}

// ---------------------------------------------------------------------------
// Layer-2 dense + log_softmax, high-occupancy version.
// Block = 256 threads; 32 rows/block; 8 threads per row, 8 cols per thread.
// Weight reads hit the same Wt[k][0:64] line across the wave (broadcast).
// log_softmax reduces across the 8 lanes of a row group via shfl_xor.
// ---------------------------------------------------------------------------
__global__ __launch_bounds__(256) void sage2_kernel(
    const float* __restrict__ h, const float* __restrict__ mean,
    const float* __restrict__ Wt, const float* __restrict__ b2,
    float* __restrict__ out) {
    const int t   = threadIdx.x;
    const int row = blockIdx.x * 32 + (t >> 3);
    const int jc  = (t & 7) * 8;
    if (row >= N3) return;

    float acc[8];
#pragma unroll
    for (int c = 0; c < 8; ++c) acc[c] = b2[jc + c];

    const float* __restrict__ arow = mean + (size_t)row * HID;
    const float* __restrict__ hrow = h    + (size_t)row * HID;

#pragma unroll 1
    for (int half = 0; half < 2; ++half) {
        const float* __restrict__ a = half ? hrow : arow;
        const float* __restrict__ w = Wt + (size_t)half * HID * OUTD + jc;
#pragma unroll 2
        for (int kc = 0; kc < HID / 4; ++kc) {
            float4 av = reinterpret_cast<const float4*>(a)[kc];
            const float* wk = w + (size_t)kc * 4 * OUTD;
            float ak[4] = {av.x, av.y, av.z, av.w};
#pragma unroll
            for (int kk = 0; kk < 4; ++kk) {
                float4 wa = *reinterpret_cast<const float4*>(wk + kk * OUTD);
                float4 wb = *reinterpret_cast<const float4*>(wk + kk * OUTD + 4);
                acc[0] += ak[kk] * wa.x; acc[1] += ak[kk] * wa.y;
                acc[2] += ak[kk] * wa.z; acc[3] += ak[kk] * wa.w;
                acc[4] += ak[kk] * wb.x; acc[5] += ak[kk] * wb.y;
                acc[6] += ak[kk] * wb.z; acc[7] += ak[kk] * wb.w;
            }
        }
    }

    // ---- log_softmax across the 8 lanes sharing this row ----
    float mx = acc[0];
#pragma unroll
    for (int c = 1; c < 8; ++c) mx = fmaxf(mx, acc[c]);
#pragma unroll
    for (int o = 1; o <= 4; o <<= 1) mx = fmaxf(mx, __shfl_xor(mx, o));
    float sum = 0.0f;
#pragma unroll
    for (int c = 0; c < 8; ++c) sum += __expf(acc[c] - mx);
#pragma unroll
    for (int o = 1; o <= 4; o <<= 1) sum += __shfl_xor(sum, o);
    const float lse = mx + __logf(sum);

    float4* op = reinterpret_cast<float4*>(out + (size_t)row * OUTD + jc);
    op[0] = make_float4(acc[0] - lse, acc[1] - lse, acc[2] - lse, acc[3] - lse);
    op[1] = make_float4(acc[4] - lse, acc[5] - lse, acc[6] - lse, acc[7] - lse);
}

// ---------------------------------------------------------------------------
extern "C" void kernel_launch(void* const* d_in, const int* in_sizes, int n_in,
                              void* d_out, int out_size, void* d_ws, size_t ws_size,
                              hipStream_t stream) {
    const float* x    = (const float*)d_in[0];
    const int*   src1 = (const int*)d_in[1];
    const int*   dst1 = (const int*)d_in[2];
    const int*   src2 = (const int*)d_in[3];
    const int*   dst2 = (const int*)d_in[4];
    const float* W1l  = (const float*)d_in[7];
    const float* W1r  = (const float*)d_in[8];
    const float* b1   = (const float*)d_in[9];
    const float* W2l  = (const float*)d_in[10];
    const float* W2r  = (const float*)d_in[11];
    const float* b2   = (const float*)d_in[12];
    float* out = (float*)d_out;

    const int E1 = in_sizes[1];
    const int E2 = in_sizes[3];

    // Workspace layout (bytes). mean2 aliases mean1 (dead after sage1).
    char* ws = (char*)d_ws;
    float* mean1     = (float*)(ws + 0);          // 20,480,000
    float* mean2     = (float*)(ws + 0);
    float* h         = (float*)(ws + 20480000);   // 40,960,000
    int*   csr1      = (int*)(ws + 61440000);     //  2,560,000
    int*   csr2      = (int*)(ws + 64000000);     //    640,000
    int*   deg1      = (int*)(ws + 64640000);     //    160,000
    int*   rowstart1 = (int*)(ws + 64800000);     //    160,000
    int*   cursor1   = (int*)(ws + 64960000);     //    160,000
    int*   deg2      = (int*)(ws + 65120000);     //     40,000
    int*   rowstart2 = (int*)(ws + 65160000);     //     40,000
    int*   cursor2   = (int*)(ws + 65200000);     //     40,000
    float* Wt        = (float*)(ws + 65240000);   //    131,072  (end 65,371,072)

    hipMemsetAsync(deg1, 0, (size_t)N2 * sizeof(int), stream);
    hipMemsetAsync(cursor1, 0, (size_t)N2 * sizeof(int), stream);
    hipMemsetAsync(deg2, 0, (size_t)N3 * sizeof(int), stream);
    hipMemsetAsync(cursor2, 0, (size_t)N3 * sizeof(int), stream);

    w2t_kernel<<<(2 * HID * OUTD + 255) / 256, 256, 0, stream>>>(W2l, W2r, Wt);

    // ---- layer 1: CSR build + gather-mean + dense ----
    hist_kernel<<<(E1 + 255) / 256, 256, 0, stream>>>(dst1, E1, deg1);
    scan_kernel<<<1, 1024, 0, stream>>>(deg1, N2, rowstart1);
    fill_kernel<<<(E1 + 255) / 256, 256, 0, stream>>>(src1, dst1, E1,
                                                      rowstart1, cursor1, csr1);
    gather1_kernel<<<N2 / 4, 256, 0, stream>>>(x, csr1, rowstart1, deg1, mean1);
    sage1_kernel<<<N2 / 64, 256, 0, stream>>>(x, mean1, W1l, W1r, b1, h);

    // ---- layer 2: CSR build + gather-mean + dense+logsoftmax ----
    hist_kernel<<<(E2 + 255) / 256, 256, 0, stream>>>(dst2, E2, deg2);
    scan_kernel<<<1, 1024, 0, stream>>>(deg2, N3, rowstart2);
    fill_kernel<<<(E2 + 255) / 256, 256, 0, stream>>>(src2, dst2, E2,
                                                      rowstart2, cursor2, csr2);
    gather2_kernel<<<N3 / 4, 256, 0, stream>>>(h, csr2, rowstart2, deg2, mean2);
    sage2_kernel<<<(N3 + 31) / 32, 256, 0, stream>>>(h, mean2, Wt, b2, out);
}

// Round 5
// 468.179 us; speedup vs baseline: 6.3358x; 1.4755x over previous
//
#include <hip/hip_runtime.h>

// Problem constants (fixed by the reference)
static constexpr int N1  = 200000;
static constexpr int N2  = 40000;
static constexpr int N3  = 10000;
static constexpr int IND = 128;
static constexpr int HID = 256;
static constexpr int OUTD = 64;

// ---------------------------------------------------------------------------
// CSR construction: degree histogram -> exclusive scan -> bucket fill.
// ---------------------------------------------------------------------------
__global__ void hist_kernel(const int* __restrict__ dst, int E,
                            int* __restrict__ deg) {
    int i = blockIdx.x * blockDim.x + threadIdx.x;
    if (i < E) atomicAdd(&deg[dst[i]], 1);
}

__global__ __launch_bounds__(1024) void scan_kernel(
    const int* __restrict__ deg, int n, int* __restrict__ rowstart) {
    __shared__ int part[1024];
    const int T = 1024, t = threadIdx.x;
    const int per = (n + T - 1) / T;
    const int beg = t * per;
    const int end = min(beg + per, n);
    int s = 0;
    for (int i = beg; i < end; ++i) s += deg[i];
    part[t] = s;
    __syncthreads();
    for (int off = 1; off < T; off <<= 1) {
        int v = (t >= off) ? part[t - off] : 0;
        __syncthreads();
        part[t] += v;
        __syncthreads();
    }
    int run = (t == 0) ? 0 : part[t - 1];   // exclusive prefix of this chunk
    for (int i = beg; i < end; ++i) { rowstart[i] = run; run += deg[i]; }
}

__global__ void fill_kernel(const int* __restrict__ src,
                            const int* __restrict__ dst, int E,
                            const int* __restrict__ rowstart,
                            int* __restrict__ cursor,
                            int* __restrict__ csr) {
    int i = blockIdx.x * blockDim.x + threadIdx.x;
    if (i < E) {
        int d = dst[i];
        int p = atomicAdd(&cursor[d], 1);
        csr[rowstart[d] + p] = src[i];
    }
}

// ---------------------------------------------------------------------------
// Gather-mean layer 1: mean1[node,:] = mean over edges of x[src,:]  (128 f32)
// ---------------------------------------------------------------------------
__global__ __launch_bounds__(256) void gather1_kernel(
    const float* __restrict__ x, const int* __restrict__ csr,
    const int* __restrict__ rowstart, const int* __restrict__ deg,
    float* __restrict__ mean) {
    const int node = blockIdx.x * 4 + (threadIdx.x >> 6);
    const int lane = threadIdx.x & 63;
    const int beg = rowstart[node];
    const int n   = deg[node];
    float2 acc0 = make_float2(0.f, 0.f), acc1 = make_float2(0.f, 0.f);
    int e = 0;
    for (; e + 1 < n; e += 2) {
        int s0 = csr[beg + e];
        int s1 = csr[beg + e + 1];
        float2 v0 = *reinterpret_cast<const float2*>(x + (size_t)s0 * IND + lane * 2);
        float2 v1 = *reinterpret_cast<const float2*>(x + (size_t)s1 * IND + lane * 2);
        acc0.x += v0.x; acc0.y += v0.y;
        acc1.x += v1.x; acc1.y += v1.y;
    }
    if (e < n) {
        int s0 = csr[beg + e];
        float2 v0 = *reinterpret_cast<const float2*>(x + (size_t)s0 * IND + lane * 2);
        acc0.x += v0.x; acc0.y += v0.y;
    }
    const float inv = (n > 0) ? 1.0f / (float)n : 0.0f;
    reinterpret_cast<float2*>(mean + (size_t)node * IND)[lane] =
        make_float2((acc0.x + acc1.x) * inv, (acc0.y + acc1.y) * inv);
}

// ---------------------------------------------------------------------------
// Gather-mean layer 2: mean2[node,:] = mean over edges of h[src,:]  (256 f32)
// ---------------------------------------------------------------------------
__global__ __launch_bounds__(256) void gather2_kernel(
    const float* __restrict__ h, const int* __restrict__ csr,
    const int* __restrict__ rowstart, const int* __restrict__ deg,
    float* __restrict__ mean) {
    const int node = blockIdx.x * 4 + (threadIdx.x >> 6);
    const int lane = threadIdx.x & 63;
    const int beg = rowstart[node];
    const int n   = deg[node];
    float4 acc0 = make_float4(0.f, 0.f, 0.f, 0.f);
    float4 acc1 = make_float4(0.f, 0.f, 0.f, 0.f);
    int e = 0;
    for (; e + 1 < n; e += 2) {
        int s0 = csr[beg + e];
        int s1 = csr[beg + e + 1];
        float4 v0 = *reinterpret_cast<const float4*>(h + (size_t)s0 * HID + lane * 4);
        float4 v1 = *reinterpret_cast<const float4*>(h + (size_t)s1 * HID + lane * 4);
        acc0.x += v0.x; acc0.y += v0.y; acc0.z += v0.z; acc0.w += v0.w;
        acc1.x += v1.x; acc1.y += v1.y; acc1.z += v1.z; acc1.w += v1.w;
    }
    if (e < n) {
        int s0 = csr[beg + e];
        float4 v0 = *reinterpret_cast<const float4*>(h + (size_t)s0 * HID + lane * 4);
        acc0.x += v0.x; acc0.y += v0.y; acc0.z += v0.z; acc0.w += v0.w;
    }
    const float inv = (n > 0) ? 1.0f / (float)n : 0.0f;
    reinterpret_cast<float4*>(mean + (size_t)node * HID)[lane] =
        make_float4((acc0.x + acc1.x) * inv, (acc0.y + acc1.y) * inv,
                    (acc0.z + acc1.z) * inv, (acc0.w + acc1.w) * inv);
}

// ---------------------------------------------------------------------------
// Weight transpose layer 1: Wt1[k][j], k-major. k<128 -> W1l[j][k],
// k>=128 -> W1r[j][k-128]. j contiguous (256 cols).
// ---------------------------------------------------------------------------
__global__ void w1t_kernel(const float* __restrict__ W1l,
                           const float* __restrict__ W1r,
                           float* __restrict__ Wt) {
    int i = blockIdx.x * blockDim.x + threadIdx.x;   // over 256*256
    if (i >= 2 * IND * HID) return;
    int k = i >> 8, j = i & 255;
    Wt[i] = (k < IND) ? W1l[(size_t)j * IND + k]
                      : W1r[(size_t)j * IND + (k - IND)];
}

// ---------------------------------------------------------------------------
// Layer-1 dense, register-blocked outer-product GEMM.
//   h = relu([mean1 | x] @ Wt1 + b1),  Wt1 k-major [256][256].
// Block = 256 thr = 4 waves (2x2); block tile 128 rows x 128 cols;
// lane tile 8x8. Per k: 8 A scalar loads + 2 W float4 loads + 64 FMA.
// ---------------------------------------------------------------------------
__global__ __launch_bounds__(256) void sage1_kernel(
    const float* __restrict__ x, const float* __restrict__ mean,
    const float* __restrict__ Wt, const float* __restrict__ b1,
    float* __restrict__ h) {
    const int t    = threadIdx.x;
    const int wave = t >> 6;
    const int lane = t & 63;
    const int wr   = (wave >> 1) << 6;       // 0 or 64
    const int wc   = (wave & 1) << 6;        // 0 or 64
    const int lr   = (lane >> 3) << 3;       // 0..56
    const int lc   = (lane & 7) << 3;        // 0..56
    const int row0 = blockIdx.x * 128 + wr + lr;
    const int col0 = blockIdx.y * 128 + wc + lc;

    // clamp rows so loads stay in-bounds (stores are guarded)
    int rows[8];
#pragma unroll
    for (int r = 0; r < 8; ++r) rows[r] = min(row0 + r, N2 - 1);

    float acc[8][8];
#pragma unroll
    for (int r = 0; r < 8; ++r)
#pragma unroll
        for (int c = 0; c < 8; ++c) acc[r][c] = 0.0f;

#pragma unroll 1
    for (int half = 0; half < 2; ++half) {
        const float* __restrict__ A = half ? x : mean;
        const float* __restrict__ W = Wt + (size_t)half * IND * HID;
#pragma unroll 2
        for (int k = 0; k < IND; ++k) {
            float a[8];
#pragma unroll
            for (int r = 0; r < 8; ++r)
                a[r] = A[(size_t)rows[r] * IND + k];
            const float* wk = W + (size_t)k * HID + col0;
            float4 w0 = *reinterpret_cast<const float4*>(wk);
            float4 w1 = *reinterpret_cast<const float4*>(wk + 4);
            float w[8] = {w0.x, w0.y, w0.z, w0.w, w1.x, w1.y, w1.z, w1.w};
#pragma unroll
            for (int r = 0; r < 8; ++r)
#pragma unroll
                for (int c = 0; c < 8; ++c)
                    acc[r][c] += a[r] * w[c];
        }
    }

    float bb[8];
#pragma unroll
    for (int c = 0; c < 8; ++c) bb[c] = b1[col0 + c];

#pragma unroll
    for (int r = 0; r < 8; ++r) {
        int row = row0 + r;
        if (row < N2) {
            float4* hp = reinterpret_cast<float4*>(h + (size_t)row * HID + col0);
            hp[0] = make_float4(fmaxf(acc[r][0] + bb[0], 0.0f),
                                fmaxf(acc[r][1] + bb[1], 0.0f),
                                fmaxf(acc[r][2] + bb[2], 0.0f),
                                fmaxf(acc[r][3] + bb[3], 0.0f));
            hp[1] = make_float4(fmaxf(acc[r][4] + bb[4], 0.0f),
                                fmaxf(acc[r][5] + bb[5], 0.0f),
                                fmaxf(acc[r][6] + bb[6], 0.0f),
                                fmaxf(acc[r][7] + bb[7], 0.0f));
        }
    }
}

// ---------------------------------------------------------------------------
// Weight transpose for layer 2: Wt[k][j] (k<256: W2l, else W2r), j contiguous.
// ---------------------------------------------------------------------------
__global__ void w2t_kernel(const float* __restrict__ W2l,
                           const float* __restrict__ W2r,
                           float* __restrict__ Wt) {
    int i = blockIdx.x * blockDim.x + threadIdx.x;   // over 512*64
    if (i >= 2 * HID * OUTD) return;
    int k = i >> 6, j = i & 63;
    Wt[i] = (k < HID) ? W2l[(size_t)j * HID + k]
                      : W2r[(size_t)j * HID + (k - HID)];
}

// ---------------------------------------------------------------------------
// Layer-2 dense + log_softmax (from R3).
// Block = 256 threads; 32 rows/block; 8 threads per row, 8 cols per thread.
// ---------------------------------------------------------------------------
__global__ __launch_bounds__(256) void sage2_kernel(
    const float* __restrict__ h, const float* __restrict__ mean,
    const float* __restrict__ Wt, const float* __restrict__ b2,
    float* __restrict__ out) {
    const int t   = threadIdx.x;
    const int row = blockIdx.x * 32 + (t >> 3);
    const int jc  = (t & 7) * 8;
    if (row >= N3) return;

    float acc[8];
#pragma unroll
    for (int c = 0; c < 8; ++c) acc[c] = b2[jc + c];

    const float* __restrict__ arow = mean + (size_t)row * HID;
    const float* __restrict__ hrow = h    + (size_t)row * HID;

#pragma unroll 1
    for (int half = 0; half < 2; ++half) {
        const float* __restrict__ a = half ? hrow : arow;
        const float* __restrict__ w = Wt + (size_t)half * HID * OUTD + jc;
#pragma unroll 2
        for (int kc = 0; kc < HID / 4; ++kc) {
            float4 av = reinterpret_cast<const float4*>(a)[kc];
            const float* wk = w + (size_t)kc * 4 * OUTD;
            float ak[4] = {av.x, av.y, av.z, av.w};
#pragma unroll
            for (int kk = 0; kk < 4; ++kk) {
                float4 wa = *reinterpret_cast<const float4*>(wk + kk * OUTD);
                float4 wb = *reinterpret_cast<const float4*>(wk + kk * OUTD + 4);
                acc[0] += ak[kk] * wa.x; acc[1] += ak[kk] * wa.y;
                acc[2] += ak[kk] * wa.z; acc[3] += ak[kk] * wa.w;
                acc[4] += ak[kk] * wb.x; acc[5] += ak[kk] * wb.y;
                acc[6] += ak[kk] * wb.z; acc[7] += ak[kk] * wb.w;
            }
        }
    }

    // ---- log_softmax across the 8 lanes sharing this row ----
    float mx = acc[0];
#pragma unroll
    for (int c = 1; c < 8; ++c) mx = fmaxf(mx, acc[c]);
#pragma unroll
    for (int o = 1; o <= 4; o <<= 1) mx = fmaxf(mx, __shfl_xor(mx, o));
    float sum = 0.0f;
#pragma unroll
    for (int c = 0; c < 8; ++c) sum += __expf(acc[c] - mx);
#pragma unroll
    for (int o = 1; o <= 4; o <<= 1) sum += __shfl_xor(sum, o);
    const float lse = mx + __logf(sum);

    float4* op = reinterpret_cast<float4*>(out + (size_t)row * OUTD + jc);
    op[0] = make_float4(acc[0] - lse, acc[1] - lse, acc[2] - lse, acc[3] - lse);
    op[1] = make_float4(acc[4] - lse, acc[5] - lse, acc[6] - lse, acc[7] - lse);
}

// ---------------------------------------------------------------------------
extern "C" void kernel_launch(void* const* d_in, const int* in_sizes, int n_in,
                              void* d_out, int out_size, void* d_ws, size_t ws_size,
                              hipStream_t stream) {
    const float* x    = (const float*)d_in[0];
    const int*   src1 = (const int*)d_in[1];
    const int*   dst1 = (const int*)d_in[2];
    const int*   src2 = (const int*)d_in[3];
    const int*   dst2 = (const int*)d_in[4];
    const float* W1l  = (const float*)d_in[7];
    const float* W1r  = (const float*)d_in[8];
    const float* b1   = (const float*)d_in[9];
    const float* W2l  = (const float*)d_in[10];
    const float* W2r  = (const float*)d_in[11];
    const float* b2   = (const float*)d_in[12];
    float* out = (float*)d_out;

    const int E1 = in_sizes[1];
    const int E2 = in_sizes[3];

    // Workspace layout (bytes). mean2 aliases mean1 (dead after sage1).
    // Wt1 aliases csr2: Wt1 is dead after sage1; csr2 is built after sage1.
    char* ws = (char*)d_ws;
    float* mean1     = (float*)(ws + 0);          // 20,480,000
    float* mean2     = (float*)(ws + 0);
    float* h         = (float*)(ws + 20480000);   // 40,960,000
    int*   csr1      = (int*)(ws + 61440000);     //  2,560,000
    int*   csr2      = (int*)(ws + 64000000);     //    640,000 (also Wt1: 262,144)
    float* Wt1       = (float*)(ws + 64000000);
    int*   deg1      = (int*)(ws + 64640000);     //    160,000
    int*   rowstart1 = (int*)(ws + 64800000);     //    160,000
    int*   cursor1   = (int*)(ws + 64960000);     //    160,000
    int*   deg2      = (int*)(ws + 65120000);     //     40,000
    int*   rowstart2 = (int*)(ws + 65160000);     //     40,000
    int*   cursor2   = (int*)(ws + 65200000);     //     40,000
    float* Wt2       = (float*)(ws + 65240000);   //    131,072  (end 65,371,072)

    hipMemsetAsync(deg1, 0, (size_t)N2 * sizeof(int), stream);
    hipMemsetAsync(cursor1, 0, (size_t)N2 * sizeof(int), stream);
    hipMemsetAsync(deg2, 0, (size_t)N3 * sizeof(int), stream);
    hipMemsetAsync(cursor2, 0, (size_t)N3 * sizeof(int), stream);

    w2t_kernel<<<(2 * HID * OUTD + 255) / 256, 256, 0, stream>>>(W2l, W2r, Wt2);
    w1t_kernel<<<(2 * IND * HID + 255) / 256, 256, 0, stream>>>(W1l, W1r, Wt1);

    // ---- layer 1: CSR build + gather-mean + dense ----
    hist_kernel<<<(E1 + 255) / 256, 256, 0, stream>>>(dst1, E1, deg1);
    scan_kernel<<<1, 1024, 0, stream>>>(deg1, N2, rowstart1);
    fill_kernel<<<(E1 + 255) / 256, 256, 0, stream>>>(src1, dst1, E1,
                                                      rowstart1, cursor1, csr1);
    gather1_kernel<<<N2 / 4, 256, 0, stream>>>(x, csr1, rowstart1, deg1, mean1);
    {
        dim3 grid((N2 + 127) / 128, HID / 128);
        sage1_kernel<<<grid, 256, 0, stream>>>(x, mean1, Wt1, b1, h);
    }

    // ---- layer 2 (CSR build AFTER sage1: csr2 overwrites Wt1) ----
    hist_kernel<<<(E2 + 255) / 256, 256, 0, stream>>>(dst2, E2, deg2);
    scan_kernel<<<1, 1024, 0, stream>>>(deg2, N3, rowstart2);
    fill_kernel<<<(E2 + 255) / 256, 256, 0, stream>>>(src2, dst2, E2,
                                                      rowstart2, cursor2, csr2);
    gather2_kernel<<<N3 / 4, 256, 0, stream>>>(h, csr2, rowstart2, deg2, mean2);
    sage2_kernel<<<(N3 + 31) / 32, 256, 0, stream>>>(h, mean2, Wt2, b2, out);
}

// Round 6
// 464.128 us; speedup vs baseline: 6.3911x; 1.0087x over previous
//
#include <hip/hip_runtime.h>

// Problem constants (fixed by the reference)
static constexpr int N1  = 200000;
static constexpr int N2  = 40000;
static constexpr int N3  = 10000;
static constexpr int IND = 128;
static constexpr int HID = 256;
static constexpr int OUTD = 64;

using f4 = __attribute__((ext_vector_type(4))) float;

// ---------------------------------------------------------------------------
// CSR construction: degree histogram -> exclusive scan -> bucket fill.
// ---------------------------------------------------------------------------
__global__ void hist_kernel(const int* __restrict__ dst, int E,
                            int* __restrict__ deg) {
    int i = blockIdx.x * blockDim.x + threadIdx.x;
    if (i < E) atomicAdd(&deg[dst[i]], 1);
}

__global__ __launch_bounds__(1024) void scan_kernel(
    const int* __restrict__ deg, int n, int* __restrict__ rowstart) {
    __shared__ int part[1024];
    const int T = 1024, t = threadIdx.x;
    const int per = (n + T - 1) / T;
    const int beg = t * per;
    const int end = min(beg + per, n);
    int s = 0;
    for (int i = beg; i < end; ++i) s += deg[i];
    part[t] = s;
    __syncthreads();
    for (int off = 1; off < T; off <<= 1) {
        int v = (t >= off) ? part[t - off] : 0;
        __syncthreads();
        part[t] += v;
        __syncthreads();
    }
    int run = (t == 0) ? 0 : part[t - 1];   // exclusive prefix of this chunk
    for (int i = beg; i < end; ++i) { rowstart[i] = run; run += deg[i]; }
}

__global__ void fill_kernel(const int* __restrict__ src,
                            const int* __restrict__ dst, int E,
                            const int* __restrict__ rowstart,
                            int* __restrict__ cursor,
                            int* __restrict__ csr) {
    int i = blockIdx.x * blockDim.x + threadIdx.x;
    if (i < E) {
        int d = dst[i];
        int p = atomicAdd(&cursor[d], 1);
        csr[rowstart[d] + p] = src[i];
    }
}

// ---------------------------------------------------------------------------
// Gather-mean layer 1: mean1[node,:] = mean over edges of x[src,:]  (128 f32)
// ---------------------------------------------------------------------------
__global__ __launch_bounds__(256) void gather1_kernel(
    const float* __restrict__ x, const int* __restrict__ csr,
    const int* __restrict__ rowstart, const int* __restrict__ deg,
    float* __restrict__ mean) {
    const int node = blockIdx.x * 4 + (threadIdx.x >> 6);
    const int lane = threadIdx.x & 63;
    const int beg = rowstart[node];
    const int n   = deg[node];
    float2 acc0 = make_float2(0.f, 0.f), acc1 = make_float2(0.f, 0.f);
    int e = 0;
    for (; e + 1 < n; e += 2) {
        int s0 = csr[beg + e];
        int s1 = csr[beg + e + 1];
        float2 v0 = *reinterpret_cast<const float2*>(x + (size_t)s0 * IND + lane * 2);
        float2 v1 = *reinterpret_cast<const float2*>(x + (size_t)s1 * IND + lane * 2);
        acc0.x += v0.x; acc0.y += v0.y;
        acc1.x += v1.x; acc1.y += v1.y;
    }
    if (e < n) {
        int s0 = csr[beg + e];
        float2 v0 = *reinterpret_cast<const float2*>(x + (size_t)s0 * IND + lane * 2);
        acc0.x += v0.x; acc0.y += v0.y;
    }
    const float inv = (n > 0) ? 1.0f / (float)n : 0.0f;
    reinterpret_cast<float2*>(mean + (size_t)node * IND)[lane] =
        make_float2((acc0.x + acc1.x) * inv, (acc0.y + acc1.y) * inv);
}

// ---------------------------------------------------------------------------
// Gather-mean layer 2: mean2[node,:] = mean over edges of h[src,:]  (256 f32)
// ---------------------------------------------------------------------------
__global__ __launch_bounds__(256) void gather2_kernel(
    const float* __restrict__ h, const int* __restrict__ csr,
    const int* __restrict__ rowstart, const int* __restrict__ deg,
    float* __restrict__ mean) {
    const int node = blockIdx.x * 4 + (threadIdx.x >> 6);
    const int lane = threadIdx.x & 63;
    const int beg = rowstart[node];
    const int n   = deg[node];
    float4 acc0 = make_float4(0.f, 0.f, 0.f, 0.f);
    float4 acc1 = make_float4(0.f, 0.f, 0.f, 0.f);
    int e = 0;
    for (; e + 1 < n; e += 2) {
        int s0 = csr[beg + e];
        int s1 = csr[beg + e + 1];
        float4 v0 = *reinterpret_cast<const float4*>(h + (size_t)s0 * HID + lane * 4);
        float4 v1 = *reinterpret_cast<const float4*>(h + (size_t)s1 * HID + lane * 4);
        acc0.x += v0.x; acc0.y += v0.y; acc0.z += v0.z; acc0.w += v0.w;
        acc1.x += v1.x; acc1.y += v1.y; acc1.z += v1.z; acc1.w += v1.w;
    }
    if (e < n) {
        int s0 = csr[beg + e];
        float4 v0 = *reinterpret_cast<const float4*>(h + (size_t)s0 * HID + lane * 4);
        acc0.x += v0.x; acc0.y += v0.y; acc0.z += v0.z; acc0.w += v0.w;
    }
    const float inv = (n > 0) ? 1.0f / (float)n : 0.0f;
    reinterpret_cast<float4*>(mean + (size_t)node * HID)[lane] =
        make_float4((acc0.x + acc1.x) * inv, (acc0.y + acc1.y) * inv,
                    (acc0.z + acc1.z) * inv, (acc0.w + acc1.w) * inv);
}

// ---------------------------------------------------------------------------
// Weight transpose layer 1: Wt1[k][j], k-major. k<128 -> W1l[j][k],
// k>=128 -> W1r[j][k-128]. j contiguous (256 cols).
// ---------------------------------------------------------------------------
__global__ void w1t_kernel(const float* __restrict__ W1l,
                           const float* __restrict__ W1r,
                           float* __restrict__ Wt) {
    int i = blockIdx.x * blockDim.x + threadIdx.x;   // over 256*256
    if (i >= 2 * IND * HID) return;
    int k = i >> 8, j = i & 255;
    Wt[i] = (k < IND) ? W1l[(size_t)j * IND + k]
                      : W1r[(size_t)j * IND + (k - IND)];
}

// ---------------------------------------------------------------------------
// Layer-1 dense, register-blocked outer-product GEMM, float4 A-path.
//   h = relu([mean1 | x] @ Wt1 + b1),  Wt1 k-major [256][256].
// Block = 256 thr = 4 waves (2x2); block tile 128 rows x 128 cols;
// lane tile 8x8. Per 4-k chunk: 8 A float4 loads, then per k: 2 W float4
// loads + 64 independent FMAs (1:16 VMEM:VALU).
// ---------------------------------------------------------------------------
__global__ __launch_bounds__(256) void sage1_kernel(
    const float* __restrict__ x, const float* __restrict__ mean,
    const float* __restrict__ Wt, const float* __restrict__ b1,
    float* __restrict__ h) {
    const int t    = threadIdx.x;
    const int wave = t >> 6;
    const int lane = t & 63;
    const int wr   = (wave >> 1) << 6;       // 0 or 64
    const int wc   = (wave & 1) << 6;        // 0 or 64
    const int lr   = (lane >> 3) << 3;       // 0..56
    const int lc   = (lane & 7) << 3;        // 0..56
    const int row0 = blockIdx.x * 128 + wr + lr;
    const int col0 = blockIdx.y * 128 + wc + lc;

    // clamp rows so loads stay in-bounds (stores are guarded)
    int rows[8];
#pragma unroll
    for (int r = 0; r < 8; ++r) rows[r] = min(row0 + r, N2 - 1);

    float acc[8][8];
#pragma unroll
    for (int r = 0; r < 8; ++r)
#pragma unroll
        for (int c = 0; c < 8; ++c) acc[r][c] = 0.0f;

#pragma unroll 1
    for (int half = 0; half < 2; ++half) {
        const float* __restrict__ A = half ? x : mean;
        const float* __restrict__ W = Wt + (size_t)half * IND * HID;
#pragma unroll 2
        for (int kc = 0; kc < IND / 4; ++kc) {
            f4 a4[8];
#pragma unroll
            for (int r = 0; r < 8; ++r)
                a4[r] = *reinterpret_cast<const f4*>(
                    A + (size_t)rows[r] * IND + kc * 4);
            const float* wk = W + (size_t)kc * 4 * HID + col0;
#pragma unroll
            for (int kk = 0; kk < 4; ++kk) {
                f4 w0 = *reinterpret_cast<const f4*>(wk + kk * HID);
                f4 w1 = *reinterpret_cast<const f4*>(wk + kk * HID + 4);
#pragma unroll
                for (int r = 0; r < 8; ++r) {
                    const float ar = a4[r][kk];
#pragma unroll
                    for (int c = 0; c < 4; ++c) {
                        acc[r][c]     += ar * w0[c];
                        acc[r][c + 4] += ar * w1[c];
                    }
                }
            }
        }
    }

    float bb[8];
#pragma unroll
    for (int c = 0; c < 8; ++c) bb[c] = b1[col0 + c];

#pragma unroll
    for (int r = 0; r < 8; ++r) {
        int row = row0 + r;
        if (row < N2) {
            float4* hp = reinterpret_cast<float4*>(h + (size_t)row * HID + col0);
            hp[0] = make_float4(fmaxf(acc[r][0] + bb[0], 0.0f),
                                fmaxf(acc[r][1] + bb[1], 0.0f),
                                fmaxf(acc[r][2] + bb[2], 0.0f),
                                fmaxf(acc[r][3] + bb[3], 0.0f));
            hp[1] = make_float4(fmaxf(acc[r][4] + bb[4], 0.0f),
                                fmaxf(acc[r][5] + bb[5], 0.0f),
                                fmaxf(acc[r][6] + bb[6], 0.0f),
                                fmaxf(acc[r][7] + bb[7], 0.0f));
        }
    }
}

// ---------------------------------------------------------------------------
// Weight transpose for layer 2: Wt[k][j] (k<256: W2l, else W2r), j contiguous.
// ---------------------------------------------------------------------------
__global__ void w2t_kernel(const float* __restrict__ W2l,
                           const float* __restrict__ W2r,
                           float* __restrict__ Wt) {
    int i = blockIdx.x * blockDim.x + threadIdx.x;   // over 512*64
    if (i >= 2 * HID * OUTD) return;
    int k = i >> 6, j = i & 63;
    Wt[i] = (k < HID) ? W2l[(size_t)j * HID + k]
                      : W2r[(size_t)j * HID + (k - HID)];
}

// ---------------------------------------------------------------------------
// Layer-2 dense + log_softmax (from R3).
// Block = 256 threads; 32 rows/block; 8 threads per row, 8 cols per thread.
// ---------------------------------------------------------------------------
__global__ __launch_bounds__(256) void sage2_kernel(
    const float* __restrict__ h, const float* __restrict__ mean,
    const float* __restrict__ Wt, const float* __restrict__ b2,
    float* __restrict__ out) {
    const int t   = threadIdx.x;
    const int row = blockIdx.x * 32 + (t >> 3);
    const int jc  = (t & 7) * 8;
    if (row >= N3) return;

    float acc[8];
#pragma unroll
    for (int c = 0; c < 8; ++c) acc[c] = b2[jc + c];

    const float* __restrict__ arow = mean + (size_t)row * HID;
    const float* __restrict__ hrow = h    + (size_t)row * HID;

#pragma unroll 1
    for (int half = 0; half < 2; ++half) {
        const float* __restrict__ a = half ? hrow : arow;
        const float* __restrict__ w = Wt + (size_t)half * HID * OUTD + jc;
#pragma unroll 2
        for (int kc = 0; kc < HID / 4; ++kc) {
            float4 av = reinterpret_cast<const float4*>(a)[kc];
            const float* wk = w + (size_t)kc * 4 * OUTD;
            float ak[4] = {av.x, av.y, av.z, av.w};
#pragma unroll
            for (int kk = 0; kk < 4; ++kk) {
                float4 wa = *reinterpret_cast<const float4*>(wk + kk * OUTD);
                float4 wb = *reinterpret_cast<const float4*>(wk + kk * OUTD + 4);
                acc[0] += ak[kk] * wa.x; acc[1] += ak[kk] * wa.y;
                acc[2] += ak[kk] * wa.z; acc[3] += ak[kk] * wa.w;
                acc[4] += ak[kk] * wb.x; acc[5] += ak[kk] * wb.y;
                acc[6] += ak[kk] * wb.z; acc[7] += ak[kk] * wb.w;
            }
        }
    }

    // ---- log_softmax across the 8 lanes sharing this row ----
    float mx = acc[0];
#pragma unroll
    for (int c = 1; c < 8; ++c) mx = fmaxf(mx, acc[c]);
#pragma unroll
    for (int o = 1; o <= 4; o <<= 1) mx = fmaxf(mx, __shfl_xor(mx, o));
    float sum = 0.0f;
#pragma unroll
    for (int c = 0; c < 8; ++c) sum += __expf(acc[c] - mx);
#pragma unroll
    for (int o = 1; o <= 4; o <<= 1) sum += __shfl_xor(sum, o);
    const float lse = mx + __logf(sum);

    float4* op = reinterpret_cast<float4*>(out + (size_t)row * OUTD + jc);
    op[0] = make_float4(acc[0] - lse, acc[1] - lse, acc[2] - lse, acc[3] - lse);
    op[1] = make_float4(acc[4] - lse, acc[5] - lse, acc[6] - lse, acc[7] - lse);
}

// ---------------------------------------------------------------------------
extern "C" void kernel_launch(void* const* d_in, const int* in_sizes, int n_in,
                              void* d_out, int out_size, void* d_ws, size_t ws_size,
                              hipStream_t stream) {
    const float* x    = (const float*)d_in[0];
    const int*   src1 = (const int*)d_in[1];
    const int*   dst1 = (const int*)d_in[2];
    const int*   src2 = (const int*)d_in[3];
    const int*   dst2 = (const int*)d_in[4];
    const float* W1l  = (const float*)d_in[7];
    const float* W1r  = (const float*)d_in[8];
    const float* b1   = (const float*)d_in[9];
    const float* W2l  = (const float*)d_in[10];
    const float* W2r  = (const float*)d_in[11];
    const float* b2   = (const float*)d_in[12];
    float* out = (float*)d_out;

    const int E1 = in_sizes[1];
    const int E2 = in_sizes[3];

    // Workspace layout (bytes). mean2 aliases mean1 (dead after sage1).
    // Wt1 aliases csr2: Wt1 is dead after sage1; csr2 is built after sage1.
    char* ws = (char*)d_ws;
    float* mean1     = (float*)(ws + 0);          // 20,480,000
    float* mean2     = (float*)(ws + 0);
    float* h         = (float*)(ws + 20480000);   // 40,960,000
    int*   csr1      = (int*)(ws + 61440000);     //  2,560,000
    int*   csr2      = (int*)(ws + 64000000);     //    640,000 (also Wt1: 262,144)
    float* Wt1       = (float*)(ws + 64000000);
    int*   deg1      = (int*)(ws + 64640000);     //    160,000
    int*   rowstart1 = (int*)(ws + 64800000);     //    160,000
    int*   cursor1   = (int*)(ws + 64960000);     //    160,000
    int*   deg2      = (int*)(ws + 65120000);     //     40,000
    int*   rowstart2 = (int*)(ws + 65160000);     //     40,000
    int*   cursor2   = (int*)(ws + 65200000);     //     40,000
    float* Wt2       = (float*)(ws + 65240000);   //    131,072  (end 65,371,072)

    hipMemsetAsync(deg1, 0, (size_t)N2 * sizeof(int), stream);
    hipMemsetAsync(cursor1, 0, (size_t)N2 * sizeof(int), stream);
    hipMemsetAsync(deg2, 0, (size_t)N3 * sizeof(int), stream);
    hipMemsetAsync(cursor2, 0, (size_t)N3 * sizeof(int), stream);

    w2t_kernel<<<(2 * HID * OUTD + 255) / 256, 256, 0, stream>>>(W2l, W2r, Wt2);
    w1t_kernel<<<(2 * IND * HID + 255) / 256, 256, 0, stream>>>(W1l, W1r, Wt1);

    // ---- layer 1: CSR build + gather-mean + dense ----
    hist_kernel<<<(E1 + 255) / 256, 256, 0, stream>>>(dst1, E1, deg1);
    scan_kernel<<<1, 1024, 0, stream>>>(deg1, N2, rowstart1);
    fill_kernel<<<(E1 + 255) / 256, 256, 0, stream>>>(src1, dst1, E1,
                                                      rowstart1, cursor1, csr1);
    gather1_kernel<<<N2 / 4, 256, 0, stream>>>(x, csr1, rowstart1, deg1, mean1);
    {
        dim3 grid((N2 + 127) / 128, HID / 128);
        sage1_kernel<<<grid, 256, 0, stream>>>(x, mean1, Wt1, b1, h);
    }

    // ---- layer 2 (CSR build AFTER sage1: csr2 overwrites Wt1) ----
    hist_kernel<<<(E2 + 255) / 256, 256, 0, stream>>>(dst2, E2, deg2);
    scan_kernel<<<1, 1024, 0, stream>>>(deg2, N3, rowstart2);
    fill_kernel<<<(E2 + 255) / 256, 256, 0, stream>>>(src2, dst2, E2,
                                                      rowstart2, cursor2, csr2);
    gather2_kernel<<<N3 / 4, 256, 0, stream>>>(h, csr2, rowstart2, deg2, mean2);
    sage2_kernel<<<(N3 + 31) / 32, 256, 0, stream>>>(h, mean2, Wt2, b2, out);
}

// Round 7
// 436.418 us; speedup vs baseline: 6.7969x; 1.0635x over previous
//
#include <hip/hip_runtime.h>

// Problem constants (fixed by the reference)
static constexpr int N1  = 200000;
static constexpr int N2  = 40000;
static constexpr int N3  = 10000;
static constexpr int IND = 128;
static constexpr int HID = 256;
static constexpr int OUTD = 64;

using f4 = __attribute__((ext_vector_type(4))) float;

// ---------------------------------------------------------------------------
// CSR construction: degree histogram -> exclusive scan -> bucket fill.
// ---------------------------------------------------------------------------
__global__ void hist_kernel(const int* __restrict__ dst, int E,
                            int* __restrict__ deg) {
    int i = blockIdx.x * blockDim.x + threadIdx.x;
    if (i < E) atomicAdd(&deg[dst[i]], 1);
}

__global__ __launch_bounds__(1024) void scan_kernel(
    const int* __restrict__ deg, int n, int* __restrict__ rowstart) {
    __shared__ int part[1024];
    const int T = 1024, t = threadIdx.x;
    const int per = (n + T - 1) / T;
    const int beg = t * per;
    const int end = min(beg + per, n);
    int s = 0;
    for (int i = beg; i < end; ++i) s += deg[i];
    part[t] = s;
    __syncthreads();
    for (int off = 1; off < T; off <<= 1) {
        int v = (t >= off) ? part[t - off] : 0;
        __syncthreads();
        part[t] += v;
        __syncthreads();
    }
    int run = (t == 0) ? 0 : part[t - 1];   // exclusive prefix of this chunk
    for (int i = beg; i < end; ++i) { rowstart[i] = run; run += deg[i]; }
}

__global__ void fill_kernel(const int* __restrict__ src,
                            const int* __restrict__ dst, int E,
                            const int* __restrict__ rowstart,
                            int* __restrict__ cursor,
                            int* __restrict__ csr) {
    int i = blockIdx.x * blockDim.x + threadIdx.x;
    if (i < E) {
        int d = dst[i];
        int p = atomicAdd(&cursor[d], 1);
        csr[rowstart[d] + p] = src[i];
    }
}

// ---------------------------------------------------------------------------
// Gather-mean layer 1: mean1[node,:] = mean over edges of x[src,:]  (128 f32)
// ---------------------------------------------------------------------------
__global__ __launch_bounds__(256) void gather1_kernel(
    const float* __restrict__ x, const int* __restrict__ csr,
    const int* __restrict__ rowstart, const int* __restrict__ deg,
    float* __restrict__ mean) {
    const int node = blockIdx.x * 4 + (threadIdx.x >> 6);
    const int lane = threadIdx.x & 63;
    const int beg = rowstart[node];
    const int n   = deg[node];
    float2 acc0 = make_float2(0.f, 0.f), acc1 = make_float2(0.f, 0.f);
    int e = 0;
    for (; e + 1 < n; e += 2) {
        int s0 = csr[beg + e];
        int s1 = csr[beg + e + 1];
        float2 v0 = *reinterpret_cast<const float2*>(x + (size_t)s0 * IND + lane * 2);
        float2 v1 = *reinterpret_cast<const float2*>(x + (size_t)s1 * IND + lane * 2);
        acc0.x += v0.x; acc0.y += v0.y;
        acc1.x += v1.x; acc1.y += v1.y;
    }
    if (e < n) {
        int s0 = csr[beg + e];
        float2 v0 = *reinterpret_cast<const float2*>(x + (size_t)s0 * IND + lane * 2);
        acc0.x += v0.x; acc0.y += v0.y;
    }
    const float inv = (n > 0) ? 1.0f / (float)n : 0.0f;
    reinterpret_cast<float2*>(mean + (size_t)node * IND)[lane] =
        make_float2((acc0.x + acc1.x) * inv, (acc0.y + acc1.y) * inv);
}

// ---------------------------------------------------------------------------
// Gather-mean layer 2: mean2[node,:] = mean over edges of h[src,:]  (256 f32)
// ---------------------------------------------------------------------------
__global__ __launch_bounds__(256) void gather2_kernel(
    const float* __restrict__ h, const int* __restrict__ csr,
    const int* __restrict__ rowstart, const int* __restrict__ deg,
    float* __restrict__ mean) {
    const int node = blockIdx.x * 4 + (threadIdx.x >> 6);
    const int lane = threadIdx.x & 63;
    const int beg = rowstart[node];
    const int n   = deg[node];
    float4 acc0 = make_float4(0.f, 0.f, 0.f, 0.f);
    float4 acc1 = make_float4(0.f, 0.f, 0.f, 0.f);
    int e = 0;
    for (; e + 1 < n; e += 2) {
        int s0 = csr[beg + e];
        int s1 = csr[beg + e + 1];
        float4 v0 = *reinterpret_cast<const float4*>(h + (size_t)s0 * HID + lane * 4);
        float4 v1 = *reinterpret_cast<const float4*>(h + (size_t)s1 * HID + lane * 4);
        acc0.x += v0.x; acc0.y += v0.y; acc0.z += v0.z; acc0.w += v0.w;
        acc1.x += v1.x; acc1.y += v1.y; acc1.z += v1.z; acc1.w += v1.w;
    }
    if (e < n) {
        int s0 = csr[beg + e];
        float4 v0 = *reinterpret_cast<const float4*>(h + (size_t)s0 * HID + lane * 4);
        acc0.x += v0.x; acc0.y += v0.y; acc0.z += v0.z; acc0.w += v0.w;
    }
    const float inv = (n > 0) ? 1.0f / (float)n : 0.0f;
    reinterpret_cast<float4*>(mean + (size_t)node * HID)[lane] =
        make_float4((acc0.x + acc1.x) * inv, (acc0.y + acc1.y) * inv,
                    (acc0.z + acc1.z) * inv, (acc0.w + acc1.w) * inv);
}

// ---------------------------------------------------------------------------
// Weight transpose layer 1: Wt1[k][j], k-major. k<128 -> W1l[j][k],
// k>=128 -> W1r[j][k-128]. j contiguous (256 cols).
// ---------------------------------------------------------------------------
__global__ void w1t_kernel(const float* __restrict__ W1l,
                           const float* __restrict__ W1r,
                           float* __restrict__ Wt) {
    int i = blockIdx.x * blockDim.x + threadIdx.x;   // over 256*256
    if (i >= 2 * IND * HID) return;
    int k = i >> 8, j = i & 255;
    Wt[i] = (k < IND) ? W1l[(size_t)j * IND + k]
                      : W1r[(size_t)j * IND + (k - IND)];
}

// ---------------------------------------------------------------------------
// Layer-1 dense GEMM, double-buffered register pipeline.
//   h = relu([mean1 | x] @ Wt1 + b1),  Wt1 k-major [256][256].
// Block = 256 thr = 4 waves (2x2); block tile 128x128; lane tile 8x8.
// 64 k-chunks (4 k each). While chunk q computes (256 FMA), chunk q+1's
// 16 float4 loads are in flight in the second register buffer.
// __launch_bounds__(256,1): grid caps occupancy at ~2.4 blocks/CU anyway,
// so spend VGPRs (~210) on load buffering instead.
// ---------------------------------------------------------------------------
__device__ __forceinline__ void load_chunk(
    int q, const float* __restrict__ mean, const float* __restrict__ x,
    const float* __restrict__ Wt, const int (&rowoff)[8], int col0,
    f4 (&a)[8], f4 (&w)[4][2]) {
    const float* __restrict__ A = (q < 32) ? mean : x;
    const int kq = (q & 31) * 4;
#pragma unroll
    for (int r = 0; r < 8; ++r)
        a[r] = *reinterpret_cast<const f4*>(A + rowoff[r] + kq);
    const float* __restrict__ wb = Wt + (size_t)q * 4 * HID + col0;
#pragma unroll
    for (int kk = 0; kk < 4; ++kk) {
        w[kk][0] = *reinterpret_cast<const f4*>(wb + kk * HID);
        w[kk][1] = *reinterpret_cast<const f4*>(wb + kk * HID + 4);
    }
}

__device__ __forceinline__ void comp_chunk(
    float (&acc)[8][8], const f4 (&a)[8], const f4 (&w)[4][2]) {
#pragma unroll
    for (int kk = 0; kk < 4; ++kk)
#pragma unroll
        for (int r = 0; r < 8; ++r) {
            const float ar = a[r][kk];
#pragma unroll
            for (int c = 0; c < 4; ++c) {
                acc[r][c]     += ar * w[kk][0][c];
                acc[r][c + 4] += ar * w[kk][1][c];
            }
        }
}

__global__ __launch_bounds__(256, 1) void sage1_kernel(
    const float* __restrict__ x, const float* __restrict__ mean,
    const float* __restrict__ Wt, const float* __restrict__ b1,
    float* __restrict__ h) {
    const int t    = threadIdx.x;
    const int wave = t >> 6;
    const int lane = t & 63;
    const int wr   = (wave >> 1) << 6;       // 0 or 64
    const int wc   = (wave & 1) << 6;        // 0 or 64
    const int lr   = (lane >> 3) << 3;       // 0..56
    const int lc   = (lane & 7) << 3;        // 0..56
    const int row0 = blockIdx.x * 128 + wr + lr;
    const int col0 = blockIdx.y * 128 + wc + lc;

    // clamp rows so loads stay in-bounds (stores are guarded)
    int rowoff[8];
#pragma unroll
    for (int r = 0; r < 8; ++r)
        rowoff[r] = min(row0 + r, N2 - 1) * IND;

    float acc[8][8];
#pragma unroll
    for (int r = 0; r < 8; ++r)
#pragma unroll
        for (int c = 0; c < 8; ++c) acc[r][c] = 0.0f;

    f4 aA[8], wA[4][2], aB[8], wB[4][2];
    load_chunk(0, mean, x, Wt, rowoff, col0, aA, wA);

#pragma unroll 1
    for (int q = 0; q < 64; q += 2) {
        load_chunk(q + 1, mean, x, Wt, rowoff, col0, aB, wB);
        comp_chunk(acc, aA, wA);
        if (q + 2 < 64)
            load_chunk(q + 2, mean, x, Wt, rowoff, col0, aA, wA);
        comp_chunk(acc, aB, wB);
    }

    float bb[8];
#pragma unroll
    for (int c = 0; c < 8; ++c) bb[c] = b1[col0 + c];

#pragma unroll
    for (int r = 0; r < 8; ++r) {
        int row = row0 + r;
        if (row < N2) {
            float4* hp = reinterpret_cast<float4*>(h + (size_t)row * HID + col0);
            hp[0] = make_float4(fmaxf(acc[r][0] + bb[0], 0.0f),
                                fmaxf(acc[r][1] + bb[1], 0.0f),
                                fmaxf(acc[r][2] + bb[2], 0.0f),
                                fmaxf(acc[r][3] + bb[3], 0.0f));
            hp[1] = make_float4(fmaxf(acc[r][4] + bb[4], 0.0f),
                                fmaxf(acc[r][5] + bb[5], 0.0f),
                                fmaxf(acc[r][6] + bb[6], 0.0f),
                                fmaxf(acc[r][7] + bb[7], 0.0f));
        }
    }
}

// ---------------------------------------------------------------------------
// Weight transpose for layer 2: Wt[k][j] (k<256: W2l, else W2r), j contiguous.
// ---------------------------------------------------------------------------
__global__ void w2t_kernel(const float* __restrict__ W2l,
                           const float* __restrict__ W2r,
                           float* __restrict__ Wt) {
    int i = blockIdx.x * blockDim.x + threadIdx.x;   // over 512*64
    if (i >= 2 * HID * OUTD) return;
    int k = i >> 6, j = i & 63;
    Wt[i] = (k < HID) ? W2l[(size_t)j * HID + k]
                      : W2r[(size_t)j * HID + (k - HID)];
}

// ---------------------------------------------------------------------------
// Layer-2 dense + log_softmax (from R3).
// Block = 256 threads; 32 rows/block; 8 threads per row, 8 cols per thread.
// ---------------------------------------------------------------------------
__global__ __launch_bounds__(256) void sage2_kernel(
    const float* __restrict__ h, const float* __restrict__ mean,
    const float* __restrict__ Wt, const float* __restrict__ b2,
    float* __restrict__ out) {
    const int t   = threadIdx.x;
    const int row = blockIdx.x * 32 + (t >> 3);
    const int jc  = (t & 7) * 8;
    if (row >= N3) return;

    float acc[8];
#pragma unroll
    for (int c = 0; c < 8; ++c) acc[c] = b2[jc + c];

    const float* __restrict__ arow = mean + (size_t)row * HID;
    const float* __restrict__ hrow = h    + (size_t)row * HID;

#pragma unroll 1
    for (int half = 0; half < 2; ++half) {
        const float* __restrict__ a = half ? hrow : arow;
        const float* __restrict__ w = Wt + (size_t)half * HID * OUTD + jc;
#pragma unroll 2
        for (int kc = 0; kc < HID / 4; ++kc) {
            float4 av = reinterpret_cast<const float4*>(a)[kc];
            const float* wk = w + (size_t)kc * 4 * OUTD;
            float ak[4] = {av.x, av.y, av.z, av.w};
#pragma unroll
            for (int kk = 0; kk < 4; ++kk) {
                float4 wa = *reinterpret_cast<const float4*>(wk + kk * OUTD);
                float4 wb = *reinterpret_cast<const float4*>(wk + kk * OUTD + 4);
                acc[0] += ak[kk] * wa.x; acc[1] += ak[kk] * wa.y;
                acc[2] += ak[kk] * wa.z; acc[3] += ak[kk] * wa.w;
                acc[4] += ak[kk] * wb.x; acc[5] += ak[kk] * wb.y;
                acc[6] += ak[kk] * wb.z; acc[7] += ak[kk] * wb.w;
            }
        }
    }

    // ---- log_softmax across the 8 lanes sharing this row ----
    float mx = acc[0];
#pragma unroll
    for (int c = 1; c < 8; ++c) mx = fmaxf(mx, acc[c]);
#pragma unroll
    for (int o = 1; o <= 4; o <<= 1) mx = fmaxf(mx, __shfl_xor(mx, o));
    float sum = 0.0f;
#pragma unroll
    for (int c = 0; c < 8; ++c) sum += __expf(acc[c] - mx);
#pragma unroll
    for (int o = 1; o <= 4; o <<= 1) sum += __shfl_xor(sum, o);
    const float lse = mx + __logf(sum);

    float4* op = reinterpret_cast<float4*>(out + (size_t)row * OUTD + jc);
    op[0] = make_float4(acc[0] - lse, acc[1] - lse, acc[2] - lse, acc[3] - lse);
    op[1] = make_float4(acc[4] - lse, acc[5] - lse, acc[6] - lse, acc[7] - lse);
}

// ---------------------------------------------------------------------------
extern "C" void kernel_launch(void* const* d_in, const int* in_sizes, int n_in,
                              void* d_out, int out_size, void* d_ws, size_t ws_size,
                              hipStream_t stream) {
    const float* x    = (const float*)d_in[0];
    const int*   src1 = (const int*)d_in[1];
    const int*   dst1 = (const int*)d_in[2];
    const int*   src2 = (const int*)d_in[3];
    const int*   dst2 = (const int*)d_in[4];
    const float* W1l  = (const float*)d_in[7];
    const float* W1r  = (const float*)d_in[8];
    const float* b1   = (const float*)d_in[9];
    const float* W2l  = (const float*)d_in[10];
    const float* W2r  = (const float*)d_in[11];
    const float* b2   = (const float*)d_in[12];
    float* out = (float*)d_out;

    const int E1 = in_sizes[1];
    const int E2 = in_sizes[3];

    // Workspace layout (bytes). mean2 aliases mean1 (dead after sage1).
    // Wt1 aliases csr2: Wt1 is dead after sage1; csr2 is built after sage1.
    char* ws = (char*)d_ws;
    float* mean1     = (float*)(ws + 0);          // 20,480,000
    float* mean2     = (float*)(ws + 0);
    float* h         = (float*)(ws + 20480000);   // 40,960,000
    int*   csr1      = (int*)(ws + 61440000);     //  2,560,000
    int*   csr2      = (int*)(ws + 64000000);     //    640,000 (also Wt1: 262,144)
    float* Wt1       = (float*)(ws + 64000000);
    int*   deg1      = (int*)(ws + 64640000);     //    160,000
    int*   rowstart1 = (int*)(ws + 64800000);     //    160,000
    int*   cursor1   = (int*)(ws + 64960000);     //    160,000
    int*   deg2      = (int*)(ws + 65120000);     //     40,000
    int*   rowstart2 = (int*)(ws + 65160000);     //     40,000
    int*   cursor2   = (int*)(ws + 65200000);     //     40,000
    float* Wt2       = (float*)(ws + 65240000);   //    131,072  (end 65,371,072)

    hipMemsetAsync(deg1, 0, (size_t)N2 * sizeof(int), stream);
    hipMemsetAsync(cursor1, 0, (size_t)N2 * sizeof(int), stream);
    hipMemsetAsync(deg2, 0, (size_t)N3 * sizeof(int), stream);
    hipMemsetAsync(cursor2, 0, (size_t)N3 * sizeof(int), stream);

    w2t_kernel<<<(2 * HID * OUTD + 255) / 256, 256, 0, stream>>>(W2l, W2r, Wt2);
    w1t_kernel<<<(2 * IND * HID + 255) / 256, 256, 0, stream>>>(W1l, W1r, Wt1);

    // ---- layer 1: CSR build + gather-mean + dense ----
    hist_kernel<<<(E1 + 255) / 256, 256, 0, stream>>>(dst1, E1, deg1);
    scan_kernel<<<1, 1024, 0, stream>>>(deg1, N2, rowstart1);
    fill_kernel<<<(E1 + 255) / 256, 256, 0, stream>>>(src1, dst1, E1,
                                                      rowstart1, cursor1, csr1);
    gather1_kernel<<<N2 / 4, 256, 0, stream>>>(x, csr1, rowstart1, deg1, mean1);
    {
        dim3 grid((N2 + 127) / 128, HID / 128);
        sage1_kernel<<<grid, 256, 0, stream>>>(x, mean1, Wt1, b1, h);
    }

    // ---- layer 2 (CSR build AFTER sage1: csr2 overwrites Wt1) ----
    hist_kernel<<<(E2 + 255) / 256, 256, 0, stream>>>(dst2, E2, deg2);
    scan_kernel<<<1, 1024, 0, stream>>>(deg2, N3, rowstart2);
    fill_kernel<<<(E2 + 255) / 256, 256, 0, stream>>>(src2, dst2, E2,
                                                      rowstart2, cursor2, csr2);
    gather2_kernel<<<N3 / 4, 256, 0, stream>>>(h, csr2, rowstart2, deg2, mean2);
    sage2_kernel<<<(N3 + 31) / 32, 256, 0, stream>>>(h, mean2, Wt2, b2, out);
}

// Round 8
// 360.052 us; speedup vs baseline: 8.2385x; 1.2121x over previous
//
#include <hip/hip_runtime.h>

// Problem constants (fixed by the reference)
static constexpr int N1  = 200000;
static constexpr int N2  = 40000;
static constexpr int N3  = 10000;
static constexpr int IND = 128;
static constexpr int HID = 256;
static constexpr int OUTD = 64;

using f4     = __attribute__((ext_vector_type(4))) float;
using f32x4  = __attribute__((ext_vector_type(4))) float;
using bf16x8 = __attribute__((ext_vector_type(8))) short;  // 8 bf16 (4 VGPRs)

// round-to-nearest-even f32 -> bf16 (finite inputs)
__device__ __forceinline__ unsigned short f2bf(float f) {
    unsigned int u = __float_as_uint(f);
    u += 0x7FFFu + ((u >> 16) & 1u);
    return (unsigned short)(u >> 16);
}

// ---------------------------------------------------------------------------
// CSR construction: degree histogram -> exclusive scan -> bucket fill.
// ---------------------------------------------------------------------------
__global__ void hist_kernel(const int* __restrict__ dst, int E,
                            int* __restrict__ deg) {
    int i = blockIdx.x * blockDim.x + threadIdx.x;
    if (i < E) atomicAdd(&deg[dst[i]], 1);
}

__global__ __launch_bounds__(1024) void scan_kernel(
    const int* __restrict__ deg, int n, int* __restrict__ rowstart) {
    __shared__ int part[1024];
    const int T = 1024, t = threadIdx.x;
    const int per = (n + T - 1) / T;
    const int beg = t * per;
    const int end = min(beg + per, n);
    int s = 0;
    for (int i = beg; i < end; ++i) s += deg[i];
    part[t] = s;
    __syncthreads();
    for (int off = 1; off < T; off <<= 1) {
        int v = (t >= off) ? part[t - off] : 0;
        __syncthreads();
        part[t] += v;
        __syncthreads();
    }
    int run = (t == 0) ? 0 : part[t - 1];   // exclusive prefix of this chunk
    for (int i = beg; i < end; ++i) { rowstart[i] = run; run += deg[i]; }
}

__global__ void fill_kernel(const int* __restrict__ src,
                            const int* __restrict__ dst, int E,
                            const int* __restrict__ rowstart,
                            int* __restrict__ cursor,
                            int* __restrict__ csr) {
    int i = blockIdx.x * blockDim.x + threadIdx.x;
    if (i < E) {
        int d = dst[i];
        int p = atomicAdd(&cursor[d], 1);
        csr[rowstart[d] + p] = src[i];
    }
}

// ---------------------------------------------------------------------------
// Gather-mean layer 1 -> bf16 into A1b cols [0,128). A1b row stride = 256.
// One wave per node; lane owns 2 floats.
// ---------------------------------------------------------------------------
__global__ __launch_bounds__(256) void gather1_kernel(
    const float* __restrict__ x, const int* __restrict__ csr,
    const int* __restrict__ rowstart, const int* __restrict__ deg,
    unsigned short* __restrict__ A1b) {
    const int node = blockIdx.x * 4 + (threadIdx.x >> 6);
    const int lane = threadIdx.x & 63;
    const int beg = rowstart[node];
    const int n   = deg[node];
    float2 acc0 = make_float2(0.f, 0.f), acc1 = make_float2(0.f, 0.f);
    int e = 0;
    for (; e + 1 < n; e += 2) {
        int s0 = csr[beg + e];
        int s1 = csr[beg + e + 1];
        float2 v0 = *reinterpret_cast<const float2*>(x + (size_t)s0 * IND + lane * 2);
        float2 v1 = *reinterpret_cast<const float2*>(x + (size_t)s1 * IND + lane * 2);
        acc0.x += v0.x; acc0.y += v0.y;
        acc1.x += v1.x; acc1.y += v1.y;
    }
    if (e < n) {
        int s0 = csr[beg + e];
        float2 v0 = *reinterpret_cast<const float2*>(x + (size_t)s0 * IND + lane * 2);
        acc0.x += v0.x; acc0.y += v0.y;
    }
    const float inv = (n > 0) ? 1.0f / (float)n : 0.0f;
    unsigned int packed = (unsigned int)f2bf((acc0.x + acc1.x) * inv)
                        | ((unsigned int)f2bf((acc0.y + acc1.y) * inv) << 16);
    *reinterpret_cast<unsigned int*>(A1b + (size_t)node * 256 + lane * 2) = packed;
}

// ---------------------------------------------------------------------------
// x rows [0,N2) -> bf16 into A1b cols [128,256).
// ---------------------------------------------------------------------------
__global__ void xcvt_kernel(const float* __restrict__ x,
                            unsigned short* __restrict__ A1b) {
    int i = blockIdx.x * blockDim.x + threadIdx.x;   // over N2*32
    if (i >= N2 * 32) return;
    int row = i >> 5, c4 = (i & 31) * 4;
    float4 v = *reinterpret_cast<const float4*>(x + (size_t)row * IND + c4);
    unsigned int lo = (unsigned int)f2bf(v.x) | ((unsigned int)f2bf(v.y) << 16);
    unsigned int hi = (unsigned int)f2bf(v.z) | ((unsigned int)f2bf(v.w) << 16);
    *reinterpret_cast<uint2*>(A1b + (size_t)row * 256 + 128 + c4) =
        make_uint2(lo, hi);
}

// ---------------------------------------------------------------------------
// Layer-1 weights -> bf16 concat Wb[j][k]: k<128 from W1l[j][k], else W1r.
// j-major, k contiguous (this IS the MFMA B-fragment layout: B[k][n]=W[n][k]).
// ---------------------------------------------------------------------------
__global__ void w1b_kernel(const float* __restrict__ W1l,
                           const float* __restrict__ W1r,
                           unsigned short* __restrict__ Wb) {
    int i = blockIdx.x * blockDim.x + threadIdx.x;   // over 256*256
    if (i >= HID * 2 * IND) return;
    int j = i >> 8, k = i & 255;
    float v = (k < IND) ? W1l[(size_t)j * IND + k]
                        : W1r[(size_t)j * IND + (k - IND)];
    Wb[i] = (short)f2bf(v);
}

// ---------------------------------------------------------------------------
// Layer-1 dense GEMM on MFMA (bf16 in, fp32 accum).
//   h = relu(A1b @ Wb^T + b1), M=40000, N=256, K=256.
// Block = 256 thr = 4 waves (2M x 2N). Wave tile 32x64 = 2x4 frags of
// mfma_f32_16x16x32_bf16. A-frag: lane holds A[row0+(l&15)][kh*8..+8];
// B-frag: lane holds W[col0+(l&15)][kh*8..+8]. C/D: col=l&15, row=kh*4+reg.
// ---------------------------------------------------------------------------
__global__ __launch_bounds__(256) void sage1_kernel(
    const unsigned short* __restrict__ A1b,
    const unsigned short* __restrict__ Wb,
    const float* __restrict__ b1,
    float* __restrict__ h) {
    const int t    = threadIdx.x;
    const int wave = t >> 6;
    const int lane = t & 63;
    const int l15  = lane & 15;
    const int kh   = lane >> 4;              // 0..3
    const int wm   = wave >> 1;              // 0..1
    const int wn   = wave & 1;               // 0..1
    const int row0 = blockIdx.x * 64 + wm * 32;    // 625*64 == 40000 exact
    const int col0 = blockIdx.y * 128 + wn * 64;

    f32x4 acc[2][4];
#pragma unroll
    for (int m = 0; m < 2; ++m)
#pragma unroll
        for (int n = 0; n < 4; ++n)
            acc[m][n] = (f32x4){0.f, 0.f, 0.f, 0.f};

#pragma unroll
    for (int ks = 0; ks < 8; ++ks) {
        const int k0 = ks * 32 + kh * 8;
        bf16x8 a[2], b[4];
#pragma unroll
        for (int m = 0; m < 2; ++m)
            a[m] = *reinterpret_cast<const bf16x8*>(
                A1b + (size_t)(row0 + m * 16 + l15) * 256 + k0);
#pragma unroll
        for (int n = 0; n < 4; ++n)
            b[n] = *reinterpret_cast<const bf16x8*>(
                Wb + (size_t)(col0 + n * 16 + l15) * 256 + k0);
#pragma unroll
        for (int m = 0; m < 2; ++m)
#pragma unroll
            for (int n = 0; n < 4; ++n)
                acc[m][n] = __builtin_amdgcn_mfma_f32_16x16x32_bf16(
                    a[m], b[n], acc[m][n], 0, 0, 0);
    }

#pragma unroll
    for (int m = 0; m < 2; ++m) {
        const int r0 = row0 + m * 16 + kh * 4;
#pragma unroll
        for (int n = 0; n < 4; ++n) {
            const int c = col0 + n * 16 + l15;
            const float bias = b1[c];
#pragma unroll
            for (int j = 0; j < 4; ++j)
                h[(size_t)(r0 + j) * HID + c] = fmaxf(acc[m][n][j] + bias, 0.0f);
        }
    }
}

// ---------------------------------------------------------------------------
// Gather-mean layer 2: mean2[node,:] = mean over edges of h[src,:]  (256 f32)
// ---------------------------------------------------------------------------
__global__ __launch_bounds__(256) void gather2_kernel(
    const float* __restrict__ h, const int* __restrict__ csr,
    const int* __restrict__ rowstart, const int* __restrict__ deg,
    float* __restrict__ mean) {
    const int node = blockIdx.x * 4 + (threadIdx.x >> 6);
    const int lane = threadIdx.x & 63;
    const int beg = rowstart[node];
    const int n   = deg[node];
    float4 acc0 = make_float4(0.f, 0.f, 0.f, 0.f);
    float4 acc1 = make_float4(0.f, 0.f, 0.f, 0.f);
    int e = 0;
    for (; e + 1 < n; e += 2) {
        int s0 = csr[beg + e];
        int s1 = csr[beg + e + 1];
        float4 v0 = *reinterpret_cast<const float4*>(h + (size_t)s0 * HID + lane * 4);
        float4 v1 = *reinterpret_cast<const float4*>(h + (size_t)s1 * HID + lane * 4);
        acc0.x += v0.x; acc0.y += v0.y; acc0.z += v0.z; acc0.w += v0.w;
        acc1.x += v1.x; acc1.y += v1.y; acc1.z += v1.z; acc1.w += v1.w;
    }
    if (e < n) {
        int s0 = csr[beg + e];
        float4 v0 = *reinterpret_cast<const float4*>(h + (size_t)s0 * HID + lane * 4);
        acc0.x += v0.x; acc0.y += v0.y; acc0.z += v0.z; acc0.w += v0.w;
    }
    const float inv = (n > 0) ? 1.0f / (float)n : 0.0f;
    reinterpret_cast<float4*>(mean + (size_t)node * HID)[lane] =
        make_float4((acc0.x + acc1.x) * inv, (acc0.y + acc1.y) * inv,
                    (acc0.z + acc1.z) * inv, (acc0.w + acc1.w) * inv);
}

// ---------------------------------------------------------------------------
// Weight transpose for layer 2: Wt[k][j] (k<256: W2l, else W2r), j contiguous.
// ---------------------------------------------------------------------------
__global__ void w2t_kernel(const float* __restrict__ W2l,
                           const float* __restrict__ W2r,
                           float* __restrict__ Wt) {
    int i = blockIdx.x * blockDim.x + threadIdx.x;   // over 512*64
    if (i >= 2 * HID * OUTD) return;
    int k = i >> 6, j = i & 63;
    Wt[i] = (k < HID) ? W2l[(size_t)j * HID + k]
                      : W2r[(size_t)j * HID + (k - HID)];
}

// ---------------------------------------------------------------------------
// Layer-2 dense + log_softmax (from R3).
// Block = 256 threads; 32 rows/block; 8 threads per row, 8 cols per thread.
// ---------------------------------------------------------------------------
__global__ __launch_bounds__(256) void sage2_kernel(
    const float* __restrict__ h, const float* __restrict__ mean,
    const float* __restrict__ Wt, const float* __restrict__ b2,
    float* __restrict__ out) {
    const int t   = threadIdx.x;
    const int row = blockIdx.x * 32 + (t >> 3);
    const int jc  = (t & 7) * 8;
    if (row >= N3) return;

    float acc[8];
#pragma unroll
    for (int c = 0; c < 8; ++c) acc[c] = b2[jc + c];

    const float* __restrict__ arow = mean + (size_t)row * HID;
    const float* __restrict__ hrow = h    + (size_t)row * HID;

#pragma unroll 1
    for (int half = 0; half < 2; ++half) {
        const float* __restrict__ a = half ? hrow : arow;
        const float* __restrict__ w = Wt + (size_t)half * HID * OUTD + jc;
#pragma unroll 2
        for (int kc = 0; kc < HID / 4; ++kc) {
            float4 av = reinterpret_cast<const float4*>(a)[kc];
            const float* wk = w + (size_t)kc * 4 * OUTD;
            float ak[4] = {av.x, av.y, av.z, av.w};
#pragma unroll
            for (int kk = 0; kk < 4; ++kk) {
                float4 wa = *reinterpret_cast<const float4*>(wk + kk * OUTD);
                float4 wb = *reinterpret_cast<const float4*>(wk + kk * OUTD + 4);
                acc[0] += ak[kk] * wa.x; acc[1] += ak[kk] * wa.y;
                acc[2] += ak[kk] * wa.z; acc[3] += ak[kk] * wa.w;
                acc[4] += ak[kk] * wb.x; acc[5] += ak[kk] * wb.y;
                acc[6] += ak[kk] * wb.z; acc[7] += ak[kk] * wb.w;
            }
        }
    }

    // ---- log_softmax across the 8 lanes sharing this row ----
    float mx = acc[0];
#pragma unroll
    for (int c = 1; c < 8; ++c) mx = fmaxf(mx, acc[c]);
#pragma unroll
    for (int o = 1; o <= 4; o <<= 1) mx = fmaxf(mx, __shfl_xor(mx, o));
    float sum = 0.0f;
#pragma unroll
    for (int c = 0; c < 8; ++c) sum += __expf(acc[c] - mx);
#pragma unroll
    for (int o = 1; o <= 4; o <<= 1) sum += __shfl_xor(sum, o);
    const float lse = mx + __logf(sum);

    float4* op = reinterpret_cast<float4*>(out + (size_t)row * OUTD + jc);
    op[0] = make_float4(acc[0] - lse, acc[1] - lse, acc[2] - lse, acc[3] - lse);
    op[1] = make_float4(acc[4] - lse, acc[5] - lse, acc[6] - lse, acc[7] - lse);
}

// ---------------------------------------------------------------------------
extern "C" void kernel_launch(void* const* d_in, const int* in_sizes, int n_in,
                              void* d_out, int out_size, void* d_ws, size_t ws_size,
                              hipStream_t stream) {
    const float* x    = (const float*)d_in[0];
    const int*   src1 = (const int*)d_in[1];
    const int*   dst1 = (const int*)d_in[2];
    const int*   src2 = (const int*)d_in[3];
    const int*   dst2 = (const int*)d_in[4];
    const float* W1l  = (const float*)d_in[7];
    const float* W1r  = (const float*)d_in[8];
    const float* b1   = (const float*)d_in[9];
    const float* W2l  = (const float*)d_in[10];
    const float* W2r  = (const float*)d_in[11];
    const float* b2   = (const float*)d_in[12];
    float* out = (float*)d_out;

    const int E1 = in_sizes[1];
    const int E2 = in_sizes[3];

    // Workspace layout (bytes):
    //   A1b [40000][256] bf16 : 0           (20,480,000)  -- dead after sage1
    //   mean2 [10000][256] f32: 0           (10,240,000)  -- aliases A1b
    //   h    [40000][256] f32 : 20,480,000  (40,960,000)
    //   csr1                  : 61,440,000  ( 2,560,000)
    //   csr2 / Wb1 (bf16 128K): 64,000,000  (   640,000)  -- Wb1 dead after sage1
    //   deg1                  : 64,640,000  (   160,000)
    //   rowstart1             : 64,800,000  (   160,000)
    //   cursor1               : 64,960,000  (   160,000)
    //   deg2                  : 65,120,000  (    40,000)
    //   rowstart2             : 65,160,000  (    40,000)
    //   cursor2               : 65,200,000  (    40,000)
    //   Wt2 (f32)             : 65,240,000  (   131,072)  end 65,371,072
    char* ws = (char*)d_ws;
    unsigned short* A1b = (unsigned short*)(ws + 0);
    float* mean2     = (float*)(ws + 0);
    float* h         = (float*)(ws + 20480000);
    int*   csr1      = (int*)(ws + 61440000);
    int*   csr2      = (int*)(ws + 64000000);
    unsigned short* Wb1 = (unsigned short*)(ws + 64000000);
    int*   deg1      = (int*)(ws + 64640000);
    int*   rowstart1 = (int*)(ws + 64800000);
    int*   cursor1   = (int*)(ws + 64960000);
    int*   deg2      = (int*)(ws + 65120000);
    int*   rowstart2 = (int*)(ws + 65160000);
    int*   cursor2   = (int*)(ws + 65200000);
    float* Wt2       = (float*)(ws + 65240000);

    hipMemsetAsync(deg1, 0, (size_t)N2 * sizeof(int), stream);
    hipMemsetAsync(cursor1, 0, (size_t)N2 * sizeof(int), stream);
    hipMemsetAsync(deg2, 0, (size_t)N3 * sizeof(int), stream);
    hipMemsetAsync(cursor2, 0, (size_t)N3 * sizeof(int), stream);

    w2t_kernel<<<(2 * HID * OUTD + 255) / 256, 256, 0, stream>>>(W2l, W2r, Wt2);
    w1b_kernel<<<(2 * IND * HID + 255) / 256, 256, 0, stream>>>(W1l, W1r, Wb1);
    xcvt_kernel<<<(N2 * 32 + 255) / 256, 256, 0, stream>>>(x, A1b);

    // ---- layer 1: CSR build + gather-mean(bf16) + MFMA dense ----
    hist_kernel<<<(E1 + 255) / 256, 256, 0, stream>>>(dst1, E1, deg1);
    scan_kernel<<<1, 1024, 0, stream>>>(deg1, N2, rowstart1);
    fill_kernel<<<(E1 + 255) / 256, 256, 0, stream>>>(src1, dst1, E1,
                                                      rowstart1, cursor1, csr1);
    gather1_kernel<<<N2 / 4, 256, 0, stream>>>(x, csr1, rowstart1, deg1, A1b);
    {
        dim3 grid(N2 / 64, HID / 128);
        sage1_kernel<<<grid, 256, 0, stream>>>(A1b, Wb1, b1, h);
    }

    // ---- layer 2 (CSR build AFTER sage1: csr2 overwrites Wb1) ----
    hist_kernel<<<(E2 + 255) / 256, 256, 0, stream>>>(dst2, E2, deg2);
    scan_kernel<<<1, 1024, 0, stream>>>(deg2, N3, rowstart2);
    fill_kernel<<<(E2 + 255) / 256, 256, 0, stream>>>(src2, dst2, E2,
                                                      rowstart2, cursor2, csr2);
    gather2_kernel<<<N3 / 4, 256, 0, stream>>>(h, csr2, rowstart2, deg2, mean2);
    sage2_kernel<<<(N3 + 31) / 32, 256, 0, stream>>>(h, mean2, Wt2, b2, out);
}

// Round 9
// 298.656 us; speedup vs baseline: 9.9321x; 1.2056x over previous
//
#include <hip/hip_runtime.h>

// Problem constants (fixed by the reference)
static constexpr int N1  = 200000;
static constexpr int N2  = 40000;
static constexpr int N3  = 10000;
static constexpr int IND = 128;
static constexpr int HID = 256;
static constexpr int OUTD = 64;

using f32x4  = __attribute__((ext_vector_type(4))) float;
using bf16x8 = __attribute__((ext_vector_type(8))) short;  // 8 bf16 (4 VGPRs)

// round-to-nearest-even f32 -> bf16 (finite inputs)
__device__ __forceinline__ unsigned short f2bf(float f) {
    unsigned int u = __float_as_uint(f);
    u += 0x7FFFu + ((u >> 16) & 1u);
    return (unsigned short)(u >> 16);
}
__device__ __forceinline__ float bf2f(unsigned short u) {
    return __uint_as_float((unsigned int)u << 16);
}

// ---------------------------------------------------------------------------
// CSR construction: degree histogram -> exclusive scan -> bucket fill.
// ---------------------------------------------------------------------------
__global__ void hist_kernel(const int* __restrict__ dst, int E,
                            int* __restrict__ deg) {
    int i = blockIdx.x * blockDim.x + threadIdx.x;
    if (i < E) atomicAdd(&deg[dst[i]], 1);
}

__global__ __launch_bounds__(1024) void scan_kernel(
    const int* __restrict__ deg, int n, int* __restrict__ rowstart) {
    __shared__ int part[1024];
    const int T = 1024, t = threadIdx.x;
    const int per = (n + T - 1) / T;
    const int beg = t * per;
    const int end = min(beg + per, n);
    int s = 0;
    for (int i = beg; i < end; ++i) s += deg[i];
    part[t] = s;
    __syncthreads();
    for (int off = 1; off < T; off <<= 1) {
        int v = (t >= off) ? part[t - off] : 0;
        __syncthreads();
        part[t] += v;
        __syncthreads();
    }
    int run = (t == 0) ? 0 : part[t - 1];   // exclusive prefix of this chunk
    for (int i = beg; i < end; ++i) { rowstart[i] = run; run += deg[i]; }
}

__global__ void fill_kernel(const int* __restrict__ src,
                            const int* __restrict__ dst, int E,
                            const int* __restrict__ rowstart,
                            int* __restrict__ cursor,
                            int* __restrict__ csr) {
    int i = blockIdx.x * blockDim.x + threadIdx.x;
    if (i < E) {
        int d = dst[i];
        int p = atomicAdd(&cursor[d], 1);
        csr[rowstart[d] + p] = src[i];
    }
}

// ---------------------------------------------------------------------------
// Gather-mean layer 1 -> bf16 into A1b cols [0,128). A1b row stride = 256.
// ---------------------------------------------------------------------------
__global__ __launch_bounds__(256) void gather1_kernel(
    const float* __restrict__ x, const int* __restrict__ csr,
    const int* __restrict__ rowstart, const int* __restrict__ deg,
    unsigned short* __restrict__ A1b) {
    const int node = blockIdx.x * 4 + (threadIdx.x >> 6);
    const int lane = threadIdx.x & 63;
    const int beg = rowstart[node];
    const int n   = deg[node];
    float2 acc0 = make_float2(0.f, 0.f), acc1 = make_float2(0.f, 0.f);
    int e = 0;
    for (; e + 1 < n; e += 2) {
        int s0 = csr[beg + e];
        int s1 = csr[beg + e + 1];
        float2 v0 = *reinterpret_cast<const float2*>(x + (size_t)s0 * IND + lane * 2);
        float2 v1 = *reinterpret_cast<const float2*>(x + (size_t)s1 * IND + lane * 2);
        acc0.x += v0.x; acc0.y += v0.y;
        acc1.x += v1.x; acc1.y += v1.y;
    }
    if (e < n) {
        int s0 = csr[beg + e];
        float2 v0 = *reinterpret_cast<const float2*>(x + (size_t)s0 * IND + lane * 2);
        acc0.x += v0.x; acc0.y += v0.y;
    }
    const float inv = (n > 0) ? 1.0f / (float)n : 0.0f;
    unsigned int packed = (unsigned int)f2bf((acc0.x + acc1.x) * inv)
                        | ((unsigned int)f2bf((acc0.y + acc1.y) * inv) << 16);
    *reinterpret_cast<unsigned int*>(A1b + (size_t)node * 256 + lane * 2) = packed;
}

// ---------------------------------------------------------------------------
// x rows [0,N2) -> bf16 into A1b cols [128,256).
// ---------------------------------------------------------------------------
__global__ void xcvt_kernel(const float* __restrict__ x,
                            unsigned short* __restrict__ A1b) {
    int i = blockIdx.x * blockDim.x + threadIdx.x;   // over N2*32
    if (i >= N2 * 32) return;
    int row = i >> 5, c4 = (i & 31) * 4;
    float4 v = *reinterpret_cast<const float4*>(x + (size_t)row * IND + c4);
    unsigned int lo = (unsigned int)f2bf(v.x) | ((unsigned int)f2bf(v.y) << 16);
    unsigned int hi = (unsigned int)f2bf(v.z) | ((unsigned int)f2bf(v.w) << 16);
    *reinterpret_cast<uint2*>(A1b + (size_t)row * 256 + 128 + c4) =
        make_uint2(lo, hi);
}

// ---------------------------------------------------------------------------
// Layer-1 weights -> bf16 concat Wb[j][k]: k<128 from W1l[j][k], else W1r.
// ---------------------------------------------------------------------------
__global__ void w1b_kernel(const float* __restrict__ W1l,
                           const float* __restrict__ W1r,
                           unsigned short* __restrict__ Wb) {
    int i = blockIdx.x * blockDim.x + threadIdx.x;   // over 256*256
    if (i >= HID * 2 * IND) return;
    int j = i >> 8, k = i & 255;
    float v = (k < IND) ? W1l[(size_t)j * IND + k]
                        : W1r[(size_t)j * IND + (k - IND)];
    Wb[i] = (short)f2bf(v);
}

// ---------------------------------------------------------------------------
// Layer-2 weights -> bf16 concat W2b[j][k] (j<64, k<512): k<256 W2l else W2r.
// ---------------------------------------------------------------------------
__global__ void w2b_kernel(const float* __restrict__ W2l,
                           const float* __restrict__ W2r,
                           unsigned short* __restrict__ Wb) {
    int i = blockIdx.x * blockDim.x + threadIdx.x;   // over 64*512
    if (i >= OUTD * 2 * HID) return;
    int j = i >> 9, k = i & 511;
    float v = (k < HID) ? W2l[(size_t)j * HID + k]
                        : W2r[(size_t)j * HID + (k - HID)];
    Wb[i] = (short)f2bf(v);
}

// ---------------------------------------------------------------------------
// Layer-1 dense GEMM on MFMA (bf16 in, fp32 accum), bf16 h output.
//   h = relu(A1b @ Wb^T + b1), M=40000, N=256, K=256.
// Block = 4 waves (2M x 2N); wave tile 32x64 = 2x4 frags of 16x16x32.
// ---------------------------------------------------------------------------
__global__ __launch_bounds__(256) void sage1_kernel(
    const unsigned short* __restrict__ A1b,
    const unsigned short* __restrict__ Wb,
    const float* __restrict__ b1,
    unsigned short* __restrict__ hb) {
    const int t    = threadIdx.x;
    const int wave = t >> 6;
    const int lane = t & 63;
    const int l15  = lane & 15;
    const int kh   = lane >> 4;              // 0..3
    const int wm   = wave >> 1;              // 0..1
    const int wn   = wave & 1;               // 0..1
    const int row0 = blockIdx.x * 64 + wm * 32;    // 625*64 == 40000 exact
    const int col0 = blockIdx.y * 128 + wn * 64;

    f32x4 acc[2][4];
#pragma unroll
    for (int m = 0; m < 2; ++m)
#pragma unroll
        for (int n = 0; n < 4; ++n)
            acc[m][n] = (f32x4){0.f, 0.f, 0.f, 0.f};

#pragma unroll
    for (int ks = 0; ks < 8; ++ks) {
        const int k0 = ks * 32 + kh * 8;
        bf16x8 a[2], b[4];
#pragma unroll
        for (int m = 0; m < 2; ++m)
            a[m] = *reinterpret_cast<const bf16x8*>(
                A1b + (size_t)(row0 + m * 16 + l15) * 256 + k0);
#pragma unroll
        for (int n = 0; n < 4; ++n)
            b[n] = *reinterpret_cast<const bf16x8*>(
                Wb + (size_t)(col0 + n * 16 + l15) * 256 + k0);
#pragma unroll
        for (int m = 0; m < 2; ++m)
#pragma unroll
            for (int n = 0; n < 4; ++n)
                acc[m][n] = __builtin_amdgcn_mfma_f32_16x16x32_bf16(
                    a[m], b[n], acc[m][n], 0, 0, 0);
    }

#pragma unroll
    for (int m = 0; m < 2; ++m) {
        const int r0 = row0 + m * 16 + kh * 4;
#pragma unroll
        for (int n = 0; n < 4; ++n) {
            const int c = col0 + n * 16 + l15;
            const float bias = b1[c];
#pragma unroll
            for (int j = 0; j < 4; ++j)
                hb[(size_t)(r0 + j) * HID + c] =
                    f2bf(fmaxf(acc[m][n][j] + bias, 0.0f));
        }
    }
}

// ---------------------------------------------------------------------------
// Gather-mean layer 2 (bf16 in, f32 accum, bf16 out).
// One wave per node; lane owns 4 cols (8 B/lane per edge row).
// ---------------------------------------------------------------------------
__global__ __launch_bounds__(256) void gather2_kernel(
    const unsigned short* __restrict__ hb, const int* __restrict__ csr,
    const int* __restrict__ rowstart, const int* __restrict__ deg,
    unsigned short* __restrict__ meanb) {
    const int node = blockIdx.x * 4 + (threadIdx.x >> 6);
    const int lane = threadIdx.x & 63;
    const int beg = rowstart[node];
    const int n   = deg[node];
    float a0 = 0.f, a1 = 0.f, a2 = 0.f, a3 = 0.f;
    float c0 = 0.f, c1 = 0.f, c2 = 0.f, c3 = 0.f;
    int e = 0;
    for (; e + 1 < n; e += 2) {
        int s0 = csr[beg + e];
        int s1 = csr[beg + e + 1];
        ushort4 v0 = *reinterpret_cast<const ushort4*>(hb + (size_t)s0 * HID + lane * 4);
        ushort4 v1 = *reinterpret_cast<const ushort4*>(hb + (size_t)s1 * HID + lane * 4);
        a0 += bf2f(v0.x); a1 += bf2f(v0.y); a2 += bf2f(v0.z); a3 += bf2f(v0.w);
        c0 += bf2f(v1.x); c1 += bf2f(v1.y); c2 += bf2f(v1.z); c3 += bf2f(v1.w);
    }
    if (e < n) {
        int s0 = csr[beg + e];
        ushort4 v0 = *reinterpret_cast<const ushort4*>(hb + (size_t)s0 * HID + lane * 4);
        a0 += bf2f(v0.x); a1 += bf2f(v0.y); a2 += bf2f(v0.z); a3 += bf2f(v0.w);
    }
    const float inv = (n > 0) ? 1.0f / (float)n : 0.0f;
    unsigned int lo = (unsigned int)f2bf((a0 + c0) * inv)
                    | ((unsigned int)f2bf((a1 + c1) * inv) << 16);
    unsigned int hi = (unsigned int)f2bf((a2 + c2) * inv)
                    | ((unsigned int)f2bf((a3 + c3) * inv) << 16);
    *reinterpret_cast<uint2*>(meanb + (size_t)node * HID + lane * 4) =
        make_uint2(lo, hi);
}

// ---------------------------------------------------------------------------
// Layer-2 dense GEMM on MFMA + in-register log_softmax.
//   out = logsoftmax([mean2b | hb[0:N3]] @ W2b^T + b2), M=10000, N=64, K=512.
// Block = 4 waves stacked in M; wave tile 16x64 = 1x4 frags.
// Row r's 64 outputs live in 4 regs x 16 lanes (one kh-group) ->
// log_softmax = in-lane max/sum over n + shfl_xor(1,2,4,8).
// ---------------------------------------------------------------------------
__global__ __launch_bounds__(256) void sage2_kernel(
    const unsigned short* __restrict__ hb,
    const unsigned short* __restrict__ meanb,
    const unsigned short* __restrict__ Wb,
    const float* __restrict__ b2,
    float* __restrict__ out) {
    const int t    = threadIdx.x;
    const int wave = t >> 6;
    const int lane = t & 63;
    const int l15  = lane & 15;
    const int kh   = lane >> 4;
    const int row0 = blockIdx.x * 64 + wave * 16;
    const int arow = min(row0 + l15, N3 - 1);   // clamp loads; stores guarded

    f32x4 acc[4];
#pragma unroll
    for (int n = 0; n < 4; ++n) acc[n] = (f32x4){0.f, 0.f, 0.f, 0.f};

#pragma unroll
    for (int half = 0; half < 2; ++half) {
        const unsigned short* __restrict__ A = half ? hb : meanb;
#pragma unroll
        for (int ks = 0; ks < 8; ++ks) {
            const int k0 = ks * 32 + kh * 8;
            bf16x8 a = *reinterpret_cast<const bf16x8*>(
                A + (size_t)arow * HID + k0);
            bf16x8 b[4];
#pragma unroll
            for (int n = 0; n < 4; ++n)
                b[n] = *reinterpret_cast<const bf16x8*>(
                    Wb + (size_t)(n * 16 + l15) * 512 + half * 256 + k0);
#pragma unroll
            for (int n = 0; n < 4; ++n)
                acc[n] = __builtin_amdgcn_mfma_f32_16x16x32_bf16(
                    a, b[n], acc[n], 0, 0, 0);
        }
    }

    // bias (col = n*16 + l15)
    float v[4][4];
#pragma unroll
    for (int n = 0; n < 4; ++n) {
        const float bn = b2[n * 16 + l15];
#pragma unroll
        for (int j = 0; j < 4; ++j) v[n][j] = acc[n][j] + bn;
    }

    // per output row j: reduce over n (in-lane) and l15 (16-lane group)
#pragma unroll
    for (int j = 0; j < 4; ++j) {
        float mx = fmaxf(fmaxf(v[0][j], v[1][j]), fmaxf(v[2][j], v[3][j]));
#pragma unroll
        for (int o = 1; o <= 8; o <<= 1) mx = fmaxf(mx, __shfl_xor(mx, o));
        float sm = 0.f;
#pragma unroll
        for (int n = 0; n < 4; ++n) sm += __expf(v[n][j] - mx);
#pragma unroll
        for (int o = 1; o <= 8; o <<= 1) sm += __shfl_xor(sm, o);
        const float lse = mx + __logf(sm);
        const int r = row0 + kh * 4 + j;
        if (r < N3) {
#pragma unroll
            for (int n = 0; n < 4; ++n)
                out[(size_t)r * OUTD + n * 16 + l15] = v[n][j] - lse;
        }
    }
}

// ---------------------------------------------------------------------------
extern "C" void kernel_launch(void* const* d_in, const int* in_sizes, int n_in,
                              void* d_out, int out_size, void* d_ws, size_t ws_size,
                              hipStream_t stream) {
    const float* x    = (const float*)d_in[0];
    const int*   src1 = (const int*)d_in[1];
    const int*   dst1 = (const int*)d_in[2];
    const int*   src2 = (const int*)d_in[3];
    const int*   dst2 = (const int*)d_in[4];
    const float* W1l  = (const float*)d_in[7];
    const float* W1r  = (const float*)d_in[8];
    const float* b1   = (const float*)d_in[9];
    const float* W2l  = (const float*)d_in[10];
    const float* W2r  = (const float*)d_in[11];
    const float* b2   = (const float*)d_in[12];
    float* out = (float*)d_out;

    const int E1 = in_sizes[1];
    const int E2 = in_sizes[3];

    // Workspace layout (bytes):
    //   A1b [40000][256] bf16 : 0           (20,480,000) -- dead after sage1
    //   mean2b [10000][256]bf16: 0          ( 5,120,000) -- aliases A1b
    //   hb   [40000][256] bf16: 20,480,000  (20,480,000)
    //   csr1                  : 61,440,000  ( 2,560,000)
    //   csr2 / Wb1 (bf16 128K): 64,000,000  (   640,000) -- Wb1 dead after sage1
    //   deg1                  : 64,640,000  (   160,000)
    //   rowstart1             : 64,800,000  (   160,000)
    //   cursor1               : 64,960,000  (   160,000)
    //   deg2                  : 65,120,000  (    40,000)
    //   rowstart2             : 65,160,000  (    40,000)
    //   cursor2               : 65,200,000  (    40,000)
    //   W2b (bf16 64x512)     : 65,240,000  (    65,536)  end 65,305,536
    char* ws = (char*)d_ws;
    unsigned short* A1b    = (unsigned short*)(ws + 0);
    unsigned short* mean2b = (unsigned short*)(ws + 0);
    unsigned short* hb     = (unsigned short*)(ws + 20480000);
    int*   csr1      = (int*)(ws + 61440000);
    int*   csr2      = (int*)(ws + 64000000);
    unsigned short* Wb1 = (unsigned short*)(ws + 64000000);
    int*   deg1      = (int*)(ws + 64640000);
    int*   rowstart1 = (int*)(ws + 64800000);
    int*   cursor1   = (int*)(ws + 64960000);
    int*   deg2      = (int*)(ws + 65120000);
    int*   rowstart2 = (int*)(ws + 65160000);
    int*   cursor2   = (int*)(ws + 65200000);
    unsigned short* W2b = (unsigned short*)(ws + 65240000);

    hipMemsetAsync(deg1, 0, (size_t)N2 * sizeof(int), stream);
    hipMemsetAsync(cursor1, 0, (size_t)N2 * sizeof(int), stream);
    hipMemsetAsync(deg2, 0, (size_t)N3 * sizeof(int), stream);
    hipMemsetAsync(cursor2, 0, (size_t)N3 * sizeof(int), stream);

    w2b_kernel<<<(OUTD * 2 * HID + 255) / 256, 256, 0, stream>>>(W2l, W2r, W2b);
    w1b_kernel<<<(2 * IND * HID + 255) / 256, 256, 0, stream>>>(W1l, W1r, Wb1);
    xcvt_kernel<<<(N2 * 32 + 255) / 256, 256, 0, stream>>>(x, A1b);

    // ---- layer 1: CSR build + gather-mean(bf16) + MFMA dense ----
    hist_kernel<<<(E1 + 255) / 256, 256, 0, stream>>>(dst1, E1, deg1);
    scan_kernel<<<1, 1024, 0, stream>>>(deg1, N2, rowstart1);
    fill_kernel<<<(E1 + 255) / 256, 256, 0, stream>>>(src1, dst1, E1,
                                                      rowstart1, cursor1, csr1);
    gather1_kernel<<<N2 / 4, 256, 0, stream>>>(x, csr1, rowstart1, deg1, A1b);
    {
        dim3 grid(N2 / 64, HID / 128);
        sage1_kernel<<<grid, 256, 0, stream>>>(A1b, Wb1, b1, hb);
    }

    // ---- layer 2 (CSR build AFTER sage1: csr2 overwrites Wb1) ----
    hist_kernel<<<(E2 + 255) / 256, 256, 0, stream>>>(dst2, E2, deg2);
    scan_kernel<<<1, 1024, 0, stream>>>(deg2, N3, rowstart2);
    fill_kernel<<<(E2 + 255) / 256, 256, 0, stream>>>(src2, dst2, E2,
                                                      rowstart2, cursor2, csr2);
    gather2_kernel<<<N3 / 4, 256, 0, stream>>>(hb, csr2, rowstart2, deg2, mean2b);
    sage2_kernel<<<(N3 + 63) / 64, 256, 0, stream>>>(hb, mean2b, W2b, b2, out);
}

// Round 10
// 276.218 us; speedup vs baseline: 10.7389x; 1.0812x over previous
//
#include <hip/hip_runtime.h>

// Problem constants (fixed by the reference)
static constexpr int N1  = 200000;
static constexpr int N2  = 40000;
static constexpr int N3  = 10000;
static constexpr int IND = 128;
static constexpr int HID = 256;
static constexpr int OUTD = 64;

using f32x4  = __attribute__((ext_vector_type(4))) float;
using bf16x8 = __attribute__((ext_vector_type(8))) short;  // 8 bf16 (4 VGPRs)

// round-to-nearest-even f32 -> bf16 (finite inputs)
__device__ __forceinline__ unsigned short f2bf(float f) {
    unsigned int u = __float_as_uint(f);
    u += 0x7FFFu + ((u >> 16) & 1u);
    return (unsigned short)(u >> 16);
}
__device__ __forceinline__ float bf2f(unsigned short u) {
    return __uint_as_float((unsigned int)u << 16);
}

// ---------------------------------------------------------------------------
// Fused CSR construction for BOTH layers: histogram -> scan -> fill.
// ---------------------------------------------------------------------------
__global__ void hist_both_kernel(const int* __restrict__ dst1, int E1,
                                 const int* __restrict__ dst2, int E2,
                                 int* __restrict__ deg1,
                                 int* __restrict__ deg2) {
    int i = blockIdx.x * blockDim.x + threadIdx.x;
    if (i < E1) atomicAdd(&deg1[dst1[i]], 1);
    else if (i - E1 < E2) atomicAdd(&deg2[dst2[i - E1]], 1);
}

__device__ __forceinline__ void scan_body(const int* __restrict__ deg, int n,
                                          int* __restrict__ rowstart,
                                          int* part) {
    const int T = 1024, t = threadIdx.x;
    const int per = (n + T - 1) / T;
    const int beg = t * per;
    const int end = min(beg + per, n);
    int s = 0;
    for (int i = beg; i < end; ++i) s += deg[i];
    part[t] = s;
    __syncthreads();
    for (int off = 1; off < T; off <<= 1) {
        int v = (t >= off) ? part[t - off] : 0;
        __syncthreads();
        part[t] += v;
        __syncthreads();
    }
    int run = (t == 0) ? 0 : part[t - 1];
    for (int i = beg; i < end; ++i) { rowstart[i] = run; run += deg[i]; }
}

__global__ __launch_bounds__(1024) void scan_both_kernel(
    const int* __restrict__ deg1, int* __restrict__ rowstart1,
    const int* __restrict__ deg2, int* __restrict__ rowstart2) {
    __shared__ int part[1024];
    if (blockIdx.x == 0) scan_body(deg1, N2, rowstart1, part);
    else                 scan_body(deg2, N3, rowstart2, part);
}

__global__ void fill_both_kernel(
    const int* __restrict__ src1, const int* __restrict__ dst1, int E1,
    const int* __restrict__ rowstart1, int* __restrict__ cursor1,
    int* __restrict__ csr1,
    const int* __restrict__ src2, const int* __restrict__ dst2, int E2,
    const int* __restrict__ rowstart2, int* __restrict__ cursor2,
    int* __restrict__ csr2) {
    int i = blockIdx.x * blockDim.x + threadIdx.x;
    if (i < E1) {
        int d = dst1[i];
        int p = atomicAdd(&cursor1[d], 1);
        csr1[rowstart1[d] + p] = src1[i];
    } else if (i - E1 < E2) {
        int j = i - E1;
        int d = dst2[j];
        int p = atomicAdd(&cursor2[d], 1);
        csr2[rowstart2[d] + p] = src2[j];
    }
}

// ---------------------------------------------------------------------------
// Whole-x f32 -> bf16 conversion (NEW path): xb[200000][128].
// ---------------------------------------------------------------------------
__global__ void xball_kernel(const float* __restrict__ x,
                             unsigned short* __restrict__ xb) {
    int i = blockIdx.x * blockDim.x + threadIdx.x;   // over N1*IND/8
    if (i >= N1 * IND / 8) return;
    const float4* p = reinterpret_cast<const float4*>(x + (size_t)i * 8);
    float4 v0 = p[0], v1 = p[1];
    uint4 u;
    u.x = (unsigned int)f2bf(v0.x) | ((unsigned int)f2bf(v0.y) << 16);
    u.y = (unsigned int)f2bf(v0.z) | ((unsigned int)f2bf(v0.w) << 16);
    u.z = (unsigned int)f2bf(v1.x) | ((unsigned int)f2bf(v1.y) << 16);
    u.w = (unsigned int)f2bf(v1.z) | ((unsigned int)f2bf(v1.w) << 16);
    *reinterpret_cast<uint4*>(xb + (size_t)i * 8) = u;
}

// ---------------------------------------------------------------------------
// OLD path: x rows [0,N2) -> bf16 into A1b cols [128,256), stride 256.
// ---------------------------------------------------------------------------
__global__ void xcvt_kernel(const float* __restrict__ x,
                            unsigned short* __restrict__ A1b) {
    int i = blockIdx.x * blockDim.x + threadIdx.x;   // over N2*32
    if (i >= N2 * 32) return;
    int row = i >> 5, c4 = (i & 31) * 4;
    float4 v = *reinterpret_cast<const float4*>(x + (size_t)row * IND + c4);
    unsigned int lo = (unsigned int)f2bf(v.x) | ((unsigned int)f2bf(v.y) << 16);
    unsigned int hi = (unsigned int)f2bf(v.z) | ((unsigned int)f2bf(v.w) << 16);
    *reinterpret_cast<uint2*>(A1b + (size_t)row * 256 + 128 + c4) =
        make_uint2(lo, hi);
}

// ---------------------------------------------------------------------------
// Weight conversions to bf16 (j-major, k contiguous = MFMA B-frag layout).
// ---------------------------------------------------------------------------
__global__ void w1b_kernel(const float* __restrict__ W1l,
                           const float* __restrict__ W1r,
                           unsigned short* __restrict__ Wb) {
    int i = blockIdx.x * blockDim.x + threadIdx.x;   // over 256*256
    if (i >= HID * 2 * IND) return;
    int j = i >> 8, k = i & 255;
    float v = (k < IND) ? W1l[(size_t)j * IND + k]
                        : W1r[(size_t)j * IND + (k - IND)];
    Wb[i] = (short)f2bf(v);
}

__global__ void w2b_kernel(const float* __restrict__ W2l,
                           const float* __restrict__ W2r,
                           unsigned short* __restrict__ Wb) {
    int i = blockIdx.x * blockDim.x + threadIdx.x;   // over 64*512
    if (i >= OUTD * 2 * HID) return;
    int j = i >> 9, k = i & 511;
    float v = (k < HID) ? W2l[(size_t)j * HID + k]
                        : W2r[(size_t)j * HID + (k - HID)];
    Wb[i] = (short)f2bf(v);
}

// ---------------------------------------------------------------------------
// NEW path gather-mean layer 1: bf16 gather from xb -> mean1b[40000][128].
// One wave per node; lane owns 2 cols (4 B/edge/lane, 256 B/edge/wave).
// ---------------------------------------------------------------------------
__global__ __launch_bounds__(256) void gather1b_kernel(
    const unsigned short* __restrict__ xb, const int* __restrict__ csr,
    const int* __restrict__ rowstart, const int* __restrict__ deg,
    unsigned short* __restrict__ meanb) {
    const int node = blockIdx.x * 4 + (threadIdx.x >> 6);
    const int lane = threadIdx.x & 63;
    const int beg = rowstart[node];
    const int n   = deg[node];
    float a0 = 0.f, a1 = 0.f, c0 = 0.f, c1 = 0.f;
    int e = 0;
    for (; e + 1 < n; e += 2) {
        int s0 = csr[beg + e];
        int s1 = csr[beg + e + 1];
        unsigned int v0 = *reinterpret_cast<const unsigned int*>(
            xb + (size_t)s0 * IND + lane * 2);
        unsigned int v1 = *reinterpret_cast<const unsigned int*>(
            xb + (size_t)s1 * IND + lane * 2);
        a0 += bf2f((unsigned short)v0); a1 += bf2f((unsigned short)(v0 >> 16));
        c0 += bf2f((unsigned short)v1); c1 += bf2f((unsigned short)(v1 >> 16));
    }
    if (e < n) {
        int s0 = csr[beg + e];
        unsigned int v0 = *reinterpret_cast<const unsigned int*>(
            xb + (size_t)s0 * IND + lane * 2);
        a0 += bf2f((unsigned short)v0); a1 += bf2f((unsigned short)(v0 >> 16));
    }
    const float inv = (n > 0) ? 1.0f / (float)n : 0.0f;
    unsigned int packed = (unsigned int)f2bf((a0 + c0) * inv)
                        | ((unsigned int)f2bf((a1 + c1) * inv) << 16);
    *reinterpret_cast<unsigned int*>(meanb + (size_t)node * IND + lane * 2) = packed;
}

// ---------------------------------------------------------------------------
// OLD path gather-mean layer 1: fp32 gather from x -> A1b cols [0,128).
// ---------------------------------------------------------------------------
__global__ __launch_bounds__(256) void gather1_kernel(
    const float* __restrict__ x, const int* __restrict__ csr,
    const int* __restrict__ rowstart, const int* __restrict__ deg,
    unsigned short* __restrict__ A1b) {
    const int node = blockIdx.x * 4 + (threadIdx.x >> 6);
    const int lane = threadIdx.x & 63;
    const int beg = rowstart[node];
    const int n   = deg[node];
    float2 acc0 = make_float2(0.f, 0.f), acc1 = make_float2(0.f, 0.f);
    int e = 0;
    for (; e + 1 < n; e += 2) {
        int s0 = csr[beg + e];
        int s1 = csr[beg + e + 1];
        float2 v0 = *reinterpret_cast<const float2*>(x + (size_t)s0 * IND + lane * 2);
        float2 v1 = *reinterpret_cast<const float2*>(x + (size_t)s1 * IND + lane * 2);
        acc0.x += v0.x; acc0.y += v0.y;
        acc1.x += v1.x; acc1.y += v1.y;
    }
    if (e < n) {
        int s0 = csr[beg + e];
        float2 v0 = *reinterpret_cast<const float2*>(x + (size_t)s0 * IND + lane * 2);
        acc0.x += v0.x; acc0.y += v0.y;
    }
    const float inv = (n > 0) ? 1.0f / (float)n : 0.0f;
    unsigned int packed = (unsigned int)f2bf((acc0.x + acc1.x) * inv)
                        | ((unsigned int)f2bf((acc0.y + acc1.y) * inv) << 16);
    *reinterpret_cast<unsigned int*>(A1b + (size_t)node * 256 + lane * 2) = packed;
}

// ---------------------------------------------------------------------------
// Layer-1 dense GEMM on MFMA, two-pointer A (mean half / x half).
//   h = relu([Am | Ax] @ Wb^T + b1), M=40000, N=256, K=256. bf16 out.
// Block = 4 waves (2M x 2N); wave tile 32x64 = 2x4 frags of 16x16x32.
// ---------------------------------------------------------------------------
__global__ __launch_bounds__(256) void sage1_kernel(
    const unsigned short* __restrict__ Am, int sM,
    const unsigned short* __restrict__ Ax, int sX,
    const unsigned short* __restrict__ Wb,
    const float* __restrict__ b1,
    unsigned short* __restrict__ hb) {
    const int t    = threadIdx.x;
    const int wave = t >> 6;
    const int lane = t & 63;
    const int l15  = lane & 15;
    const int kh   = lane >> 4;              // 0..3
    const int wm   = wave >> 1;              // 0..1
    const int wn   = wave & 1;               // 0..1
    const int row0 = blockIdx.x * 64 + wm * 32;    // 625*64 == 40000 exact
    const int col0 = blockIdx.y * 128 + wn * 64;

    f32x4 acc[2][4];
#pragma unroll
    for (int m = 0; m < 2; ++m)
#pragma unroll
        for (int n = 0; n < 4; ++n)
            acc[m][n] = (f32x4){0.f, 0.f, 0.f, 0.f};

#pragma unroll
    for (int ks = 0; ks < 8; ++ks) {
        const unsigned short* __restrict__ Ab = (ks < 4) ? Am : Ax;
        const int sA = (ks < 4) ? sM : sX;
        const int k0 = (ks & 3) * 32 + kh * 8;
        bf16x8 a[2], b[4];
#pragma unroll
        for (int m = 0; m < 2; ++m)
            a[m] = *reinterpret_cast<const bf16x8*>(
                Ab + (size_t)(row0 + m * 16 + l15) * sA + k0);
#pragma unroll
        for (int n = 0; n < 4; ++n)
            b[n] = *reinterpret_cast<const bf16x8*>(
                Wb + (size_t)(col0 + n * 16 + l15) * 256 + ks * 32 + kh * 8);
#pragma unroll
        for (int m = 0; m < 2; ++m)
#pragma unroll
            for (int n = 0; n < 4; ++n)
                acc[m][n] = __builtin_amdgcn_mfma_f32_16x16x32_bf16(
                    a[m], b[n], acc[m][n], 0, 0, 0);
    }

#pragma unroll
    for (int m = 0; m < 2; ++m) {
        const int r0 = row0 + m * 16 + kh * 4;
#pragma unroll
        for (int n = 0; n < 4; ++n) {
            const int c = col0 + n * 16 + l15;
            const float bias = b1[c];
#pragma unroll
            for (int j = 0; j < 4; ++j)
                hb[(size_t)(r0 + j) * HID + c] =
                    f2bf(fmaxf(acc[m][n][j] + bias, 0.0f));
        }
    }
}

// ---------------------------------------------------------------------------
// Gather-mean layer 2 (bf16 in, f32 accum, bf16 out).
// ---------------------------------------------------------------------------
__global__ __launch_bounds__(256) void gather2_kernel(
    const unsigned short* __restrict__ hb, const int* __restrict__ csr,
    const int* __restrict__ rowstart, const int* __restrict__ deg,
    unsigned short* __restrict__ meanb) {
    const int node = blockIdx.x * 4 + (threadIdx.x >> 6);
    const int lane = threadIdx.x & 63;
    const int beg = rowstart[node];
    const int n   = deg[node];
    float a0 = 0.f, a1 = 0.f, a2 = 0.f, a3 = 0.f;
    float c0 = 0.f, c1 = 0.f, c2 = 0.f, c3 = 0.f;
    int e = 0;
    for (; e + 1 < n; e += 2) {
        int s0 = csr[beg + e];
        int s1 = csr[beg + e + 1];
        ushort4 v0 = *reinterpret_cast<const ushort4*>(hb + (size_t)s0 * HID + lane * 4);
        ushort4 v1 = *reinterpret_cast<const ushort4*>(hb + (size_t)s1 * HID + lane * 4);
        a0 += bf2f(v0.x); a1 += bf2f(v0.y); a2 += bf2f(v0.z); a3 += bf2f(v0.w);
        c0 += bf2f(v1.x); c1 += bf2f(v1.y); c2 += bf2f(v1.z); c3 += bf2f(v1.w);
    }
    if (e < n) {
        int s0 = csr[beg + e];
        ushort4 v0 = *reinterpret_cast<const ushort4*>(hb + (size_t)s0 * HID + lane * 4);
        a0 += bf2f(v0.x); a1 += bf2f(v0.y); a2 += bf2f(v0.z); a3 += bf2f(v0.w);
    }
    const float inv = (n > 0) ? 1.0f / (float)n : 0.0f;
    unsigned int lo = (unsigned int)f2bf((a0 + c0) * inv)
                    | ((unsigned int)f2bf((a1 + c1) * inv) << 16);
    unsigned int hi = (unsigned int)f2bf((a2 + c2) * inv)
                    | ((unsigned int)f2bf((a3 + c3) * inv) << 16);
    *reinterpret_cast<uint2*>(meanb + (size_t)node * HID + lane * 4) =
        make_uint2(lo, hi);
}

// ---------------------------------------------------------------------------
// Layer-2 dense GEMM on MFMA + in-register log_softmax.
// ---------------------------------------------------------------------------
__global__ __launch_bounds__(256) void sage2_kernel(
    const unsigned short* __restrict__ hb,
    const unsigned short* __restrict__ meanb,
    const unsigned short* __restrict__ Wb,
    const float* __restrict__ b2,
    float* __restrict__ out) {
    const int t    = threadIdx.x;
    const int wave = t >> 6;
    const int lane = t & 63;
    const int l15  = lane & 15;
    const int kh   = lane >> 4;
    const int row0 = blockIdx.x * 64 + wave * 16;
    const int arow = min(row0 + l15, N3 - 1);   // clamp loads; stores guarded

    f32x4 acc[4];
#pragma unroll
    for (int n = 0; n < 4; ++n) acc[n] = (f32x4){0.f, 0.f, 0.f, 0.f};

#pragma unroll
    for (int half = 0; half < 2; ++half) {
        const unsigned short* __restrict__ A = half ? hb : meanb;
#pragma unroll
        for (int ks = 0; ks < 8; ++ks) {
            const int k0 = ks * 32 + kh * 8;
            bf16x8 a = *reinterpret_cast<const bf16x8*>(
                A + (size_t)arow * HID + k0);
            bf16x8 b[4];
#pragma unroll
            for (int n = 0; n < 4; ++n)
                b[n] = *reinterpret_cast<const bf16x8*>(
                    Wb + (size_t)(n * 16 + l15) * 512 + half * 256 + k0);
#pragma unroll
            for (int n = 0; n < 4; ++n)
                acc[n] = __builtin_amdgcn_mfma_f32_16x16x32_bf16(
                    a, b[n], acc[n], 0, 0, 0);
        }
    }

    float v[4][4];
#pragma unroll
    for (int n = 0; n < 4; ++n) {
        const float bn = b2[n * 16 + l15];
#pragma unroll
        for (int j = 0; j < 4; ++j) v[n][j] = acc[n][j] + bn;
    }

#pragma unroll
    for (int j = 0; j < 4; ++j) {
        float mx = fmaxf(fmaxf(v[0][j], v[1][j]), fmaxf(v[2][j], v[3][j]));
#pragma unroll
        for (int o = 1; o <= 8; o <<= 1) mx = fmaxf(mx, __shfl_xor(mx, o));
        float sm = 0.f;
#pragma unroll
        for (int n = 0; n < 4; ++n) sm += __expf(v[n][j] - mx);
#pragma unroll
        for (int o = 1; o <= 8; o <<= 1) sm += __shfl_xor(sm, o);
        const float lse = mx + __logf(sm);
        const int r = row0 + kh * 4 + j;
        if (r < N3) {
#pragma unroll
            for (int n = 0; n < 4; ++n)
                out[(size_t)r * OUTD + n * 16 + l15] = v[n][j] - lse;
        }
    }
}

// ---------------------------------------------------------------------------
extern "C" void kernel_launch(void* const* d_in, const int* in_sizes, int n_in,
                              void* d_out, int out_size, void* d_ws, size_t ws_size,
                              hipStream_t stream) {
    const float* x    = (const float*)d_in[0];
    const int*   src1 = (const int*)d_in[1];
    const int*   dst1 = (const int*)d_in[2];
    const int*   src2 = (const int*)d_in[3];
    const int*   dst2 = (const int*)d_in[4];
    const float* W1l  = (const float*)d_in[7];
    const float* W1r  = (const float*)d_in[8];
    const float* b1   = (const float*)d_in[9];
    const float* W2l  = (const float*)d_in[10];
    const float* W2r  = (const float*)d_in[11];
    const float* b2   = (const float*)d_in[12];
    float* out = (float*)d_out;

    const int E1 = in_sizes[1];
    const int E2 = in_sizes[3];

    // NEW layout (needs ~86 MB): full-x bf16 copy, mean1b separate.
    static constexpr size_t NEED_NEW = 85916608;
    const bool big = ws_size >= NEED_NEW;

    char* ws = (char*)d_ws;
    unsigned short *mean1b, *mean2b, *hb, *xb = nullptr, *A1b = nullptr;
    unsigned short *W2b, *Wb1;
    int *csr1, *csr2, *deg1, *cursor1, *deg2, *cursor2, *rowstart1, *rowstart2;
    char* z0;   // start of the contiguous {deg1,cursor1,deg2,cursor2} block

    if (big) {
        mean1b   = (unsigned short*)(ws + 0);           // 10,240,000
        mean2b   = (unsigned short*)(ws + 0);           // aliases (5.12 MB)
        hb       = (unsigned short*)(ws + 10240000);    // 20,480,000
        xb       = (unsigned short*)(ws + 30720000);    // 51,200,000
        csr1     = (int*)(ws + 81920000);               //  2,560,000
        csr2     = (int*)(ws + 84480000);               //    640,000
        deg1     = (int*)(ws + 85120000);
        cursor1  = (int*)(ws + 85280000);
        deg2     = (int*)(ws + 85440000);
        cursor2  = (int*)(ws + 85480000);
        rowstart1= (int*)(ws + 85520000);
        rowstart2= (int*)(ws + 85680000);
        W2b      = (unsigned short*)(ws + 85720000);
        Wb1      = (unsigned short*)(ws + 85785536);    // end 85,916,608
        z0 = ws + 85120000;
    } else {
        A1b      = (unsigned short*)(ws + 0);           // 20,480,000
        mean1b   = nullptr;
        mean2b   = (unsigned short*)(ws + 0);
        hb       = (unsigned short*)(ws + 20480000);    // 20,480,000
        csr1     = (int*)(ws + 40960000);               //  2,560,000
        csr2     = (int*)(ws + 43520000);               //    640,000
        deg1     = (int*)(ws + 44160000);
        cursor1  = (int*)(ws + 44320000);
        deg2     = (int*)(ws + 44480000);
        cursor2  = (int*)(ws + 44520000);
        rowstart1= (int*)(ws + 44560000);
        rowstart2= (int*)(ws + 44720000);
        W2b      = (unsigned short*)(ws + 44760000);
        Wb1      = (unsigned short*)(ws + 44825536);    // end 44,956,608
        z0 = ws + 44160000;
    }

    // one memset covers deg1|cursor1|deg2|cursor2 (contiguous 400,000 B)
    hipMemsetAsync(z0, 0, 400000, stream);

    if (big) {
        xball_kernel<<<(N1 * IND / 8 + 255) / 256, 256, 0, stream>>>(x, xb);
    } else {
        xcvt_kernel<<<(N2 * 32 + 255) / 256, 256, 0, stream>>>(x, A1b);
    }
    w1b_kernel<<<(2 * IND * HID + 255) / 256, 256, 0, stream>>>(W1l, W1r, Wb1);
    w2b_kernel<<<(OUTD * 2 * HID + 255) / 256, 256, 0, stream>>>(W2l, W2r, W2b);

    // ---- fused CSR build for both layers ----
    {
        int tot = E1 + E2;
        hist_both_kernel<<<(tot + 255) / 256, 256, 0, stream>>>(
            dst1, E1, dst2, E2, deg1, deg2);
        scan_both_kernel<<<2, 1024, 0, stream>>>(deg1, rowstart1, deg2, rowstart2);
        fill_both_kernel<<<(tot + 255) / 256, 256, 0, stream>>>(
            src1, dst1, E1, rowstart1, cursor1, csr1,
            src2, dst2, E2, rowstart2, cursor2, csr2);
    }

    // ---- layer 1: gather-mean + MFMA dense ----
    if (big) {
        gather1b_kernel<<<N2 / 4, 256, 0, stream>>>(xb, csr1, rowstart1, deg1,
                                                    mean1b);
        dim3 grid(N2 / 64, HID / 128);
        sage1_kernel<<<grid, 256, 0, stream>>>(mean1b, IND, xb, IND, Wb1, b1, hb);
    } else {
        gather1_kernel<<<N2 / 4, 256, 0, stream>>>(x, csr1, rowstart1, deg1, A1b);
        dim3 grid(N2 / 64, HID / 128);
        sage1_kernel<<<grid, 256, 0, stream>>>(A1b, HID, A1b + 128, HID, Wb1,
                                               b1, hb);
    }

    // ---- layer 2: gather-mean + MFMA dense + log_softmax ----
    gather2_kernel<<<N3 / 4, 256, 0, stream>>>(hb, csr2, rowstart2, deg2, mean2b);
    sage2_kernel<<<(N3 + 63) / 64, 256, 0, stream>>>(hb, mean2b, W2b, b2, out);
}

// Round 11
// 219.709 us; speedup vs baseline: 13.5009x; 1.2572x over previous
//
#include <hip/hip_runtime.h>

// Problem constants (fixed by the reference)
static constexpr int N1  = 200000;
static constexpr int N2  = 40000;
static constexpr int N3  = 10000;
static constexpr int IND = 128;
static constexpr int HID = 256;
static constexpr int OUTD = 64;

using f32x4  = __attribute__((ext_vector_type(4))) float;
using bf16x8 = __attribute__((ext_vector_type(8))) short;  // 8 bf16 (4 VGPRs)

// round-to-nearest-even f32 -> bf16 (finite inputs)
__device__ __forceinline__ unsigned short f2bf(float f) {
    unsigned int u = __float_as_uint(f);
    u += 0x7FFFu + ((u >> 16) & 1u);
    return (unsigned short)(u >> 16);
}
__device__ __forceinline__ float bf2f(unsigned short u) {
    return __uint_as_float((unsigned int)u << 16);
}

// ---------------------------------------------------------------------------
// Fused histogram for both layers.
// ---------------------------------------------------------------------------
__global__ void hist_both_kernel(const int* __restrict__ dst1, int E1,
                                 const int* __restrict__ dst2, int E2,
                                 int* __restrict__ deg1,
                                 int* __restrict__ deg2) {
    int i = blockIdx.x * blockDim.x + threadIdx.x;
    if (i < E1) atomicAdd(&deg1[dst1[i]], 1);
    else if (i - E1 < E2) atomicAdd(&deg2[dst2[i - E1]], 1);
}

// ---------------------------------------------------------------------------
// Reduce-then-scan over concatenated {deg1 (40 blocks), deg2 (10 blocks)}.
// CHUNK=1024 elems/block. Tail reads run past deg into the adjacent ZEROED
// cursor buffers (memset covers deg1|cursor1|deg2|cursor2) -> no load guards.
// ---------------------------------------------------------------------------
static constexpr int SCAN_NB1 = (N2 + 1023) / 1024;   // 40
static constexpr int SCAN_NB2 = (N3 + 1023) / 1024;   // 10
static constexpr int SCAN_NB  = SCAN_NB1 + SCAN_NB2;  // 50

__global__ __launch_bounds__(256) void scan1_kernel(
    const int* __restrict__ deg1, const int* __restrict__ deg2,
    int* __restrict__ blocksum) {
    const int b = blockIdx.x;
    const int t = threadIdx.x;
    const int lane = t & 63, wid = t >> 6;
    const int* __restrict__ deg = (b < SCAN_NB1) ? deg1 : deg2;
    const int base = (b < SCAN_NB1 ? b : b - SCAN_NB1) * 1024;
    int4 v = *reinterpret_cast<const int4*>(deg + base + t * 4);
    int s = v.x + v.y + v.z + v.w;
#pragma unroll
    for (int o = 1; o < 64; o <<= 1) s += __shfl_xor(s, o);
    __shared__ int wsum[4];
    if (lane == 0) wsum[wid] = s;
    __syncthreads();
    if (t == 0) blocksum[b] = wsum[0] + wsum[1] + wsum[2] + wsum[3];
}

__global__ __launch_bounds__(64) void scan2_kernel(
    const int* __restrict__ blocksum, int* __restrict__ blockoff) {
    const int lane = threadIdx.x & 63;
    int bs = (lane < SCAN_NB) ? blocksum[lane] : 0;
    int incl = bs;
#pragma unroll
    for (int o = 1; o < 64; o <<= 1) {
        int v = __shfl_up(incl, o);
        if (lane >= o) incl += v;
    }
    const int total1 = __shfl(incl, SCAN_NB1 - 1);
    if (lane < SCAN_NB) {
        int excl = incl - bs;
        blockoff[lane] = (lane < SCAN_NB1) ? excl : excl - total1;
    }
}

__global__ __launch_bounds__(256) void scan3_kernel(
    const int* __restrict__ deg1, int* __restrict__ rowstart1,
    const int* __restrict__ deg2, int* __restrict__ rowstart2,
    const int* __restrict__ blockoff) {
    const int b = blockIdx.x;
    const int t = threadIdx.x;
    const int lane = t & 63, wid = t >> 6;
    const bool seg0 = (b < SCAN_NB1);
    const int* __restrict__ deg = seg0 ? deg1 : deg2;
    int* __restrict__ rowstart  = seg0 ? rowstart1 : rowstart2;
    const int n    = seg0 ? N2 : N3;
    const int base = (seg0 ? b : b - SCAN_NB1) * 1024;

    int4 v = *reinterpret_cast<const int4*>(deg + base + t * 4);
    int t4 = v.x + v.y + v.z + v.w;
    int incl = t4;
#pragma unroll
    for (int o = 1; o < 64; o <<= 1) {
        int u = __shfl_up(incl, o);
        if (lane >= o) incl += u;
    }
    __shared__ int wsum[4];
    if (lane == 63) wsum[wid] = incl;
    __syncthreads();
    int wpre = 0;
#pragma unroll
    for (int w = 0; w < 4; ++w) wpre += (w < wid) ? wsum[w] : 0;

    int rs = blockoff[b] + wpre + (incl - t4);
    const int idx = base + t * 4;
    if (idx + 0 < n) rowstart[idx + 0] = rs;  rs += v.x;
    if (idx + 1 < n) rowstart[idx + 1] = rs;  rs += v.y;
    if (idx + 2 < n) rowstart[idx + 2] = rs;  rs += v.z;
    if (idx + 3 < n) rowstart[idx + 3] = rs;
}

// ---------------------------------------------------------------------------
// Fused CSR fill for both layers.
// ---------------------------------------------------------------------------
__global__ void fill_both_kernel(
    const int* __restrict__ src1, const int* __restrict__ dst1, int E1,
    const int* __restrict__ rowstart1, int* __restrict__ cursor1,
    int* __restrict__ csr1,
    const int* __restrict__ src2, const int* __restrict__ dst2, int E2,
    const int* __restrict__ rowstart2, int* __restrict__ cursor2,
    int* __restrict__ csr2) {
    int i = blockIdx.x * blockDim.x + threadIdx.x;
    if (i < E1) {
        int d = dst1[i];
        int p = atomicAdd(&cursor1[d], 1);
        csr1[rowstart1[d] + p] = src1[i];
    } else if (i - E1 < E2) {
        int j = i - E1;
        int d = dst2[j];
        int p = atomicAdd(&cursor2[d], 1);
        csr2[rowstart2[d] + p] = src2[j];
    }
}

// ---------------------------------------------------------------------------
// Whole-x f32 -> bf16 conversion (NEW path): xb[200000][128].
// ---------------------------------------------------------------------------
__global__ void xball_kernel(const float* __restrict__ x,
                             unsigned short* __restrict__ xb) {
    int i = blockIdx.x * blockDim.x + threadIdx.x;   // over N1*IND/8
    if (i >= N1 * IND / 8) return;
    const float4* p = reinterpret_cast<const float4*>(x + (size_t)i * 8);
    float4 v0 = p[0], v1 = p[1];
    uint4 u;
    u.x = (unsigned int)f2bf(v0.x) | ((unsigned int)f2bf(v0.y) << 16);
    u.y = (unsigned int)f2bf(v0.z) | ((unsigned int)f2bf(v0.w) << 16);
    u.z = (unsigned int)f2bf(v1.x) | ((unsigned int)f2bf(v1.y) << 16);
    u.w = (unsigned int)f2bf(v1.z) | ((unsigned int)f2bf(v1.w) << 16);
    *reinterpret_cast<uint4*>(xb + (size_t)i * 8) = u;
}

// ---------------------------------------------------------------------------
// OLD path: x rows [0,N2) -> bf16 into A1b cols [128,256), stride 256.
// ---------------------------------------------------------------------------
__global__ void xcvt_kernel(const float* __restrict__ x,
                            unsigned short* __restrict__ A1b) {
    int i = blockIdx.x * blockDim.x + threadIdx.x;   // over N2*32
    if (i >= N2 * 32) return;
    int row = i >> 5, c4 = (i & 31) * 4;
    float4 v = *reinterpret_cast<const float4*>(x + (size_t)row * IND + c4);
    unsigned int lo = (unsigned int)f2bf(v.x) | ((unsigned int)f2bf(v.y) << 16);
    unsigned int hi = (unsigned int)f2bf(v.z) | ((unsigned int)f2bf(v.w) << 16);
    *reinterpret_cast<uint2*>(A1b + (size_t)row * 256 + 128 + c4) =
        make_uint2(lo, hi);
}

// ---------------------------------------------------------------------------
// Weight conversions to bf16 (j-major, k contiguous = MFMA B-frag layout).
// ---------------------------------------------------------------------------
__global__ void w1b_kernel(const float* __restrict__ W1l,
                           const float* __restrict__ W1r,
                           unsigned short* __restrict__ Wb) {
    int i = blockIdx.x * blockDim.x + threadIdx.x;   // over 256*256
    if (i >= HID * 2 * IND) return;
    int j = i >> 8, k = i & 255;
    float v = (k < IND) ? W1l[(size_t)j * IND + k]
                        : W1r[(size_t)j * IND + (k - IND)];
    Wb[i] = (short)f2bf(v);
}

__global__ void w2b_kernel(const float* __restrict__ W2l,
                           const float* __restrict__ W2r,
                           unsigned short* __restrict__ Wb) {
    int i = blockIdx.x * blockDim.x + threadIdx.x;   // over 64*512
    if (i >= OUTD * 2 * HID) return;
    int j = i >> 9, k = i & 511;
    float v = (k < HID) ? W2l[(size_t)j * HID + k]
                        : W2r[(size_t)j * HID + (k - HID)];
    Wb[i] = (short)f2bf(v);
}

// ---------------------------------------------------------------------------
// NEW path gather-mean layer 1: bf16 gather from xb -> mean1b[40000][128].
// ---------------------------------------------------------------------------
__global__ __launch_bounds__(256) void gather1b_kernel(
    const unsigned short* __restrict__ xb, const int* __restrict__ csr,
    const int* __restrict__ rowstart, const int* __restrict__ deg,
    unsigned short* __restrict__ meanb) {
    const int node = blockIdx.x * 4 + (threadIdx.x >> 6);
    const int lane = threadIdx.x & 63;
    const int beg = rowstart[node];
    const int n   = deg[node];
    float a0 = 0.f, a1 = 0.f, c0 = 0.f, c1 = 0.f;
    int e = 0;
    for (; e + 1 < n; e += 2) {
        int s0 = csr[beg + e];
        int s1 = csr[beg + e + 1];
        unsigned int v0 = *reinterpret_cast<const unsigned int*>(
            xb + (size_t)s0 * IND + lane * 2);
        unsigned int v1 = *reinterpret_cast<const unsigned int*>(
            xb + (size_t)s1 * IND + lane * 2);
        a0 += bf2f((unsigned short)v0); a1 += bf2f((unsigned short)(v0 >> 16));
        c0 += bf2f((unsigned short)v1); c1 += bf2f((unsigned short)(v1 >> 16));
    }
    if (e < n) {
        int s0 = csr[beg + e];
        unsigned int v0 = *reinterpret_cast<const unsigned int*>(
            xb + (size_t)s0 * IND + lane * 2);
        a0 += bf2f((unsigned short)v0); a1 += bf2f((unsigned short)(v0 >> 16));
    }
    const float inv = (n > 0) ? 1.0f / (float)n : 0.0f;
    unsigned int packed = (unsigned int)f2bf((a0 + c0) * inv)
                        | ((unsigned int)f2bf((a1 + c1) * inv) << 16);
    *reinterpret_cast<unsigned int*>(meanb + (size_t)node * IND + lane * 2) = packed;
}

// ---------------------------------------------------------------------------
// OLD path gather-mean layer 1: fp32 gather from x -> A1b cols [0,128).
// ---------------------------------------------------------------------------
__global__ __launch_bounds__(256) void gather1_kernel(
    const float* __restrict__ x, const int* __restrict__ csr,
    const int* __restrict__ rowstart, const int* __restrict__ deg,
    unsigned short* __restrict__ A1b) {
    const int node = blockIdx.x * 4 + (threadIdx.x >> 6);
    const int lane = threadIdx.x & 63;
    const int beg = rowstart[node];
    const int n   = deg[node];
    float2 acc0 = make_float2(0.f, 0.f), acc1 = make_float2(0.f, 0.f);
    int e = 0;
    for (; e + 1 < n; e += 2) {
        int s0 = csr[beg + e];
        int s1 = csr[beg + e + 1];
        float2 v0 = *reinterpret_cast<const float2*>(x + (size_t)s0 * IND + lane * 2);
        float2 v1 = *reinterpret_cast<const float2*>(x + (size_t)s1 * IND + lane * 2);
        acc0.x += v0.x; acc0.y += v0.y;
        acc1.x += v1.x; acc1.y += v1.y;
    }
    if (e < n) {
        int s0 = csr[beg + e];
        float2 v0 = *reinterpret_cast<const float2*>(x + (size_t)s0 * IND + lane * 2);
        acc0.x += v0.x; acc0.y += v0.y;
    }
    const float inv = (n > 0) ? 1.0f / (float)n : 0.0f;
    unsigned int packed = (unsigned int)f2bf((acc0.x + acc1.x) * inv)
                        | ((unsigned int)f2bf((acc0.y + acc1.y) * inv) << 16);
    *reinterpret_cast<unsigned int*>(A1b + (size_t)node * 256 + lane * 2) = packed;
}

// ---------------------------------------------------------------------------
// Layer-1 dense GEMM on MFMA, two-pointer A (mean half / x half).
// ---------------------------------------------------------------------------
__global__ __launch_bounds__(256) void sage1_kernel(
    const unsigned short* __restrict__ Am, int sM,
    const unsigned short* __restrict__ Ax, int sX,
    const unsigned short* __restrict__ Wb,
    const float* __restrict__ b1,
    unsigned short* __restrict__ hb) {
    const int t    = threadIdx.x;
    const int wave = t >> 6;
    const int lane = t & 63;
    const int l15  = lane & 15;
    const int kh   = lane >> 4;              // 0..3
    const int wm   = wave >> 1;              // 0..1
    const int wn   = wave & 1;               // 0..1
    const int row0 = blockIdx.x * 64 + wm * 32;    // 625*64 == 40000 exact
    const int col0 = blockIdx.y * 128 + wn * 64;

    f32x4 acc[2][4];
#pragma unroll
    for (int m = 0; m < 2; ++m)
#pragma unroll
        for (int n = 0; n < 4; ++n)
            acc[m][n] = (f32x4){0.f, 0.f, 0.f, 0.f};

#pragma unroll
    for (int ks = 0; ks < 8; ++ks) {
        const unsigned short* __restrict__ Ab = (ks < 4) ? Am : Ax;
        const int sA = (ks < 4) ? sM : sX;
        const int k0 = (ks & 3) * 32 + kh * 8;
        bf16x8 a[2], b[4];
#pragma unroll
        for (int m = 0; m < 2; ++m)
            a[m] = *reinterpret_cast<const bf16x8*>(
                Ab + (size_t)(row0 + m * 16 + l15) * sA + k0);
#pragma unroll
        for (int n = 0; n < 4; ++n)
            b[n] = *reinterpret_cast<const bf16x8*>(
                Wb + (size_t)(col0 + n * 16 + l15) * 256 + ks * 32 + kh * 8);
#pragma unroll
        for (int m = 0; m < 2; ++m)
#pragma unroll
            for (int n = 0; n < 4; ++n)
                acc[m][n] = __builtin_amdgcn_mfma_f32_16x16x32_bf16(
                    a[m], b[n], acc[m][n], 0, 0, 0);
    }

#pragma unroll
    for (int m = 0; m < 2; ++m) {
        const int r0 = row0 + m * 16 + kh * 4;
#pragma unroll
        for (int n = 0; n < 4; ++n) {
            const int c = col0 + n * 16 + l15;
            const float bias = b1[c];
#pragma unroll
            for (int j = 0; j < 4; ++j)
                hb[(size_t)(r0 + j) * HID + c] =
                    f2bf(fmaxf(acc[m][n][j] + bias, 0.0f));
        }
    }
}

// ---------------------------------------------------------------------------
// Gather-mean layer 2 (bf16 in, f32 accum, bf16 out).
// ---------------------------------------------------------------------------
__global__ __launch_bounds__(256) void gather2_kernel(
    const unsigned short* __restrict__ hb, const int* __restrict__ csr,
    const int* __restrict__ rowstart, const int* __restrict__ deg,
    unsigned short* __restrict__ meanb) {
    const int node = blockIdx.x * 4 + (threadIdx.x >> 6);
    const int lane = threadIdx.x & 63;
    const int beg = rowstart[node];
    const int n   = deg[node];
    float a0 = 0.f, a1 = 0.f, a2 = 0.f, a3 = 0.f;
    float c0 = 0.f, c1 = 0.f, c2 = 0.f, c3 = 0.f;
    int e = 0;
    for (; e + 1 < n; e += 2) {
        int s0 = csr[beg + e];
        int s1 = csr[beg + e + 1];
        ushort4 v0 = *reinterpret_cast<const ushort4*>(hb + (size_t)s0 * HID + lane * 4);
        ushort4 v1 = *reinterpret_cast<const ushort4*>(hb + (size_t)s1 * HID + lane * 4);
        a0 += bf2f(v0.x); a1 += bf2f(v0.y); a2 += bf2f(v0.z); a3 += bf2f(v0.w);
        c0 += bf2f(v1.x); c1 += bf2f(v1.y); c2 += bf2f(v1.z); c3 += bf2f(v1.w);
    }
    if (e < n) {
        int s0 = csr[beg + e];
        ushort4 v0 = *reinterpret_cast<const ushort4*>(hb + (size_t)s0 * HID + lane * 4);
        a0 += bf2f(v0.x); a1 += bf2f(v0.y); a2 += bf2f(v0.z); a3 += bf2f(v0.w);
    }
    const float inv = (n > 0) ? 1.0f / (float)n : 0.0f;
    unsigned int lo = (unsigned int)f2bf((a0 + c0) * inv)
                    | ((unsigned int)f2bf((a1 + c1) * inv) << 16);
    unsigned int hi = (unsigned int)f2bf((a2 + c2) * inv)
                    | ((unsigned int)f2bf((a3 + c3) * inv) << 16);
    *reinterpret_cast<uint2*>(meanb + (size_t)node * HID + lane * 4) =
        make_uint2(lo, hi);
}

// ---------------------------------------------------------------------------
// Layer-2 dense GEMM on MFMA + in-register log_softmax.
// ---------------------------------------------------------------------------
__global__ __launch_bounds__(256) void sage2_kernel(
    const unsigned short* __restrict__ hb,
    const unsigned short* __restrict__ meanb,
    const unsigned short* __restrict__ Wb,
    const float* __restrict__ b2,
    float* __restrict__ out) {
    const int t    = threadIdx.x;
    const int wave = t >> 6;
    const int lane = t & 63;
    const int l15  = lane & 15;
    const int kh   = lane >> 4;
    const int row0 = blockIdx.x * 64 + wave * 16;
    const int arow = min(row0 + l15, N3 - 1);   // clamp loads; stores guarded

    f32x4 acc[4];
#pragma unroll
    for (int n = 0; n < 4; ++n) acc[n] = (f32x4){0.f, 0.f, 0.f, 0.f};

#pragma unroll
    for (int half = 0; half < 2; ++half) {
        const unsigned short* __restrict__ A = half ? hb : meanb;
#pragma unroll
        for (int ks = 0; ks < 8; ++ks) {
            const int k0 = ks * 32 + kh * 8;
            bf16x8 a = *reinterpret_cast<const bf16x8*>(
                A + (size_t)arow * HID + k0);
            bf16x8 b[4];
#pragma unroll
            for (int n = 0; n < 4; ++n)
                b[n] = *reinterpret_cast<const bf16x8*>(
                    Wb + (size_t)(n * 16 + l15) * 512 + half * 256 + k0);
#pragma unroll
            for (int n = 0; n < 4; ++n)
                acc[n] = __builtin_amdgcn_mfma_f32_16x16x32_bf16(
                    a, b[n], acc[n], 0, 0, 0);
        }
    }

    float v[4][4];
#pragma unroll
    for (int n = 0; n < 4; ++n) {
        const float bn = b2[n * 16 + l15];
#pragma unroll
        for (int j = 0; j < 4; ++j) v[n][j] = acc[n][j] + bn;
    }

#pragma unroll
    for (int j = 0; j < 4; ++j) {
        float mx = fmaxf(fmaxf(v[0][j], v[1][j]), fmaxf(v[2][j], v[3][j]));
#pragma unroll
        for (int o = 1; o <= 8; o <<= 1) mx = fmaxf(mx, __shfl_xor(mx, o));
        float sm = 0.f;
#pragma unroll
        for (int n = 0; n < 4; ++n) sm += __expf(v[n][j] - mx);
#pragma unroll
        for (int o = 1; o <= 8; o <<= 1) sm += __shfl_xor(sm, o);
        const float lse = mx + __logf(sm);
        const int r = row0 + kh * 4 + j;
        if (r < N3) {
#pragma unroll
            for (int n = 0; n < 4; ++n)
                out[(size_t)r * OUTD + n * 16 + l15] = v[n][j] - lse;
        }
    }
}

// ---------------------------------------------------------------------------
extern "C" void kernel_launch(void* const* d_in, const int* in_sizes, int n_in,
                              void* d_out, int out_size, void* d_ws, size_t ws_size,
                              hipStream_t stream) {
    const float* x    = (const float*)d_in[0];
    const int*   src1 = (const int*)d_in[1];
    const int*   dst1 = (const int*)d_in[2];
    const int*   src2 = (const int*)d_in[3];
    const int*   dst2 = (const int*)d_in[4];
    const float* W1l  = (const float*)d_in[7];
    const float* W1r  = (const float*)d_in[8];
    const float* b1   = (const float*)d_in[9];
    const float* W2l  = (const float*)d_in[10];
    const float* W2r  = (const float*)d_in[11];
    const float* b2   = (const float*)d_in[12];
    float* out = (float*)d_out;

    const int E1 = in_sizes[1];
    const int E2 = in_sizes[3];

    // NEW layout (needs ~86 MB): full-x bf16 copy, mean1b separate.
    static constexpr size_t NEED_NEW = 85917120;
    const bool big = ws_size >= NEED_NEW;

    char* ws = (char*)d_ws;
    unsigned short *mean1b, *mean2b, *hb, *xb = nullptr, *A1b = nullptr;
    unsigned short *W2b, *Wb1;
    int *csr1, *csr2, *deg1, *cursor1, *deg2, *cursor2, *rowstart1, *rowstart2;
    int *bsum, *boff;
    char* z0;   // start of the contiguous {deg1,cursor1,deg2,cursor2} block

    if (big) {
        mean1b   = (unsigned short*)(ws + 0);           // 10,240,000
        mean2b   = (unsigned short*)(ws + 0);           // aliases (5.12 MB)
        hb       = (unsigned short*)(ws + 10240000);    // 20,480,000
        xb       = (unsigned short*)(ws + 30720000);    // 51,200,000
        csr1     = (int*)(ws + 81920000);               //  2,560,000
        csr2     = (int*)(ws + 84480000);               //    640,000
        deg1     = (int*)(ws + 85120000);               //    160,000
        cursor1  = (int*)(ws + 85280000);               //    160,000
        deg2     = (int*)(ws + 85440000);               //     40,000
        cursor2  = (int*)(ws + 85480000);               //     40,000
        rowstart1= (int*)(ws + 85520000);
        rowstart2= (int*)(ws + 85680000);
        W2b      = (unsigned short*)(ws + 85720000);
        Wb1      = (unsigned short*)(ws + 85785536);
        bsum     = (int*)(ws + 85916608);               //  256 B
        boff     = (int*)(ws + 85916864);               //  256 B (end 85,917,120)
        z0 = ws + 85120000;
    } else {
        A1b      = (unsigned short*)(ws + 0);           // 20,480,000
        mean1b   = nullptr;
        mean2b   = (unsigned short*)(ws + 0);
        hb       = (unsigned short*)(ws + 20480000);    // 20,480,000
        csr1     = (int*)(ws + 40960000);               //  2,560,000
        csr2     = (int*)(ws + 43520000);               //    640,000
        deg1     = (int*)(ws + 44160000);
        cursor1  = (int*)(ws + 44320000);
        deg2     = (int*)(ws + 44480000);
        cursor2  = (int*)(ws + 44520000);
        rowstart1= (int*)(ws + 44560000);
        rowstart2= (int*)(ws + 44720000);
        W2b      = (unsigned short*)(ws + 44760000);
        Wb1      = (unsigned short*)(ws + 44825536);
        bsum     = (int*)(ws + 44956608);
        boff     = (int*)(ws + 44956864);               // end 44,957,120
        z0 = ws + 44160000;
    }

    // one memset covers deg1|cursor1|deg2|cursor2 (contiguous 400,000 B)
    hipMemsetAsync(z0, 0, 400000, stream);

    if (big) {
        xball_kernel<<<(N1 * IND / 8 + 255) / 256, 256, 0, stream>>>(x, xb);
    } else {
        xcvt_kernel<<<(N2 * 32 + 255) / 256, 256, 0, stream>>>(x, A1b);
    }
    w1b_kernel<<<(2 * IND * HID + 255) / 256, 256, 0, stream>>>(W1l, W1r, Wb1);
    w2b_kernel<<<(OUTD * 2 * HID + 255) / 256, 256, 0, stream>>>(W2l, W2r, W2b);

    // ---- fused CSR build for both layers (hist -> 3-stage scan -> fill) ----
    {
        int tot = E1 + E2;
        hist_both_kernel<<<(tot + 255) / 256, 256, 0, stream>>>(
            dst1, E1, dst2, E2, deg1, deg2);
        scan1_kernel<<<SCAN_NB, 256, 0, stream>>>(deg1, deg2, bsum);
        scan2_kernel<<<1, 64, 0, stream>>>(bsum, boff);
        scan3_kernel<<<SCAN_NB, 256, 0, stream>>>(deg1, rowstart1,
                                                  deg2, rowstart2, boff);
        fill_both_kernel<<<(tot + 255) / 256, 256, 0, stream>>>(
            src1, dst1, E1, rowstart1, cursor1, csr1,
            src2, dst2, E2, rowstart2, cursor2, csr2);
    }

    // ---- layer 1: gather-mean + MFMA dense ----
    if (big) {
        gather1b_kernel<<<N2 / 4, 256, 0, stream>>>(xb, csr1, rowstart1, deg1,
                                                    mean1b);
        dim3 grid(N2 / 64, HID / 128);
        sage1_kernel<<<grid, 256, 0, stream>>>(mean1b, IND, xb, IND, Wb1, b1, hb);
    } else {
        gather1_kernel<<<N2 / 4, 256, 0, stream>>>(x, csr1, rowstart1, deg1, A1b);
        dim3 grid(N2 / 64, HID / 128);
        sage1_kernel<<<grid, 256, 0, stream>>>(A1b, HID, A1b + 128, HID, Wb1,
                                               b1, hb);
    }

    // ---- layer 2: gather-mean + MFMA dense + log_softmax ----
    gather2_kernel<<<N3 / 4, 256, 0, stream>>>(hb, csr2, rowstart2, deg2, mean2b);
    sage2_kernel<<<(N3 + 63) / 64, 256, 0, stream>>>(hb, mean2b, W2b, b2, out);
}

// Round 12
// 208.260 us; speedup vs baseline: 14.2431x; 1.0550x over previous
//
#include <hip/hip_runtime.h>

// Problem constants (fixed by the reference)
static constexpr int N1  = 200000;
static constexpr int N2  = 40000;
static constexpr int N3  = 10000;
static constexpr int IND = 128;
static constexpr int HID = 256;
static constexpr int OUTD = 64;

using f32x4  = __attribute__((ext_vector_type(4))) float;
using bf16x8 = __attribute__((ext_vector_type(8))) short;  // 8 bf16 (4 VGPRs)

// round-to-nearest-even f32 -> bf16 (finite inputs)
__device__ __forceinline__ unsigned short f2bf(float f) {
    unsigned int u = __float_as_uint(f);
    u += 0x7FFFu + ((u >> 16) & 1u);
    return (unsigned short)(u >> 16);
}
__device__ __forceinline__ float bf2f(unsigned short u) {
    return __uint_as_float((unsigned int)u << 16);
}

// ---------------------------------------------------------------------------
// Fused prep: zero {deg|cursor} block + W1->bf16 + W2->bf16 + x->bf16.
// All independent elementwise work; one launch instead of four.
//   range [0, NX)              : x convert (big: 8 f/thr whole x; small: 4 f/thr
//                                rows<N2 into A1b cols[128,256))
//   range [NX, NX+NZ)          : int4 zero of the deg/cursor block (400,000 B)
//   range [.., +NW1)           : W1l|W1r -> Wb1 (4 elems/thr)
//   range [.., +NW2)           : W2l|W2r -> W2b (4 elems/thr)
// ---------------------------------------------------------------------------
static constexpr int NZ4  = 400000 / 16;          // 25,000 int4
static constexpr int NW1g = HID * 2 * IND / 4;    // 16,384 groups
static constexpr int NW2g = OUTD * 2 * HID / 4;   //  8,192 groups
static constexpr int NX_BIG   = N1 * IND / 8;     // 3,200,000
static constexpr int NX_SMALL = N2 * 32;          // 1,280,000

__global__ void prep_kernel(const float* __restrict__ x,
                            unsigned short* __restrict__ xdst, int big,
                            int4* __restrict__ z0,
                            const float* __restrict__ W1l,
                            const float* __restrict__ W1r,
                            unsigned short* __restrict__ Wb1,
                            const float* __restrict__ W2l,
                            const float* __restrict__ W2r,
                            unsigned short* __restrict__ W2b) {
    int i = blockIdx.x * blockDim.x + threadIdx.x;
    const int NX = big ? NX_BIG : NX_SMALL;
    if (i < NX) {
        if (big) {
            const float4* p = reinterpret_cast<const float4*>(x + (size_t)i * 8);
            float4 v0 = p[0], v1 = p[1];
            uint4 u;
            u.x = (unsigned int)f2bf(v0.x) | ((unsigned int)f2bf(v0.y) << 16);
            u.y = (unsigned int)f2bf(v0.z) | ((unsigned int)f2bf(v0.w) << 16);
            u.z = (unsigned int)f2bf(v1.x) | ((unsigned int)f2bf(v1.y) << 16);
            u.w = (unsigned int)f2bf(v1.z) | ((unsigned int)f2bf(v1.w) << 16);
            *reinterpret_cast<uint4*>(xdst + (size_t)i * 8) = u;
        } else {
            int row = i >> 5, c4 = (i & 31) * 4;
            float4 v = *reinterpret_cast<const float4*>(x + (size_t)row * IND + c4);
            unsigned int lo = (unsigned int)f2bf(v.x) | ((unsigned int)f2bf(v.y) << 16);
            unsigned int hi = (unsigned int)f2bf(v.z) | ((unsigned int)f2bf(v.w) << 16);
            *reinterpret_cast<uint2*>(xdst + (size_t)row * 256 + 128 + c4) =
                make_uint2(lo, hi);
        }
        return;
    }
    i -= NX;
    if (i < NZ4) { z0[i] = make_int4(0, 0, 0, 0); return; }
    i -= NZ4;
    if (i < NW1g) {
        int j = i >> 6, k4 = (i & 63) * 4;
        const float* src = (k4 < IND) ? (W1l + (size_t)j * IND + k4)
                                      : (W1r + (size_t)j * IND + (k4 - IND));
        float4 v = *reinterpret_cast<const float4*>(src);
        ushort4 o = make_ushort4(f2bf(v.x), f2bf(v.y), f2bf(v.z), f2bf(v.w));
        *reinterpret_cast<ushort4*>(Wb1 + (size_t)j * 256 + k4) = o;
        return;
    }
    i -= NW1g;
    if (i < NW2g) {
        int j = i >> 7, k4 = (i & 127) * 4;
        const float* src = (k4 < HID) ? (W2l + (size_t)j * HID + k4)
                                      : (W2r + (size_t)j * HID + (k4 - HID));
        float4 v = *reinterpret_cast<const float4*>(src);
        ushort4 o = make_ushort4(f2bf(v.x), f2bf(v.y), f2bf(v.z), f2bf(v.w));
        *reinterpret_cast<ushort4*>(W2b + (size_t)j * 512 + k4) = o;
    }
}

// ---------------------------------------------------------------------------
// Fused histogram for both layers.
// ---------------------------------------------------------------------------
__global__ void hist_both_kernel(const int* __restrict__ dst1, int E1,
                                 const int* __restrict__ dst2, int E2,
                                 int* __restrict__ deg1,
                                 int* __restrict__ deg2) {
    int i = blockIdx.x * blockDim.x + threadIdx.x;
    if (i < E1) atomicAdd(&deg1[dst1[i]], 1);
    else if (i - E1 < E2) atomicAdd(&deg2[dst2[i - E1]], 1);
}

// ---------------------------------------------------------------------------
// Single-block fused exclusive scan of both deg arrays (int4 + two-level
// shfl scan). 1024 threads, 16 waves.
// ---------------------------------------------------------------------------
__device__ __forceinline__ int block_excl_scan(int s, int* wl) {
    __syncthreads();                       // protect wl reuse across calls
    const int t = threadIdx.x, lane = t & 63, wid = t >> 6;
    int incl = s;
#pragma unroll
    for (int o = 1; o < 64; o <<= 1) {
        int u = __shfl_up(incl, o);
        if (lane >= o) incl += u;
    }
    if (lane == 63) wl[wid] = incl;
    __syncthreads();
    if (t < 16) {
        int v = wl[t], iv = v;
#pragma unroll
        for (int o = 1; o < 16; o <<= 1) {
            int u = __shfl_up(iv, o);
            if (t >= o) iv += u;
        }
        wl[t] = iv - v;                    // exclusive wave prefix
    }
    __syncthreads();
    return wl[wid] + incl - s;
}

template <int PER>
__device__ __forceinline__ void scan_seg(const int* __restrict__ deg,
                                         int* __restrict__ rs,
                                         int n4, int* wl) {
    const int t = threadIdx.x;
    int4 v[PER];
    int s = 0;
#pragma unroll
    for (int i = 0; i < PER; ++i) {
        int idx = t * PER + i;
        if (idx < n4) {
            v[i] = reinterpret_cast<const int4*>(deg)[idx];
            s += v[i].x + v[i].y + v[i].z + v[i].w;
        } else {
            v[i] = make_int4(0, 0, 0, 0);
        }
    }
    int run = block_excl_scan(s, wl);
#pragma unroll
    for (int i = 0; i < PER; ++i) {
        int idx = t * PER + i;
        if (idx < n4) {
            reinterpret_cast<int4*>(rs)[idx] =
                make_int4(run, run + v[i].x, run + v[i].x + v[i].y,
                          run + v[i].x + v[i].y + v[i].z);
            run += v[i].x + v[i].y + v[i].z + v[i].w;
        }
    }
}

__global__ __launch_bounds__(1024) void scan_fused_kernel(
    const int* __restrict__ deg1, int* __restrict__ rowstart1,
    const int* __restrict__ deg2, int* __restrict__ rowstart2) {
    __shared__ int wl[16];
    scan_seg<10>(deg1, rowstart1, N2 / 4, wl);   // 10,000 int4
    scan_seg<3>(deg2, rowstart2, N3 / 4, wl);    //  2,500 int4
}

// ---------------------------------------------------------------------------
// Fused CSR fill for both layers.
// ---------------------------------------------------------------------------
__global__ void fill_both_kernel(
    const int* __restrict__ src1, const int* __restrict__ dst1, int E1,
    const int* __restrict__ rowstart1, int* __restrict__ cursor1,
    int* __restrict__ csr1,
    const int* __restrict__ src2, const int* __restrict__ dst2, int E2,
    const int* __restrict__ rowstart2, int* __restrict__ cursor2,
    int* __restrict__ csr2) {
    int i = blockIdx.x * blockDim.x + threadIdx.x;
    if (i < E1) {
        int d = dst1[i];
        int p = atomicAdd(&cursor1[d], 1);
        csr1[rowstart1[d] + p] = src1[i];
    } else if (i - E1 < E2) {
        int j = i - E1;
        int d = dst2[j];
        int p = atomicAdd(&cursor2[d], 1);
        csr2[rowstart2[d] + p] = src2[j];
    }
}

// ---------------------------------------------------------------------------
// NEW path gather-mean layer 1 (bf16 gather, 4-edge unroll).
// ---------------------------------------------------------------------------
__global__ __launch_bounds__(256) void gather1b_kernel(
    const unsigned short* __restrict__ xb, const int* __restrict__ csr,
    const int* __restrict__ rowstart, const int* __restrict__ deg,
    unsigned short* __restrict__ meanb) {
    const int node = blockIdx.x * 4 + (threadIdx.x >> 6);
    const int lane = threadIdx.x & 63;
    const int beg = rowstart[node];
    const int n   = deg[node];
    const unsigned short* __restrict__ xcol = xb + lane * 2;
    float a0 = 0.f, a1 = 0.f, b0 = 0.f, b1 = 0.f;
    float c0 = 0.f, c1 = 0.f, d0 = 0.f, d1 = 0.f;
    int e = 0;
    for (; e + 3 < n; e += 4) {
        int s0 = csr[beg + e],     s1 = csr[beg + e + 1];
        int s2 = csr[beg + e + 2], s3 = csr[beg + e + 3];
        unsigned int v0 = *reinterpret_cast<const unsigned int*>(xcol + (size_t)s0 * IND);
        unsigned int v1 = *reinterpret_cast<const unsigned int*>(xcol + (size_t)s1 * IND);
        unsigned int v2 = *reinterpret_cast<const unsigned int*>(xcol + (size_t)s2 * IND);
        unsigned int v3 = *reinterpret_cast<const unsigned int*>(xcol + (size_t)s3 * IND);
        a0 += bf2f((unsigned short)v0); a1 += bf2f((unsigned short)(v0 >> 16));
        b0 += bf2f((unsigned short)v1); b1 += bf2f((unsigned short)(v1 >> 16));
        c0 += bf2f((unsigned short)v2); c1 += bf2f((unsigned short)(v2 >> 16));
        d0 += bf2f((unsigned short)v3); d1 += bf2f((unsigned short)(v3 >> 16));
    }
    for (; e < n; ++e) {
        int s0 = csr[beg + e];
        unsigned int v0 = *reinterpret_cast<const unsigned int*>(xcol + (size_t)s0 * IND);
        a0 += bf2f((unsigned short)v0); a1 += bf2f((unsigned short)(v0 >> 16));
    }
    const float inv = (n > 0) ? 1.0f / (float)n : 0.0f;
    const float m0 = ((a0 + b0) + (c0 + d0)) * inv;
    const float m1 = ((a1 + b1) + (c1 + d1)) * inv;
    unsigned int packed = (unsigned int)f2bf(m0) | ((unsigned int)f2bf(m1) << 16);
    *reinterpret_cast<unsigned int*>(meanb + (size_t)node * IND + lane * 2) = packed;
}

// ---------------------------------------------------------------------------
// OLD (small-ws) path gather-mean layer 1: fp32 gather -> A1b cols [0,128).
// ---------------------------------------------------------------------------
__global__ __launch_bounds__(256) void gather1_kernel(
    const float* __restrict__ x, const int* __restrict__ csr,
    const int* __restrict__ rowstart, const int* __restrict__ deg,
    unsigned short* __restrict__ A1b) {
    const int node = blockIdx.x * 4 + (threadIdx.x >> 6);
    const int lane = threadIdx.x & 63;
    const int beg = rowstart[node];
    const int n   = deg[node];
    float2 acc0 = make_float2(0.f, 0.f), acc1 = make_float2(0.f, 0.f);
    int e = 0;
    for (; e + 1 < n; e += 2) {
        int s0 = csr[beg + e];
        int s1 = csr[beg + e + 1];
        float2 v0 = *reinterpret_cast<const float2*>(x + (size_t)s0 * IND + lane * 2);
        float2 v1 = *reinterpret_cast<const float2*>(x + (size_t)s1 * IND + lane * 2);
        acc0.x += v0.x; acc0.y += v0.y;
        acc1.x += v1.x; acc1.y += v1.y;
    }
    if (e < n) {
        int s0 = csr[beg + e];
        float2 v0 = *reinterpret_cast<const float2*>(x + (size_t)s0 * IND + lane * 2);
        acc0.x += v0.x; acc0.y += v0.y;
    }
    const float inv = (n > 0) ? 1.0f / (float)n : 0.0f;
    unsigned int packed = (unsigned int)f2bf((acc0.x + acc1.x) * inv)
                        | ((unsigned int)f2bf((acc0.y + acc1.y) * inv) << 16);
    *reinterpret_cast<unsigned int*>(A1b + (size_t)node * 256 + lane * 2) = packed;
}

// ---------------------------------------------------------------------------
// Layer-1 dense GEMM on MFMA, two-pointer A (mean half / x half).
// ---------------------------------------------------------------------------
__global__ __launch_bounds__(256) void sage1_kernel(
    const unsigned short* __restrict__ Am, int sM,
    const unsigned short* __restrict__ Ax, int sX,
    const unsigned short* __restrict__ Wb,
    const float* __restrict__ b1,
    unsigned short* __restrict__ hb) {
    const int t    = threadIdx.x;
    const int wave = t >> 6;
    const int lane = t & 63;
    const int l15  = lane & 15;
    const int kh   = lane >> 4;              // 0..3
    const int wm   = wave >> 1;              // 0..1
    const int wn   = wave & 1;               // 0..1
    const int row0 = blockIdx.x * 64 + wm * 32;    // 625*64 == 40000 exact
    const int col0 = blockIdx.y * 128 + wn * 64;

    f32x4 acc[2][4];
#pragma unroll
    for (int m = 0; m < 2; ++m)
#pragma unroll
        for (int n = 0; n < 4; ++n)
            acc[m][n] = (f32x4){0.f, 0.f, 0.f, 0.f};

#pragma unroll
    for (int ks = 0; ks < 8; ++ks) {
        const unsigned short* __restrict__ Ab = (ks < 4) ? Am : Ax;
        const int sA = (ks < 4) ? sM : sX;
        const int k0 = (ks & 3) * 32 + kh * 8;
        bf16x8 a[2], b[4];
#pragma unroll
        for (int m = 0; m < 2; ++m)
            a[m] = *reinterpret_cast<const bf16x8*>(
                Ab + (size_t)(row0 + m * 16 + l15) * sA + k0);
#pragma unroll
        for (int n = 0; n < 4; ++n)
            b[n] = *reinterpret_cast<const bf16x8*>(
                Wb + (size_t)(col0 + n * 16 + l15) * 256 + ks * 32 + kh * 8);
#pragma unroll
        for (int m = 0; m < 2; ++m)
#pragma unroll
            for (int n = 0; n < 4; ++n)
                acc[m][n] = __builtin_amdgcn_mfma_f32_16x16x32_bf16(
                    a[m], b[n], acc[m][n], 0, 0, 0);
    }

#pragma unroll
    for (int m = 0; m < 2; ++m) {
        const int r0 = row0 + m * 16 + kh * 4;
#pragma unroll
        for (int n = 0; n < 4; ++n) {
            const int c = col0 + n * 16 + l15;
            const float bias = b1[c];
#pragma unroll
            for (int j = 0; j < 4; ++j)
                hb[(size_t)(r0 + j) * HID + c] =
                    f2bf(fmaxf(acc[m][n][j] + bias, 0.0f));
        }
    }
}

// ---------------------------------------------------------------------------
// Gather-mean layer 2 (bf16 in, f32 accum, bf16 out, 4-edge unroll).
// ---------------------------------------------------------------------------
__global__ __launch_bounds__(256) void gather2_kernel(
    const unsigned short* __restrict__ hb, const int* __restrict__ csr,
    const int* __restrict__ rowstart, const int* __restrict__ deg,
    unsigned short* __restrict__ meanb) {
    const int node = blockIdx.x * 4 + (threadIdx.x >> 6);
    const int lane = threadIdx.x & 63;
    const int beg = rowstart[node];
    const int n   = deg[node];
    const unsigned short* __restrict__ hcol = hb + lane * 4;
    float acc0 = 0.f, acc1 = 0.f, acc2 = 0.f, acc3 = 0.f;
    int e = 0;
    for (; e + 3 < n; e += 4) {
        int s0 = csr[beg + e],     s1 = csr[beg + e + 1];
        int s2 = csr[beg + e + 2], s3 = csr[beg + e + 3];
        ushort4 v0 = *reinterpret_cast<const ushort4*>(hcol + (size_t)s0 * HID);
        ushort4 v1 = *reinterpret_cast<const ushort4*>(hcol + (size_t)s1 * HID);
        ushort4 v2 = *reinterpret_cast<const ushort4*>(hcol + (size_t)s2 * HID);
        ushort4 v3 = *reinterpret_cast<const ushort4*>(hcol + (size_t)s3 * HID);
        acc0 += (bf2f(v0.x) + bf2f(v1.x)) + (bf2f(v2.x) + bf2f(v3.x));
        acc1 += (bf2f(v0.y) + bf2f(v1.y)) + (bf2f(v2.y) + bf2f(v3.y));
        acc2 += (bf2f(v0.z) + bf2f(v1.z)) + (bf2f(v2.z) + bf2f(v3.z));
        acc3 += (bf2f(v0.w) + bf2f(v1.w)) + (bf2f(v2.w) + bf2f(v3.w));
    }
    for (; e < n; ++e) {
        int s0 = csr[beg + e];
        ushort4 v0 = *reinterpret_cast<const ushort4*>(hcol + (size_t)s0 * HID);
        acc0 += bf2f(v0.x); acc1 += bf2f(v0.y);
        acc2 += bf2f(v0.z); acc3 += bf2f(v0.w);
    }
    const float inv = (n > 0) ? 1.0f / (float)n : 0.0f;
    unsigned int lo = (unsigned int)f2bf(acc0 * inv)
                    | ((unsigned int)f2bf(acc1 * inv) << 16);
    unsigned int hi = (unsigned int)f2bf(acc2 * inv)
                    | ((unsigned int)f2bf(acc3 * inv) << 16);
    *reinterpret_cast<uint2*>(meanb + (size_t)node * HID + lane * 4) =
        make_uint2(lo, hi);
}

// ---------------------------------------------------------------------------
// Layer-2 dense GEMM on MFMA + in-register log_softmax.
// ---------------------------------------------------------------------------
__global__ __launch_bounds__(256) void sage2_kernel(
    const unsigned short* __restrict__ hb,
    const unsigned short* __restrict__ meanb,
    const unsigned short* __restrict__ Wb,
    const float* __restrict__ b2,
    float* __restrict__ out) {
    const int t    = threadIdx.x;
    const int wave = t >> 6;
    const int lane = t & 63;
    const int l15  = lane & 15;
    const int kh   = lane >> 4;
    const int row0 = blockIdx.x * 64 + wave * 16;
    const int arow = min(row0 + l15, N3 - 1);   // clamp loads; stores guarded

    f32x4 acc[4];
#pragma unroll
    for (int n = 0; n < 4; ++n) acc[n] = (f32x4){0.f, 0.f, 0.f, 0.f};

#pragma unroll
    for (int half = 0; half < 2; ++half) {
        const unsigned short* __restrict__ A = half ? hb : meanb;
#pragma unroll
        for (int ks = 0; ks < 8; ++ks) {
            const int k0 = ks * 32 + kh * 8;
            bf16x8 a = *reinterpret_cast<const bf16x8*>(
                A + (size_t)arow * HID + k0);
            bf16x8 b[4];
#pragma unroll
            for (int n = 0; n < 4; ++n)
                b[n] = *reinterpret_cast<const bf16x8*>(
                    Wb + (size_t)(n * 16 + l15) * 512 + half * 256 + k0);
#pragma unroll
            for (int n = 0; n < 4; ++n)
                acc[n] = __builtin_amdgcn_mfma_f32_16x16x32_bf16(
                    a, b[n], acc[n], 0, 0, 0);
        }
    }

    float v[4][4];
#pragma unroll
    for (int n = 0; n < 4; ++n) {
        const float bn = b2[n * 16 + l15];
#pragma unroll
        for (int j = 0; j < 4; ++j) v[n][j] = acc[n][j] + bn;
    }

#pragma unroll
    for (int j = 0; j < 4; ++j) {
        float mx = fmaxf(fmaxf(v[0][j], v[1][j]), fmaxf(v[2][j], v[3][j]));
#pragma unroll
        for (int o = 1; o <= 8; o <<= 1) mx = fmaxf(mx, __shfl_xor(mx, o));
        float sm = 0.f;
#pragma unroll
        for (int n = 0; n < 4; ++n) sm += __expf(v[n][j] - mx);
#pragma unroll
        for (int o = 1; o <= 8; o <<= 1) sm += __shfl_xor(sm, o);
        const float lse = mx + __logf(sm);
        const int r = row0 + kh * 4 + j;
        if (r < N3) {
#pragma unroll
            for (int n = 0; n < 4; ++n)
                out[(size_t)r * OUTD + n * 16 + l15] = v[n][j] - lse;
        }
    }
}

// ---------------------------------------------------------------------------
extern "C" void kernel_launch(void* const* d_in, const int* in_sizes, int n_in,
                              void* d_out, int out_size, void* d_ws, size_t ws_size,
                              hipStream_t stream) {
    const float* x    = (const float*)d_in[0];
    const int*   src1 = (const int*)d_in[1];
    const int*   dst1 = (const int*)d_in[2];
    const int*   src2 = (const int*)d_in[3];
    const int*   dst2 = (const int*)d_in[4];
    const float* W1l  = (const float*)d_in[7];
    const float* W1r  = (const float*)d_in[8];
    const float* b1   = (const float*)d_in[9];
    const float* W2l  = (const float*)d_in[10];
    const float* W2r  = (const float*)d_in[11];
    const float* b2   = (const float*)d_in[12];
    float* out = (float*)d_out;

    const int E1 = in_sizes[1];
    const int E2 = in_sizes[3];

    static constexpr size_t NEED_NEW = 85916608;
    const bool big = ws_size >= NEED_NEW;

    char* ws = (char*)d_ws;
    unsigned short *mean1b, *mean2b, *hb, *xb = nullptr, *A1b = nullptr;
    unsigned short *W2b, *Wb1;
    int *csr1, *csr2, *deg1, *cursor1, *deg2, *cursor2, *rowstart1, *rowstart2;
    char* z0;   // start of the contiguous {deg1,cursor1,deg2,cursor2} block

    if (big) {
        mean1b   = (unsigned short*)(ws + 0);           // 10,240,000
        mean2b   = (unsigned short*)(ws + 0);           // aliases (5.12 MB)
        hb       = (unsigned short*)(ws + 10240000);    // 20,480,000
        xb       = (unsigned short*)(ws + 30720000);    // 51,200,000
        csr1     = (int*)(ws + 81920000);               //  2,560,000
        csr2     = (int*)(ws + 84480000);               //    640,000
        deg1     = (int*)(ws + 85120000);               //    160,000
        cursor1  = (int*)(ws + 85280000);               //    160,000
        deg2     = (int*)(ws + 85440000);               //     40,000
        cursor2  = (int*)(ws + 85480000);               //     40,000
        rowstart1= (int*)(ws + 85520000);
        rowstart2= (int*)(ws + 85680000);
        W2b      = (unsigned short*)(ws + 85720000);
        Wb1      = (unsigned short*)(ws + 85785536);    // end 85,916,608
        z0 = ws + 85120000;
    } else {
        A1b      = (unsigned short*)(ws + 0);           // 20,480,000
        mean1b   = nullptr;
        mean2b   = (unsigned short*)(ws + 0);
        hb       = (unsigned short*)(ws + 20480000);    // 20,480,000
        csr1     = (int*)(ws + 40960000);               //  2,560,000
        csr2     = (int*)(ws + 43520000);               //    640,000
        deg1     = (int*)(ws + 44160000);
        cursor1  = (int*)(ws + 44320000);
        deg2     = (int*)(ws + 44480000);
        cursor2  = (int*)(ws + 44520000);
        rowstart1= (int*)(ws + 44560000);
        rowstart2= (int*)(ws + 44720000);
        W2b      = (unsigned short*)(ws + 44760000);
        Wb1      = (unsigned short*)(ws + 44825536);    // end 44,956,608
        z0 = ws + 44160000;
    }

    // ---- fused prep: zero + weight converts + x convert (1 launch) ----
    {
        const int NX = big ? NX_BIG : NX_SMALL;
        const int total = NX + NZ4 + NW1g + NW2g;
        prep_kernel<<<(total + 255) / 256, 256, 0, stream>>>(
            x, big ? xb : A1b, (int)big, (int4*)z0,
            W1l, W1r, Wb1, W2l, W2r, W2b);
    }

    // ---- fused CSR build: hist -> single-block scan -> fill (3 launches) ----
    {
        int tot = E1 + E2;
        hist_both_kernel<<<(tot + 255) / 256, 256, 0, stream>>>(
            dst1, E1, dst2, E2, deg1, deg2);
        scan_fused_kernel<<<1, 1024, 0, stream>>>(deg1, rowstart1,
                                                  deg2, rowstart2);
        fill_both_kernel<<<(tot + 255) / 256, 256, 0, stream>>>(
            src1, dst1, E1, rowstart1, cursor1, csr1,
            src2, dst2, E2, rowstart2, cursor2, csr2);
    }

    // ---- layer 1: gather-mean + MFMA dense ----
    if (big) {
        gather1b_kernel<<<N2 / 4, 256, 0, stream>>>(xb, csr1, rowstart1, deg1,
                                                    mean1b);
        dim3 grid(N2 / 64, HID / 128);
        sage1_kernel<<<grid, 256, 0, stream>>>(mean1b, IND, xb, IND, Wb1, b1, hb);
    } else {
        gather1_kernel<<<N2 / 4, 256, 0, stream>>>(x, csr1, rowstart1, deg1, A1b);
        dim3 grid(N2 / 64, HID / 128);
        sage1_kernel<<<grid, 256, 0, stream>>>(A1b, HID, A1b + 128, HID, Wb1,
                                               b1, hb);
    }

    // ---- layer 2: gather-mean + MFMA dense + log_softmax ----
    gather2_kernel<<<N3 / 4, 256, 0, stream>>>(hb, csr2, rowstart2, deg2, mean2b);
    sage2_kernel<<<(N3 + 63) / 64, 256, 0, stream>>>(hb, mean2b, W2b, b2, out);
}